// Round 2
// baseline (2185.546 us; speedup 1.0000x reference)
//
#include <hip/hip_runtime.h>
#include <cstdint>
#include <cstddef>

#define SS 8192
#define DD 1024
#define DI2 2048
#define NR 16384   // B*S

typedef __attribute__((ext_vector_type(4))) float f32x4;
typedef __attribute__((ext_vector_type(8))) __bf16 bf16x8;

union U16 { uint4 u; bf16x8 b; };

static __device__ __forceinline__ f32x4 MFMA(uint4 a, uint4 b, f32x4 c) {
  U16 ua, ub; ua.u = a; ub.u = b;
  return __builtin_amdgcn_mfma_f32_16x16x32_bf16(ua.b, ub.b, c, 0, 0, 0);
}

static __device__ __forceinline__ unsigned short f2bf(float f) {
  union { float f; unsigned u; } v; v.f = f;
  return (unsigned short)((v.u + 0x7FFFu + ((v.u >> 16) & 1u)) >> 16);
}
static __device__ __forceinline__ float bf2f(unsigned b) {
  union { unsigned u; float f; } v; v.u = b << 16; return v.f;
}
static __device__ __forceinline__ void unpack8(uint4 u, float* f) {
  f[0] = bf2f(u.x & 0xFFFFu); f[1] = bf2f(u.x >> 16);
  f[2] = bf2f(u.y & 0xFFFFu); f[3] = bf2f(u.y >> 16);
  f[4] = bf2f(u.z & 0xFFFFu); f[5] = bf2f(u.z >> 16);
  f[6] = bf2f(u.w & 0xFFFFu); f[7] = bf2f(u.w >> 16);
}

// Bijective XOR swizzles (bank-conflict-reduced b128 frag reads + staging writes).
static __device__ __forceinline__ int swz64(int row, int kb)  { return ((row << 6) | kb) ^ ((row & 7) << 4); }   // 64B rows
static __device__ __forceinline__ int swz128(int row, int kb) { return ((row << 7) | kb) ^ ((row & 7) << 4); }   // 128B rows
// scan M-mirror: per-wave region, 16 e-rows x 512B (256 dk bf16). kb < 512.
static __device__ __forceinline__ int swzM(int e, int kb)     { return ((e << 9) | kb) ^ ((e & 7) << 4); }

// ---------------- weight transpose + cast: out[c][r] = bf16(in[r][c]) ----------------
__global__ __launch_bounds__(256)
void transpose_cast(const float* __restrict__ in, unsigned short* __restrict__ out, int R, int Cc) {
  __shared__ float tile[32][33];
  const int r0 = blockIdx.y * 32, c0 = blockIdx.x * 32;
  const int tx = threadIdx.x, ty = threadIdx.y;
#pragma unroll
  for (int i = 0; i < 4; i++)
    tile[ty + i * 8][tx] = in[(size_t)(r0 + ty + i * 8) * Cc + c0 + tx];
  __syncthreads();
#pragma unroll
  for (int i = 0; i < 4; i++)
    out[(size_t)(c0 + ty + i * 8) * R + r0 + tx] = f2bf(tile[tx][ty + i * 8]);
}

// ---------------- RMSNorm (fp32 in -> bf16 out) ----------------
__global__ __launch_bounds__(256)
void rmsnorm_kernel(const float* __restrict__ x, const float* __restrict__ w,
                    unsigned short* __restrict__ out) {
  const int row = blockIdx.x, t = threadIdx.x;
  const float4 v = ((const float4*)(x + (size_t)row * DD))[t];
  float ss = v.x * v.x + v.y * v.y + v.z * v.z + v.w * v.w;
  __shared__ float sred[256];
  sred[t] = ss;
  __syncthreads();
  for (int o = 128; o > 0; o >>= 1) {
    if (t < o) sred[t] += sred[t + o];
    __syncthreads();
  }
  const float rr = rsqrtf(sred[0] * (1.0f / (float)DD) + 1e-5f);
  const float4 wv = ((const float4*)w)[t];
  uint2 pk;
  pk.x = (unsigned)f2bf(v.x * rr * wv.x) | ((unsigned)f2bf(v.y * rr * wv.y) << 16);
  pk.y = (unsigned)f2bf(v.z * rr * wv.z) | ((unsigned)f2bf(v.w * rr * wv.w) << 16);
  *(uint2*)(out + (size_t)row * DD + t * 4) = pk;
}

// ---------------- generic bf16 GEMM: C[M][N] = A[M][K] @ Bt[N][K]^T ----------------
enum { EP_BF16 = 0, EP_BF16_BOTH = 1, EP_BF16_T = 2, EP_F32_RES = 3 };

template <int MODE>
__global__ __launch_bounds__(256)
void gemm_bt(const unsigned short* __restrict__ A, const unsigned short* __restrict__ Bt,
             unsigned short* __restrict__ Cb, unsigned short* __restrict__ Ct,
             float* __restrict__ Cf, const float* __restrict__ resid,
             int M, int N, int K, float scale) {
  __shared__ char sA[8192];
  __shared__ char sB[8192];
  const int t = threadIdx.x, lane = t & 63, wid = t >> 6;
  const int wr = wid >> 1, wc = wid & 1;
  const int l15 = lane & 15, lh = lane >> 4;
  const int m0 = blockIdx.y * 128, n0 = blockIdx.x * 128;
  const int sr = t >> 2, skb = (t & 3) * 16;
  const unsigned short* Ar0 = A + (size_t)(m0 + sr) * K;
  const unsigned short* Ar1 = A + (size_t)(m0 + 64 + sr) * K;
  const unsigned short* Br0 = Bt + (size_t)(n0 + sr) * K;
  const unsigned short* Br1 = Bt + (size_t)(n0 + 64 + sr) * K;
  f32x4 acc[4][4] = {};
  for (int k0 = 0; k0 < K; k0 += 32) {
    const int ke = k0 + (t & 3) * 8;
    uint4 ra0 = *(const uint4*)(Ar0 + ke);
    uint4 ra1 = *(const uint4*)(Ar1 + ke);
    uint4 rb0 = *(const uint4*)(Br0 + ke);
    uint4 rb1 = *(const uint4*)(Br1 + ke);
    __syncthreads();
    *(uint4*)(sA + swz64(sr, skb)) = ra0;
    *(uint4*)(sA + swz64(sr + 64, skb)) = ra1;
    *(uint4*)(sB + swz64(sr, skb)) = rb0;
    *(uint4*)(sB + swz64(sr + 64, skb)) = rb1;
    __syncthreads();
    uint4 af[4], bfr[4];
#pragma unroll
    for (int i = 0; i < 4; i++) af[i]  = *(uint4*)(sA + swz64(wr * 64 + i * 16 + l15, lh * 16));
#pragma unroll
    for (int i = 0; i < 4; i++) bfr[i] = *(uint4*)(sB + swz64(wc * 64 + i * 16 + l15, lh * 16));
#pragma unroll
    for (int mf = 0; mf < 4; mf++)
#pragma unroll
      for (int nf = 0; nf < 4; nf++)
        acc[mf][nf] = MFMA(af[mf], bfr[nf], acc[mf][nf]);
  }
#pragma unroll
  for (int mf = 0; mf < 4; mf++) {
    const int r0 = m0 + wr * 64 + mf * 16 + lh * 4;
#pragma unroll
    for (int nf = 0; nf < 4; nf++) {
      const int c = n0 + wc * 64 + nf * 16 + l15;
      f32x4 v = acc[mf][nf] * scale;
      if constexpr (MODE == EP_F32_RES) {
#pragma unroll
        for (int jj = 0; jj < 4; jj++) {
          const size_t idx = (size_t)(r0 + jj) * N + c;
          Cf[idx] = v[jj] + resid[idx];
        }
      } else {
        if constexpr (MODE == EP_BF16 || MODE == EP_BF16_BOTH) {
#pragma unroll
          for (int jj = 0; jj < 4; jj++)
            Cb[(size_t)(r0 + jj) * N + c] = f2bf(v[jj]);
        }
        if constexpr (MODE == EP_BF16_BOTH || MODE == EP_BF16_T) {
          // transposed store: Ct[b][c][s]  (requires N == DD)
          const int bb = r0 >> 13, s0 = r0 & (SS - 1);
          uint2 pk;
          pk.x = (unsigned)f2bf(v[0]) | ((unsigned)f2bf(v[1]) << 16);
          pk.y = (unsigned)f2bf(v[2]) | ((unsigned)f2bf(v[3]) << 16);
          *(uint2*)(Ct + ((size_t)bb * DD + c) * SS + s0) = pk;
        }
      }
    }
  }
}

// ---------------- causal depthwise conv (K=4) + SiLU, gate SiLU, multiply ----------------
__global__ __launch_bounds__(256)
void convgate_kernel(const unsigned short* __restrict__ ug, const float* __restrict__ cw,
                     const float* __restrict__ cb, unsigned short* __restrict__ hin) {
  const int r = blockIdx.x;          // global row (b*S + s)
  const int c0 = threadIdx.x * 8;    // channel base [0,2048)
  const int s = r & (SS - 1);
  float acc[8];
#pragma unroll
  for (int i = 0; i < 8; i++) acc[i] = cb[c0 + i];
  for (int tap = 0; tap < 4; tap++) {
    const int ds = s - 3 + tap;
    if (ds < 0) continue;
    uint4 uv = *(const uint4*)(ug + (size_t)(r - 3 + tap) * 4096 + c0);
    float u[8]; unpack8(uv, u);
#pragma unroll
    for (int i = 0; i < 8; i++) acc[i] += u[i] * cw[tap * DI2 + c0 + i];
  }
  uint4 gv = *(const uint4*)(ug + (size_t)r * 4096 + DI2 + c0);
  float gt[8]; unpack8(gv, gt);
  unsigned short o16[8];
#pragma unroll
  for (int i = 0; i < 8; i++) {
    const float val = acc[i] / (1.0f + __expf(-acc[i]));
    const float gg  = gt[i] / (1.0f + __expf(-gt[i]));
    o16[i] = f2bf(val * gg);
  }
  uint4 ov;
  ov.x = (unsigned)o16[0] | ((unsigned)o16[1] << 16);
  ov.y = (unsigned)o16[2] | ((unsigned)o16[3] << 16);
  ov.z = (unsigned)o16[4] | ((unsigned)o16[5] << 16);
  ov.w = (unsigned)o16[6] | ((unsigned)o16[7] << 16);
  *(uint4*)(hin + (size_t)r * DI2 + c0) = ov;
}

// ---------------- intra-chunk: obuf = (tril(Q K^T)) V  per 64-chunk ----------------
__global__ __launch_bounds__(256)
void intra_kernel(const unsigned short* __restrict__ q, const unsigned short* __restrict__ k,
                  const unsigned short* __restrict__ vt, unsigned short* __restrict__ obuf) {
  __shared__ char sS[64 * 128];  // masked S as bf16, 128B rows, swizzled
  __shared__ char sQ[64 * 64];
  __shared__ char sK[64 * 64];
  const int j = blockIdx.x, b = blockIdx.y;
  const size_t g = (size_t)b * SS + (size_t)j * 64;
  const int t = threadIdx.x, lane = t & 63, wid = t >> 6;
  const int l15 = lane & 15, lh = lane >> 4;
  const int sr = t >> 2, skb = (t & 3) * 16;
  f32x4 accS[4] = {};
  for (int k0 = 0; k0 < DD; k0 += 32) {
    const int ke = k0 + (t & 3) * 8;
    uint4 rq = *(const uint4*)(q + (g + sr) * DD + ke);
    uint4 rk = *(const uint4*)(k + (g + sr) * DD + ke);
    __syncthreads();
    *(uint4*)(sQ + swz64(sr, skb)) = rq;
    *(uint4*)(sK + swz64(sr, skb)) = rk;
    __syncthreads();
    uint4 aq = *(uint4*)(sQ + swz64(wid * 16 + l15, lh * 16));
#pragma unroll
    for (int nf = 0; nf < 4; nf++) {
      uint4 bk = *(uint4*)(sK + swz64(nf * 16 + l15, lh * 16));
      accS[nf] = MFMA(aq, bk, accS[nf]);
    }
  }
  // mask (inclusive causal) + store S to LDS as bf16
#pragma unroll
  for (int nf = 0; nf < 4; nf++)
#pragma unroll
    for (int jj = 0; jj < 4; jj++) {
      const int r = wid * 16 + lh * 4 + jj;
      const int c = nf * 16 + l15;
      const float v = (c <= r) ? accS[nf][jj] : 0.0f;
      *(unsigned short*)(sS + swz128(r, c * 2)) = f2bf(v);
    }
  __syncthreads();
  uint4 a2[2];
  a2[0] = *(uint4*)(sS + swz128(wid * 16 + l15, lh * 16));
  a2[1] = *(uint4*)(sS + swz128(wid * 16 + l15, 64 + lh * 16));
  const unsigned short* vtb = vt + (size_t)b * DD * SS + (size_t)j * 64;
  for (int nb = 0; nb < 16; nb++) {
    f32x4 acc2[4] = {};
#pragma unroll
    for (int nf = 0; nf < 4; nf++) {
      const int col = nb * 64 + nf * 16 + l15;
      uint4 b0 = *(const uint4*)(vtb + (size_t)col * SS + lh * 8);
      uint4 b1 = *(const uint4*)(vtb + (size_t)col * SS + 32 + lh * 8);
      acc2[nf] = MFMA(a2[0], b0, acc2[nf]);
      acc2[nf] = MFMA(a2[1], b1, acc2[nf]);
    }
#pragma unroll
    for (int nf = 0; nf < 4; nf++)
#pragma unroll
      for (int jj = 0; jj < 4; jj++)
        obuf[(g + wid * 16 + lh * 4 + jj) * DD + nb * 64 + nf * 16 + l15] = f2bf(acc2[nf][jj]);
  }
}

// ---------------- sequential scan: obuf += Q_c @ M ;  M = 0.9*M + K_c^T V_c ----------------
// grid (64 e-slices, 2 batches): each block owns M[:, e0:e0+16] in MFMA acc registers (fp32).
// M^T bf16 mirror is PER-WAVE: wave wid both writes and reads dk in [wid*256, wid*256+256).
__global__ __launch_bounds__(256)
void scan_kernel(const unsigned short* __restrict__ q, const unsigned short* __restrict__ kt,
                 const unsigned short* __restrict__ vt, unsigned short* __restrict__ obuf) {
  __shared__ char Mt[4 * 8192];     // 4 waves x (16 e-rows x 512B = 256 dk bf16), 32KB
  __shared__ float red[4][64][16];  // cross-wave partial reduce, 16KB
  const int eg = blockIdx.x, b = blockIdx.y;
  const int e0 = eg * 16;
  const int t = threadIdx.x, lane = t & 63, wid = t >> 6;
  const int l15 = lane & 15, lh = lane >> 4;
  f32x4 Mreg[16] = {};
  char* Mw = Mt + wid * 8192;
  {
    uint4 z = make_uint4(0, 0, 0, 0);
    for (int i = t; i < (4 * 8192) / 16; i += 256) ((uint4*)Mt)[i] = z;
  }
  __syncthreads();
  const unsigned short* qb  = q  + (size_t)b * SS * DD;
  const unsigned short* ktb = kt + (size_t)b * DD * SS;
  const unsigned short* vtb = vt + ((size_t)b * DD + e0) * SS;
  unsigned short* obb = obuf + (size_t)b * SS * DD + e0;
  const int kbase = wid * 256;
  for (int j = 0; j < 128; j++) {
    // inter = Q_c @ M  (each wave: partial over its 256-wide dk-range)
    f32x4 acci[4] = {};
    for (int kk = 0; kk < 8; kk++) {
      const int k0 = kbase + kk * 32;
      uint4 bm = *(uint4*)(Mw + swzM(l15, (kk * 32 + lh * 8) * 2));
#pragma unroll
      for (int mf = 0; mf < 4; mf++) {
        uint4 aq = *(const uint4*)(qb + (size_t)(j * 64 + mf * 16 + l15) * DD + k0 + lh * 8);
        acci[mf] = MFMA(aq, bm, acci[mf]);
      }
    }
#pragma unroll
    for (int mf = 0; mf < 4; mf++)
#pragma unroll
      for (int jj = 0; jj < 4; jj++)
        red[wid][mf * 16 + lh * 4 + jj][l15] = acci[mf][jj];
    __syncthreads();
    // reduce over waves, add intra (already in obuf), write back
    {
      const int r = t >> 2, e4 = (t & 3) * 4;
      f32x4 sum = *(f32x4*)&red[0][r][e4];
      sum += *(f32x4*)&red[1][r][e4];
      sum += *(f32x4*)&red[2][r][e4];
      sum += *(f32x4*)&red[3][r][e4];
      unsigned short* op = obb + (size_t)(j * 64 + r) * DD + e4;
      uint2 iv = *(uint2*)op;
      uint2 ov;
      ov.x = (unsigned)f2bf(bf2f(iv.x & 0xFFFFu) + sum[0]) |
             ((unsigned)f2bf(bf2f(iv.x >> 16) + sum[1]) << 16);
      ov.y = (unsigned)f2bf(bf2f(iv.y & 0xFFFFu) + sum[2]) |
             ((unsigned)f2bf(bf2f(iv.y >> 16) + sum[3]) << 16);
      *(uint2*)op = ov;
    }
    // M = 0.9*M + K_c^T V_c  (each wave: its 256-row dk range; state stays in regs, fp32)
#pragma unroll
    for (int i = 0; i < 16; i++) Mreg[i] = Mreg[i] * 0.9f;
#pragma unroll
    for (int kk2 = 0; kk2 < 2; kk2++) {
      const int key = j * 64 + kk2 * 32 + lh * 8;
      uint4 bv = *(const uint4*)(vtb + (size_t)l15 * SS + key);
#pragma unroll
      for (int mf2 = 0; mf2 < 16; mf2++) {
        uint4 ak = *(const uint4*)(ktb + (size_t)(kbase + mf2 * 16 + l15) * SS + key);
        Mreg[mf2] = MFMA(ak, bv, Mreg[mf2]);
      }
    }
    // refresh per-wave bf16 mirror for next chunk's inter.
    // Mreg[mf2][jj] holds M[dk = kbase+mf2*16+lh*4+jj][e = l15]; mirror is [e][dkLocal].
#pragma unroll
    for (int mf2 = 0; mf2 < 16; mf2++) {
      uint2 pk;
      pk.x = (unsigned)f2bf(Mreg[mf2][0]) | ((unsigned)f2bf(Mreg[mf2][1]) << 16);
      pk.y = (unsigned)f2bf(Mreg[mf2][2]) | ((unsigned)f2bf(Mreg[mf2][3]) << 16);
      *(uint2*)(Mw + swzM(l15, mf2 * 32 + lh * 8)) = pk;
    }
    __syncthreads();
  }
}

extern "C" void kernel_launch(void* const* d_in, const int* in_sizes, int n_in,
                              void* d_out, int out_size, void* d_ws, size_t ws_size,
                              hipStream_t stream) {
  (void)in_sizes; (void)n_in; (void)out_size;
  const float* x      = (const float*)d_in[0];
  const float* norm_w = (const float*)d_in[1];
  const float* w_up   = (const float*)d_in[2];
  const float* w_gate = (const float*)d_in[3];
  const float* w_down = (const float*)d_in[4];
  const float* conv_w = (const float*)d_in[5];
  const float* conv_b = (const float*)d_in[6];
  const float* wq     = (const float*)d_in[7];
  const float* wk     = (const float*)d_in[8];
  const float* wv     = (const float*)d_in[9];
  const float* wo     = (const float*)d_in[10];
  float* out = (float*)d_out;

  const size_t MB = 1ull << 20;
  // Aliased workspace plan (212 MiB total). Lifetimes verified against launch order:
  //   [0,128M)   ug            -> then hbuf[0,32M) qbuf[32,64) kbuf[64,96) ktbuf[96,128)
  //   [128,160M) normed        -> then hin[128,192M) -> then vtbuf[128,160M)
  //   [160,192M)               ->      (hin tail)    -> then obuf[160,192M)
  //   [192,212M) weight transposes (wugt 8M, wdt 4M, wqt/wkt/wvt/wot 2M each)
  if (ws_size < 212 * MB) return;  // diagnostic: exact absmax 5.40625 => ws too small
  char* base = (char*)d_ws;
  unsigned short* ug     = (unsigned short*)(base + 0);
  unsigned short* hbuf   = (unsigned short*)(base + 0);
  unsigned short* qbuf   = (unsigned short*)(base + 32 * MB);
  unsigned short* kbuf   = (unsigned short*)(base + 64 * MB);
  unsigned short* ktbuf  = (unsigned short*)(base + 96 * MB);
  unsigned short* normed = (unsigned short*)(base + 128 * MB);
  unsigned short* hin    = (unsigned short*)(base + 128 * MB);
  unsigned short* vtbuf  = (unsigned short*)(base + 128 * MB);
  unsigned short* obuf   = (unsigned short*)(base + 160 * MB);
  unsigned short* wugt   = (unsigned short*)(base + 192 * MB);
  unsigned short* wdt    = (unsigned short*)(base + 200 * MB);
  unsigned short* wqt    = (unsigned short*)(base + 204 * MB);
  unsigned short* wkt    = (unsigned short*)(base + 206 * MB);
  unsigned short* wvt    = (unsigned short*)(base + 208 * MB);
  unsigned short* wot    = (unsigned short*)(base + 210 * MB);

  dim3 tb(32, 8);
  transpose_cast<<<dim3(DI2 / 32, DD / 32), tb, 0, stream>>>(w_up,   wugt,                    DD,  DI2);
  transpose_cast<<<dim3(DI2 / 32, DD / 32), tb, 0, stream>>>(w_gate, wugt + (size_t)DI2 * DD, DD,  DI2);
  transpose_cast<<<dim3(DD / 32, DI2 / 32), tb, 0, stream>>>(w_down, wdt, DI2, DD);
  transpose_cast<<<dim3(DD / 32, DD / 32),  tb, 0, stream>>>(wq, wqt, DD, DD);
  transpose_cast<<<dim3(DD / 32, DD / 32),  tb, 0, stream>>>(wk, wkt, DD, DD);
  transpose_cast<<<dim3(DD / 32, DD / 32),  tb, 0, stream>>>(wv, wvt, DD, DD);
  transpose_cast<<<dim3(DD / 32, DD / 32),  tb, 0, stream>>>(wo, wot, DD, DD);

  rmsnorm_kernel<<<NR, 256, 0, stream>>>(x, norm_w, normed);

  // [16384,1024] @ [1024,4096] -> ug (u | gate_pre)
  gemm_bt<EP_BF16><<<dim3(4096 / 128, NR / 128), 256, 0, stream>>>(
      normed, wugt, ug, nullptr, nullptr, nullptr, NR, 4096, DD, 1.0f);

  convgate_kernel<<<NR, 256, 0, stream>>>(ug, conv_w, conv_b, hin);

  // [16384,2048] @ [2048,1024] -> h
  gemm_bt<EP_BF16><<<dim3(DD / 128, NR / 128), 256, 0, stream>>>(
      hin, wdt, hbuf, nullptr, nullptr, nullptr, NR, DD, DI2, 1.0f);

  // q (scaled), k (+k^T), v^T
  gemm_bt<EP_BF16><<<dim3(DD / 128, NR / 128), 256, 0, stream>>>(
      hbuf, wqt, qbuf, nullptr, nullptr, nullptr, NR, DD, DD, 0.03125f);
  gemm_bt<EP_BF16_BOTH><<<dim3(DD / 128, NR / 128), 256, 0, stream>>>(
      hbuf, wkt, kbuf, ktbuf, nullptr, nullptr, NR, DD, DD, 1.0f);
  gemm_bt<EP_BF16_T><<<dim3(DD / 128, NR / 128), 256, 0, stream>>>(
      hbuf, wvt, nullptr, vtbuf, nullptr, nullptr, NR, DD, DD, 1.0f);

  intra_kernel<<<dim3(128, 2), 256, 0, stream>>>(qbuf, kbuf, vtbuf, obuf);
  scan_kernel<<<dim3(64, 2), 256, 0, stream>>>(qbuf, ktbuf, vtbuf, obuf);

  // out = obuf @ wo + x
  gemm_bt<EP_F32_RES><<<dim3(DD / 128, NR / 128), 256, 0, stream>>>(
      obuf, wot, nullptr, nullptr, out, x, NR, DD, DD, 1.0f);
}

// Round 3
// 1039.123 us; speedup vs baseline: 2.1033x; 2.1033x over previous
//
#include <hip/hip_runtime.h>
#include <cstdint>
#include <cstddef>

#define SS 8192
#define DD 1024
#define DI2 2048
#define NR 16384   // B*S

#define LOG2_09 (-0.152003093445050f)   // log2(0.9)
#define LAMBDA16 0.185302018885184f     // 0.9^16

typedef __attribute__((ext_vector_type(4))) float f32x4;
typedef __attribute__((ext_vector_type(8))) __bf16 bf16x8;

union U16 { uint4 u; bf16x8 b; };

static __device__ __forceinline__ f32x4 MFMA(uint4 a, uint4 b, f32x4 c) {
  U16 ua, ub; ua.u = a; ub.u = b;
  return __builtin_amdgcn_mfma_f32_16x16x32_bf16(ua.b, ub.b, c, 0, 0, 0);
}

static __device__ __forceinline__ unsigned short f2bf(float f) {
  union { float f; unsigned u; } v; v.f = f;
  return (unsigned short)((v.u + 0x7FFFu + ((v.u >> 16) & 1u)) >> 16);
}
static __device__ __forceinline__ float bf2f(unsigned b) {
  union { unsigned u; float f; } v; v.u = b << 16; return v.f;
}
static __device__ __forceinline__ void unpack8(uint4 u, float* f) {
  f[0] = bf2f(u.x & 0xFFFFu); f[1] = bf2f(u.x >> 16);
  f[2] = bf2f(u.y & 0xFFFFu); f[3] = bf2f(u.y >> 16);
  f[4] = bf2f(u.z & 0xFFFFu); f[5] = bf2f(u.z >> 16);
  f[6] = bf2f(u.w & 0xFFFFu); f[7] = bf2f(u.w >> 16);
}
static __device__ __forceinline__ uint4 scale8(uint4 u, float w) {
  float f[8]; unpack8(u, f);
  uint4 o;
  o.x = (unsigned)f2bf(f[0] * w) | ((unsigned)f2bf(f[1] * w) << 16);
  o.y = (unsigned)f2bf(f[2] * w) | ((unsigned)f2bf(f[3] * w) << 16);
  o.z = (unsigned)f2bf(f[4] * w) | ((unsigned)f2bf(f[5] * w) << 16);
  o.w = (unsigned)f2bf(f[6] * w) | ((unsigned)f2bf(f[7] * w) << 16);
  return o;
}

// Bijective XOR swizzles (bank-conflict-reduced b128 frag reads + staging writes).
static __device__ __forceinline__ int swz64(int row, int kb) { return ((row << 6) | kb) ^ ((row & 7) << 4); }    // 64B rows
static __device__ __forceinline__ int swzA(int row, int kb)  { return ((row << 11) | kb) ^ ((row & 7) << 4); }   // 2KB rows

// ---------------- weight transpose + cast: out[c][r] = bf16(in[r][c]) ----------------
__global__ __launch_bounds__(256)
void transpose_cast(const float* __restrict__ in, unsigned short* __restrict__ out, int R, int Cc) {
  __shared__ float tile[32][33];
  const int r0 = blockIdx.y * 32, c0 = blockIdx.x * 32;
  const int tx = threadIdx.x, ty = threadIdx.y;
#pragma unroll
  for (int i = 0; i < 4; i++)
    tile[ty + i * 8][tx] = in[(size_t)(r0 + ty + i * 8) * Cc + c0 + tx];
  __syncthreads();
#pragma unroll
  for (int i = 0; i < 4; i++)
    out[(size_t)(c0 + ty + i * 8) * R + r0 + tx] = f2bf(tile[tx][ty + i * 8]);
}

// ---------------- RMSNorm (fp32 in -> bf16 out) ----------------
__global__ __launch_bounds__(256)
void rmsnorm_kernel(const float* __restrict__ x, const float* __restrict__ w,
                    unsigned short* __restrict__ out) {
  const int row = blockIdx.x, t = threadIdx.x;
  const float4 v = ((const float4*)(x + (size_t)row * DD))[t];
  float ss = v.x * v.x + v.y * v.y + v.z * v.z + v.w * v.w;
  __shared__ float sred[256];
  sred[t] = ss;
  __syncthreads();
  for (int o = 128; o > 0; o >>= 1) {
    if (t < o) sred[t] += sred[t + o];
    __syncthreads();
  }
  const float rr = rsqrtf(sred[0] * (1.0f / (float)DD) + 1e-5f);
  const float4 wv = ((const float4*)w)[t];
  uint2 pk;
  pk.x = (unsigned)f2bf(v.x * rr * wv.x) | ((unsigned)f2bf(v.y * rr * wv.y) << 16);
  pk.y = (unsigned)f2bf(v.z * rr * wv.z) | ((unsigned)f2bf(v.w * rr * wv.w) << 16);
  *(uint2*)(out + (size_t)row * DD + t * 4) = pk;
}

// ---------------- generic bf16 GEMM: C[M][N] = A[M][K] @ Bt[N][K]^T ----------------
enum { EP_BF16 = 0, EP_BF16_BOTH = 1, EP_BF16_T = 2, EP_F32_RES = 3 };

template <int MODE>
__global__ __launch_bounds__(256)
void gemm_bt(const unsigned short* __restrict__ A, const unsigned short* __restrict__ Bt,
             unsigned short* __restrict__ Cb, unsigned short* __restrict__ Ct,
             float* __restrict__ Cf, const float* __restrict__ resid,
             int M, int N, int K, float scale) {
  __shared__ char sA[8192];
  __shared__ char sB[8192];
  const int t = threadIdx.x, lane = t & 63, wid = t >> 6;
  const int wr = wid >> 1, wc = wid & 1;
  const int l15 = lane & 15, lh = lane >> 4;
  const int m0 = blockIdx.y * 128, n0 = blockIdx.x * 128;
  const int sr = t >> 2, skb = (t & 3) * 16;
  const unsigned short* Ar0 = A + (size_t)(m0 + sr) * K;
  const unsigned short* Ar1 = A + (size_t)(m0 + 64 + sr) * K;
  const unsigned short* Br0 = Bt + (size_t)(n0 + sr) * K;
  const unsigned short* Br1 = Bt + (size_t)(n0 + 64 + sr) * K;
  f32x4 acc[4][4] = {};
  for (int k0 = 0; k0 < K; k0 += 32) {
    const int ke = k0 + (t & 3) * 8;
    uint4 ra0 = *(const uint4*)(Ar0 + ke);
    uint4 ra1 = *(const uint4*)(Ar1 + ke);
    uint4 rb0 = *(const uint4*)(Br0 + ke);
    uint4 rb1 = *(const uint4*)(Br1 + ke);
    __syncthreads();
    *(uint4*)(sA + swz64(sr, skb)) = ra0;
    *(uint4*)(sA + swz64(sr + 64, skb)) = ra1;
    *(uint4*)(sB + swz64(sr, skb)) = rb0;
    *(uint4*)(sB + swz64(sr + 64, skb)) = rb1;
    __syncthreads();
    uint4 af[4], bfr[4];
#pragma unroll
    for (int i = 0; i < 4; i++) af[i]  = *(uint4*)(sA + swz64(wr * 64 + i * 16 + l15, lh * 16));
#pragma unroll
    for (int i = 0; i < 4; i++) bfr[i] = *(uint4*)(sB + swz64(wc * 64 + i * 16 + l15, lh * 16));
#pragma unroll
    for (int mf = 0; mf < 4; mf++)
#pragma unroll
      for (int nf = 0; nf < 4; nf++)
        acc[mf][nf] = MFMA(af[mf], bfr[nf], acc[mf][nf]);
  }
#pragma unroll
  for (int mf = 0; mf < 4; mf++) {
    const int r0 = m0 + wr * 64 + mf * 16 + lh * 4;
#pragma unroll
    for (int nf = 0; nf < 4; nf++) {
      const int c = n0 + wc * 64 + nf * 16 + l15;
      f32x4 v = acc[mf][nf] * scale;
      if constexpr (MODE == EP_F32_RES) {
#pragma unroll
        for (int jj = 0; jj < 4; jj++) {
          const size_t idx = (size_t)(r0 + jj) * N + c;
          Cf[idx] = v[jj] + resid[idx];
        }
      } else {
        if constexpr (MODE == EP_BF16 || MODE == EP_BF16_BOTH) {
#pragma unroll
          for (int jj = 0; jj < 4; jj++)
            Cb[(size_t)(r0 + jj) * N + c] = f2bf(v[jj]);
        }
        if constexpr (MODE == EP_BF16_BOTH || MODE == EP_BF16_T) {
          // transposed store: Ct[b][c][s]  (requires N == DD)
          const int bb = r0 >> 13, s0 = r0 & (SS - 1);
          uint2 pk;
          pk.x = (unsigned)f2bf(v[0]) | ((unsigned)f2bf(v[1]) << 16);
          pk.y = (unsigned)f2bf(v[2]) | ((unsigned)f2bf(v[3]) << 16);
          *(uint2*)(Ct + ((size_t)bb * DD + c) * SS + s0) = pk;
        }
      }
    }
  }
}

// ---------------- causal depthwise conv (K=4) + SiLU, gate SiLU, multiply ----------------
__global__ __launch_bounds__(256)
void convgate_kernel(const unsigned short* __restrict__ ug, const float* __restrict__ cw,
                     const float* __restrict__ cb, unsigned short* __restrict__ hin) {
  const int r = blockIdx.x;          // global row (b*S + s)
  const int c0 = threadIdx.x * 8;    // channel base [0,2048)
  const int s = r & (SS - 1);
  float acc[8];
#pragma unroll
  for (int i = 0; i < 8; i++) acc[i] = cb[c0 + i];
  for (int tap = 0; tap < 4; tap++) {
    const int ds = s - 3 + tap;
    if (ds < 0) continue;
    uint4 uv = *(const uint4*)(ug + (size_t)(r - 3 + tap) * 4096 + c0);
    float u[8]; unpack8(uv, u);
#pragma unroll
    for (int i = 0; i < 8; i++) acc[i] += u[i] * cw[tap * DI2 + c0 + i];
  }
  uint4 gv = *(const uint4*)(ug + (size_t)r * 4096 + DI2 + c0);
  float gt[8]; unpack8(gv, gt);
  unsigned short o16[8];
#pragma unroll
  for (int i = 0; i < 8; i++) {
    const float val = acc[i] / (1.0f + __expf(-acc[i]));
    const float gg  = gt[i] / (1.0f + __expf(-gt[i]));
    o16[i] = f2bf(val * gg);
  }
  uint4 ov;
  ov.x = (unsigned)o16[0] | ((unsigned)o16[1] << 16);
  ov.y = (unsigned)o16[2] | ((unsigned)o16[3] << 16);
  ov.z = (unsigned)o16[4] | ((unsigned)o16[5] << 16);
  ov.w = (unsigned)o16[6] | ((unsigned)o16[7] << 16);
  *(uint4*)(hin + (size_t)r * DI2 + c0) = ov;
}

// ---------------- superchunk state: T[gb][e][dk] = sum_t 0.9^(15-t/64) V[t][e] K[t][dk] ----------------
__global__ __launch_bounds__(256)
void state_gemm(const unsigned short* __restrict__ vt, const unsigned short* __restrict__ kt,
                unsigned short* __restrict__ Tb) {
  __shared__ char sA[8192];
  __shared__ char sB[8192];
  const int t = threadIdx.x, lane = t & 63, wid = t >> 6;
  const int wr = wid >> 1, wc = wid & 1;
  const int l15 = lane & 15, lh = lane >> 4;
  const int gb = blockIdx.z, b = gb >> 3, g = gb & 7;
  const int m0 = blockIdx.y * 128, n0 = blockIdx.x * 128;
  const int sr = t >> 2, skb = (t & 3) * 16;
  const size_t kofs = (size_t)g * 1024;
  const unsigned short* Ar0 = vt + (size_t)(b * DD + m0 + sr) * SS + kofs;
  const unsigned short* Ar1 = Ar0 + (size_t)64 * SS;
  const unsigned short* Br0 = kt + (size_t)(b * DD + n0 + sr) * SS + kofs;
  const unsigned short* Br1 = Br0 + (size_t)64 * SS;
  f32x4 acc[4][4] = {};
  for (int k0 = 0; k0 < 1024; k0 += 32) {
    const int ke = k0 + (t & 3) * 8;
    const float w = exp2f((float)(15 - (ke >> 6)) * LOG2_09);
    uint4 ra0 = scale8(*(const uint4*)(Ar0 + ke), w);
    uint4 ra1 = scale8(*(const uint4*)(Ar1 + ke), w);
    uint4 rb0 = *(const uint4*)(Br0 + ke);
    uint4 rb1 = *(const uint4*)(Br1 + ke);
    __syncthreads();
    *(uint4*)(sA + swz64(sr, skb)) = ra0;
    *(uint4*)(sA + swz64(sr + 64, skb)) = ra1;
    *(uint4*)(sB + swz64(sr, skb)) = rb0;
    *(uint4*)(sB + swz64(sr + 64, skb)) = rb1;
    __syncthreads();
    uint4 af[4], bfr[4];
#pragma unroll
    for (int i = 0; i < 4; i++) af[i]  = *(uint4*)(sA + swz64(wr * 64 + i * 16 + l15, lh * 16));
#pragma unroll
    for (int i = 0; i < 4; i++) bfr[i] = *(uint4*)(sB + swz64(wc * 64 + i * 16 + l15, lh * 16));
#pragma unroll
    for (int mf = 0; mf < 4; mf++)
#pragma unroll
      for (int nf = 0; nf < 4; nf++)
        acc[mf][nf] = MFMA(af[mf], bfr[nf], acc[mf][nf]);
  }
  unsigned short* Tg = Tb + ((size_t)gb << 20);
#pragma unroll
  for (int mf = 0; mf < 4; mf++) {
    const int r0 = m0 + wr * 64 + mf * 16 + lh * 4;
#pragma unroll
    for (int nf = 0; nf < 4; nf++) {
      const int c = n0 + wc * 64 + nf * 16 + l15;
#pragma unroll
      for (int jj = 0; jj < 4; jj++)
        Tg[(size_t)(r0 + jj) * 1024 + c] = f2bf(acc[mf][nf][jj]);
    }
  }
}

// ---------------- superchunk prefix (in-place): Minit_g = 0.9^16 Minit_{g-1} + T_{g-1} ----------------
__global__ __launch_bounds__(256)
void prefix_kernel(unsigned short* __restrict__ Tb) {
  const int tid = blockIdx.x * 256 + threadIdx.x;  // 262144 threads
  const int b = tid >> 17, i = tid & 131071;
  unsigned short* p = Tb + (((size_t)b * 8) << 20) + (size_t)i * 8;
  float acc[8] = {};
  for (int g = 0; g < 8; g++) {
    unsigned short* pg = p + ((size_t)g << 20);
    uint4 tv = *(uint4*)pg;
    float tf_[8]; unpack8(tv, tf_);
    uint4 ov;
    ov.x = (unsigned)f2bf(acc[0]) | ((unsigned)f2bf(acc[1]) << 16);
    ov.y = (unsigned)f2bf(acc[2]) | ((unsigned)f2bf(acc[3]) << 16);
    ov.z = (unsigned)f2bf(acc[4]) | ((unsigned)f2bf(acc[5]) << 16);
    ov.w = (unsigned)f2bf(acc[6]) | ((unsigned)f2bf(acc[7]) << 16);
    *(uint4*)pg = ov;
#pragma unroll
    for (int e = 0; e < 8; e++) acc[e] = LAMBDA16 * acc[e] + tf_[e];
  }
}

// ---------------- fused within-superchunk attention (intra + within-superchunk inter) ----------------
// block = (qt: chunk-of-64 within superchunk, gb): S[64][t<= (qt+1)*64] decay-masked -> LDS bf16;
// then O = S @ V over 8 e-tiles of 128. Pure store to obuf.
__global__ __launch_bounds__(256)
void fused_attn(const unsigned short* __restrict__ q, const unsigned short* __restrict__ k,
                const unsigned short* __restrict__ vt, unsigned short* __restrict__ obuf) {
  __shared__ char sA[64 * 2048];  // 128KB: weighted scores bf16 [64 qr][1024 t], swizzled
  const int qt = blockIdx.x;      // 0..15
  const int gb = blockIdx.y;      // b*8+g
  const int b = gb >> 3, g = gb & 7;
  const int t = threadIdx.x, lane = t & 63, wid = t >> 6;
  const int l15 = lane & 15, lh = lane >> 4;
  const size_t qrow0 = (size_t)b * SS + (size_t)g * 1024 + (size_t)qt * 64;
  const unsigned short* qb = q + qrow0 * DD;
  const unsigned short* kb = k + ((size_t)b * SS + (size_t)g * 1024) * DD;
  const int nT = qt + 1;  // t-blocks of 64 (cols 0 .. nT*64)
  // ---- phase A: scores ----
  for (int tb = wid; tb < nT; tb += 4) {
    f32x4 s[4][4] = {};
    for (int k0 = 0; k0 < DD; k0 += 32) {
      uint4 qf[4], kf[4];
#pragma unroll
      for (int rf = 0; rf < 4; rf++)
        qf[rf] = *(const uint4*)(qb + (size_t)(rf * 16 + l15) * DD + k0 + lh * 8);
#pragma unroll
      for (int tf = 0; tf < 4; tf++)
        kf[tf] = *(const uint4*)(kb + (size_t)(tb * 64 + tf * 16 + l15) * DD + k0 + lh * 8);
#pragma unroll
      for (int rf = 0; rf < 4; rf++)
#pragma unroll
        for (int tf = 0; tf < 4; tf++)
          s[rf][tf] = MFMA(qf[rf], kf[tf], s[rf][tf]);
    }
    const bool diag = (tb == qt);
    const float w = diag ? 1.0f : exp2f((float)(qt - 1 - tb) * LOG2_09);
#pragma unroll
    for (int rf = 0; rf < 4; rf++)
#pragma unroll
      for (int tf = 0; tf < 4; tf++)
#pragma unroll
        for (int jj = 0; jj < 4; jj++) {
          const int qr = rf * 16 + lh * 4 + jj;   // 0..63
          const int tc = tf * 16 + l15;           // col within t-block
          float val = s[rf][tf][jj] * w;
          if (diag && tc > qr) val = 0.0f;        // inclusive tril within chunk
          *(unsigned short*)(sA + swzA(qr, (tb * 64 + tc) * 2)) = f2bf(val);
        }
  }
  __syncthreads();
  // ---- phase B: O = S @ V ----
  const unsigned short* vb = vt + (size_t)b * DD * SS + (size_t)g * 1024;  // + e*SS + t
  const int tEnd = nT * 64;
  for (int et = 0; et < 8; et++) {
    const int ew = et * 128 + wid * 32;  // wave's e-base
    f32x4 o[4][2] = {};
    for (int tc = 0; tc < tEnd; tc += 32) {
      uint4 af2[4], vf[2];
#pragma unroll
      for (int rf = 0; rf < 4; rf++)
        af2[rf] = *(uint4*)(sA + swzA(rf * 16 + l15, (tc + lh * 8) * 2));
#pragma unroll
      for (int cf = 0; cf < 2; cf++)
        vf[cf] = *(const uint4*)(vb + (size_t)(ew + cf * 16 + l15) * SS + tc + lh * 8);
#pragma unroll
      for (int rf = 0; rf < 4; rf++)
#pragma unroll
        for (int cf = 0; cf < 2; cf++)
          o[rf][cf] = MFMA(af2[rf], vf[cf], o[rf][cf]);
    }
#pragma unroll
    for (int rf = 0; rf < 4; rf++)
#pragma unroll
      for (int cf = 0; cf < 2; cf++)
#pragma unroll
        for (int jj = 0; jj < 4; jj++)
          obuf[(qrow0 + rf * 16 + lh * 4 + jj) * DD + ew + cf * 16 + l15] = f2bf(o[rf][cf][jj]);
  }
}

// ---------------- cross term: obuf += 0.9^cl(row) * Q @ Minit_g ----------------
__global__ __launch_bounds__(256)
void cross_gemm(const unsigned short* __restrict__ q, const unsigned short* __restrict__ Minit,
                unsigned short* __restrict__ obuf) {
  __shared__ char sA[8192];
  __shared__ char sB[8192];
  const int t = threadIdx.x, lane = t & 63, wid = t >> 6;
  const int wr = wid >> 1, wc = wid & 1;
  const int l15 = lane & 15, lh = lane >> 4;
  const int gb = blockIdx.z, b = gb >> 3, g = gb & 7;
  const int m0 = blockIdx.y * 128, n0 = blockIdx.x * 128;
  const int sr = t >> 2, skb = (t & 3) * 16;
  const unsigned short* Ar0 = q + (size_t)(b * SS + g * 1024 + m0 + sr) * DD;
  const unsigned short* Ar1 = Ar0 + (size_t)64 * DD;
  const unsigned short* Br0 = Minit + ((size_t)gb << 20) + (size_t)(n0 + sr) * 1024;
  const unsigned short* Br1 = Br0 + (size_t)64 * 1024;
  f32x4 acc[4][4] = {};
  for (int k0 = 0; k0 < 1024; k0 += 32) {
    const int ke = k0 + (t & 3) * 8;
    uint4 ra0 = *(const uint4*)(Ar0 + ke);
    uint4 ra1 = *(const uint4*)(Ar1 + ke);
    uint4 rb0 = *(const uint4*)(Br0 + ke);
    uint4 rb1 = *(const uint4*)(Br1 + ke);
    __syncthreads();
    *(uint4*)(sA + swz64(sr, skb)) = ra0;
    *(uint4*)(sA + swz64(sr + 64, skb)) = ra1;
    *(uint4*)(sB + swz64(sr, skb)) = rb0;
    *(uint4*)(sB + swz64(sr + 64, skb)) = rb1;
    __syncthreads();
    uint4 af[4], bfr[4];
#pragma unroll
    for (int i = 0; i < 4; i++) af[i]  = *(uint4*)(sA + swz64(wr * 64 + i * 16 + l15, lh * 16));
#pragma unroll
    for (int i = 0; i < 4; i++) bfr[i] = *(uint4*)(sB + swz64(wc * 64 + i * 16 + l15, lh * 16));
#pragma unroll
    for (int mf = 0; mf < 4; mf++)
#pragma unroll
      for (int nf = 0; nf < 4; nf++)
        acc[mf][nf] = MFMA(af[mf], bfr[nf], acc[mf][nf]);
  }
#pragma unroll
  for (int mf = 0; mf < 4; mf++) {
    const int rl = m0 + wr * 64 + mf * 16 + lh * 4;  // row within superchunk [0,1024)
#pragma unroll
    for (int nf = 0; nf < 4; nf++) {
      const int c = n0 + wc * 64 + nf * 16 + l15;
#pragma unroll
      for (int jj = 0; jj < 4; jj++) {
        const int r = rl + jj;
        const float rs = exp2f((float)(r >> 6) * LOG2_09);  // 0.9^chunk-local
        const size_t idx = ((size_t)b * SS + (size_t)g * 1024 + r) * DD + c;
        obuf[idx] = f2bf(bf2f(obuf[idx]) + acc[mf][nf][jj] * rs);
      }
    }
  }
}

extern "C" void kernel_launch(void* const* d_in, const int* in_sizes, int n_in,
                              void* d_out, int out_size, void* d_ws, size_t ws_size,
                              hipStream_t stream) {
  (void)in_sizes; (void)n_in; (void)out_size;
  const float* x      = (const float*)d_in[0];
  const float* norm_w = (const float*)d_in[1];
  const float* w_up   = (const float*)d_in[2];
  const float* w_gate = (const float*)d_in[3];
  const float* w_down = (const float*)d_in[4];
  const float* conv_w = (const float*)d_in[5];
  const float* conv_b = (const float*)d_in[6];
  const float* wq     = (const float*)d_in[7];
  const float* wk     = (const float*)d_in[8];
  const float* wv     = (const float*)d_in[9];
  const float* wo     = (const float*)d_in[10];
  float* out = (float*)d_out;

  const size_t MB = 1ull << 20;
  // Aliased workspace plan (212 MiB total). Lifetimes:
  //   [0,128M)   ug -> then hbuf[0,32M) qbuf[32,64) kbuf[64,96) ktbuf[96,128)
  //              hbuf dead after QKV gemms -> Tbuf/Minit [0,32M)
  //   [128,160M) normed -> hin[128,192M) -> vtbuf[128,160M)
  //   [160,192M) (hin tail) -> obuf[160,192M)
  //   [192,212M) weight transposes
  if (ws_size < 212 * MB) return;
  char* base = (char*)d_ws;
  unsigned short* ug     = (unsigned short*)(base + 0);
  unsigned short* hbuf   = (unsigned short*)(base + 0);
  unsigned short* Tbuf   = (unsigned short*)(base + 0);
  unsigned short* qbuf   = (unsigned short*)(base + 32 * MB);
  unsigned short* kbuf   = (unsigned short*)(base + 64 * MB);
  unsigned short* ktbuf  = (unsigned short*)(base + 96 * MB);
  unsigned short* normed = (unsigned short*)(base + 128 * MB);
  unsigned short* hin    = (unsigned short*)(base + 128 * MB);
  unsigned short* vtbuf  = (unsigned short*)(base + 128 * MB);
  unsigned short* obuf   = (unsigned short*)(base + 160 * MB);
  unsigned short* wugt   = (unsigned short*)(base + 192 * MB);
  unsigned short* wdt    = (unsigned short*)(base + 200 * MB);
  unsigned short* wqt    = (unsigned short*)(base + 204 * MB);
  unsigned short* wkt    = (unsigned short*)(base + 206 * MB);
  unsigned short* wvt    = (unsigned short*)(base + 208 * MB);
  unsigned short* wot    = (unsigned short*)(base + 210 * MB);

  dim3 tb(32, 8);
  transpose_cast<<<dim3(DI2 / 32, DD / 32), tb, 0, stream>>>(w_up,   wugt,                    DD,  DI2);
  transpose_cast<<<dim3(DI2 / 32, DD / 32), tb, 0, stream>>>(w_gate, wugt + (size_t)DI2 * DD, DD,  DI2);
  transpose_cast<<<dim3(DD / 32, DI2 / 32), tb, 0, stream>>>(w_down, wdt, DI2, DD);
  transpose_cast<<<dim3(DD / 32, DD / 32),  tb, 0, stream>>>(wq, wqt, DD, DD);
  transpose_cast<<<dim3(DD / 32, DD / 32),  tb, 0, stream>>>(wk, wkt, DD, DD);
  transpose_cast<<<dim3(DD / 32, DD / 32),  tb, 0, stream>>>(wv, wvt, DD, DD);
  transpose_cast<<<dim3(DD / 32, DD / 32),  tb, 0, stream>>>(wo, wot, DD, DD);

  rmsnorm_kernel<<<NR, 256, 0, stream>>>(x, norm_w, normed);

  gemm_bt<EP_BF16><<<dim3(4096 / 128, NR / 128), 256, 0, stream>>>(
      normed, wugt, ug, nullptr, nullptr, nullptr, NR, 4096, DD, 1.0f);

  convgate_kernel<<<NR, 256, 0, stream>>>(ug, conv_w, conv_b, hin);

  gemm_bt<EP_BF16><<<dim3(DD / 128, NR / 128), 256, 0, stream>>>(
      hin, wdt, hbuf, nullptr, nullptr, nullptr, NR, DD, DI2, 1.0f);

  gemm_bt<EP_BF16><<<dim3(DD / 128, NR / 128), 256, 0, stream>>>(
      hbuf, wqt, qbuf, nullptr, nullptr, nullptr, NR, DD, DD, 0.03125f);
  gemm_bt<EP_BF16_BOTH><<<dim3(DD / 128, NR / 128), 256, 0, stream>>>(
      hbuf, wkt, kbuf, ktbuf, nullptr, nullptr, NR, DD, DD, 1.0f);
  gemm_bt<EP_BF16_T><<<dim3(DD / 128, NR / 128), 256, 0, stream>>>(
      hbuf, wvt, nullptr, vtbuf, nullptr, nullptr, NR, DD, DD, 1.0f);

  // Hebbian memory via superchunk decomposition (G=16 chunks per superchunk):
  state_gemm<<<dim3(8, 8, 16), 256, 0, stream>>>(vtbuf, ktbuf, Tbuf);
  prefix_kernel<<<1024, 256, 0, stream>>>(Tbuf);
  fused_attn<<<dim3(16, 16), 256, 0, stream>>>(qbuf, kbuf, vtbuf, obuf);
  cross_gemm<<<dim3(8, 8, 16), 256, 0, stream>>>(qbuf, Tbuf, obuf);

  // out = obuf @ wo + x
  gemm_bt<EP_F32_RES><<<dim3(DD / 128, NR / 128), 256, 0, stream>>>(
      obuf, wot, nullptr, nullptr, out, x, NR, DD, DD, 1.0f);
}

// Round 4
// 939.824 us; speedup vs baseline: 2.3255x; 1.1057x over previous
//
#include <hip/hip_runtime.h>
#include <cstdint>
#include <cstddef>

#define SS 8192
#define DD 1024
#define DI2 2048
#define NR 16384   // B*S

#define LOG2_09 (-0.152003093445050f)   // log2(0.9)
#define LAMBDA16 0.185302018885184f     // 0.9^16

typedef __attribute__((ext_vector_type(4))) float f32x4;
typedef __attribute__((ext_vector_type(8))) __bf16 bf16x8;

union U16 { uint4 u; bf16x8 b; };

static __device__ __forceinline__ f32x4 MFMA(uint4 a, uint4 b, f32x4 c) {
  U16 ua, ub; ua.u = a; ub.u = b;
  return __builtin_amdgcn_mfma_f32_16x16x32_bf16(ua.b, ub.b, c, 0, 0, 0);
}

static __device__ __forceinline__ unsigned short f2bf(float f) {
  union { float f; unsigned u; } v; v.f = f;
  return (unsigned short)((v.u + 0x7FFFu + ((v.u >> 16) & 1u)) >> 16);
}
static __device__ __forceinline__ float bf2f(unsigned b) {
  union { unsigned u; float f; } v; v.u = b << 16; return v.f;
}
static __device__ __forceinline__ void unpack8(uint4 u, float* f) {
  f[0] = bf2f(u.x & 0xFFFFu); f[1] = bf2f(u.x >> 16);
  f[2] = bf2f(u.y & 0xFFFFu); f[3] = bf2f(u.y >> 16);
  f[4] = bf2f(u.z & 0xFFFFu); f[5] = bf2f(u.z >> 16);
  f[6] = bf2f(u.w & 0xFFFFu); f[7] = bf2f(u.w >> 16);
}
static __device__ __forceinline__ uint4 scale8(uint4 u, float w) {
  float f[8]; unpack8(u, f);
  uint4 o;
  o.x = (unsigned)f2bf(f[0] * w) | ((unsigned)f2bf(f[1] * w) << 16);
  o.y = (unsigned)f2bf(f[2] * w) | ((unsigned)f2bf(f[3] * w) << 16);
  o.z = (unsigned)f2bf(f[4] * w) | ((unsigned)f2bf(f[5] * w) << 16);
  o.w = (unsigned)f2bf(f[6] * w) | ((unsigned)f2bf(f[7] * w) << 16);
  return o;
}

// async global->LDS, 16B per lane. LDS dest is wave-uniform base + lane*16.
static __device__ __forceinline__ void glds16(const unsigned short* g, char* l) {
  __builtin_amdgcn_global_load_lds(
      (const __attribute__((address_space(1))) unsigned int*)g,
      (__attribute__((address_space(3))) unsigned int*)l, 16, 0, 0);
}

// Bijective XOR swizzle for reg-staged state_gemm tiles (64B rows).
static __device__ __forceinline__ int swz64(int row, int kb) { return ((row << 6) | kb) ^ ((row & 7) << 4); }

// ---------------- weight transpose + cast: out[c][r] = bf16(in[r][c]) ----------------
__global__ __launch_bounds__(256)
void transpose_cast(const float* __restrict__ in, unsigned short* __restrict__ out, int R, int Cc) {
  __shared__ float tile[32][33];
  const int r0 = blockIdx.y * 32, c0 = blockIdx.x * 32;
  const int tx = threadIdx.x, ty = threadIdx.y;
#pragma unroll
  for (int i = 0; i < 4; i++)
    tile[ty + i * 8][tx] = in[(size_t)(r0 + ty + i * 8) * Cc + c0 + tx];
  __syncthreads();
#pragma unroll
  for (int i = 0; i < 4; i++)
    out[(size_t)(c0 + ty + i * 8) * R + r0 + tx] = f2bf(tile[tx][ty + i * 8]);
}

// ---------------- RMSNorm (fp32 in -> bf16 out) ----------------
__global__ __launch_bounds__(256)
void rmsnorm_kernel(const float* __restrict__ x, const float* __restrict__ w,
                    unsigned short* __restrict__ out) {
  const int row = blockIdx.x, t = threadIdx.x;
  const float4 v = ((const float4*)(x + (size_t)row * DD))[t];
  float ss = v.x * v.x + v.y * v.y + v.z * v.z + v.w * v.w;
  __shared__ float sred[256];
  sred[t] = ss;
  __syncthreads();
  for (int o = 128; o > 0; o >>= 1) {
    if (t < o) sred[t] += sred[t + o];
    __syncthreads();
  }
  const float rr = rsqrtf(sred[0] * (1.0f / (float)DD) + 1e-5f);
  const float4 wv = ((const float4*)w)[t];
  uint2 pk;
  pk.x = (unsigned)f2bf(v.x * rr * wv.x) | ((unsigned)f2bf(v.y * rr * wv.y) << 16);
  pk.y = (unsigned)f2bf(v.z * rr * wv.z) | ((unsigned)f2bf(v.w * rr * wv.w) << 16);
  *(uint2*)(out + (size_t)row * DD + t * 4) = pk;
}

// ---------------- generic bf16 GEMM (m97-style gload_lds staging, linear LDS) ----------------
enum { EP_BF16 = 0, EP_BF16_BOTH = 1, EP_BF16_T = 2, EP_F32_RES = 3 };

template <int MODE>
__global__ __launch_bounds__(256)
void gemm_bt(const unsigned short* __restrict__ A, const unsigned short* __restrict__ Bt,
             unsigned short* __restrict__ Cb, unsigned short* __restrict__ Ct,
             float* __restrict__ Cf, const float* __restrict__ resid,
             int M, int N, int K, float scale) {
  __shared__ char sA[8192];   // [128 rows][32 cols] bf16, linear
  __shared__ char sB[8192];
  const int t = threadIdx.x, lane = t & 63, wid = t >> 6;
  const int wr = wid >> 1, wc = wid & 1;
  const int l15 = lane & 15, lh = lane >> 4;
  const int m0 = blockIdx.y * 128, n0 = blockIdx.x * 128;
  const int srow = wid * 16 + (lane >> 2), scol = (lane & 3) * 8;
  const unsigned short* Ar0 = A + (size_t)(m0 + srow) * K + scol;
  const unsigned short* Ar1 = A + (size_t)(m0 + 64 + srow) * K + scol;
  const unsigned short* Br0 = Bt + (size_t)(n0 + srow) * K + scol;
  const unsigned short* Br1 = Bt + (size_t)(n0 + 64 + srow) * K + scol;
  char* lA0 = sA + wid * 1024;
  char* lA1 = sA + 4096 + wid * 1024;
  char* lB0 = sB + wid * 1024;
  char* lB1 = sB + 4096 + wid * 1024;
  f32x4 acc[4][4] = {};
  for (int k0 = 0; k0 < K; k0 += 32) {
    glds16(Ar0 + k0, lA0);
    glds16(Ar1 + k0, lA1);
    glds16(Br0 + k0, lB0);
    glds16(Br1 + k0, lB1);
    __syncthreads();
    uint4 af[4], bfr[4];
#pragma unroll
    for (int i = 0; i < 4; i++) af[i]  = *(uint4*)(sA + (wr * 64 + i * 16 + l15) * 64 + lh * 16);
#pragma unroll
    for (int i = 0; i < 4; i++) bfr[i] = *(uint4*)(sB + (wc * 64 + i * 16 + l15) * 64 + lh * 16);
#pragma unroll
    for (int mf = 0; mf < 4; mf++)
#pragma unroll
      for (int nf = 0; nf < 4; nf++)
        acc[mf][nf] = MFMA(af[mf], bfr[nf], acc[mf][nf]);
    __syncthreads();
  }
#pragma unroll
  for (int mf = 0; mf < 4; mf++) {
    const int r0 = m0 + wr * 64 + mf * 16 + lh * 4;
#pragma unroll
    for (int nf = 0; nf < 4; nf++) {
      const int c = n0 + wc * 64 + nf * 16 + l15;
      f32x4 v = acc[mf][nf] * scale;
      if constexpr (MODE == EP_F32_RES) {
#pragma unroll
        for (int jj = 0; jj < 4; jj++) {
          const size_t idx = (size_t)(r0 + jj) * N + c;
          Cf[idx] = v[jj] + resid[idx];
        }
      } else {
        if constexpr (MODE == EP_BF16 || MODE == EP_BF16_BOTH) {
#pragma unroll
          for (int jj = 0; jj < 4; jj++)
            Cb[(size_t)(r0 + jj) * N + c] = f2bf(v[jj]);
        }
        if constexpr (MODE == EP_BF16_BOTH || MODE == EP_BF16_T) {
          // transposed store: Ct[b][c][s]  (requires N == DD)
          const int bb = r0 >> 13, s0 = r0 & (SS - 1);
          uint2 pk;
          pk.x = (unsigned)f2bf(v[0]) | ((unsigned)f2bf(v[1]) << 16);
          pk.y = (unsigned)f2bf(v[2]) | ((unsigned)f2bf(v[3]) << 16);
          *(uint2*)(Ct + ((size_t)bb * DD + c) * SS + s0) = pk;
        }
      }
    }
  }
}

// ---------------- causal depthwise conv (K=4) + SiLU, gate SiLU, multiply ----------------
__global__ __launch_bounds__(256)
void convgate_kernel(const unsigned short* __restrict__ ug, const float* __restrict__ cw,
                     const float* __restrict__ cb, unsigned short* __restrict__ hin) {
  const int r = blockIdx.x;          // global row (b*S + s)
  const int c0 = threadIdx.x * 8;    // channel base [0,2048)
  const int s = r & (SS - 1);
  float acc[8];
#pragma unroll
  for (int i = 0; i < 8; i++) acc[i] = cb[c0 + i];
  for (int tap = 0; tap < 4; tap++) {
    const int ds = s - 3 + tap;
    if (ds < 0) continue;
    uint4 uv = *(const uint4*)(ug + (size_t)(r - 3 + tap) * 4096 + c0);
    float u[8]; unpack8(uv, u);
#pragma unroll
    for (int i = 0; i < 8; i++) acc[i] += u[i] * cw[tap * DI2 + c0 + i];
  }
  uint4 gv = *(const uint4*)(ug + (size_t)r * 4096 + DI2 + c0);
  float gt[8]; unpack8(gv, gt);
  unsigned short o16[8];
#pragma unroll
  for (int i = 0; i < 8; i++) {
    const float val = acc[i] / (1.0f + __expf(-acc[i]));
    const float gg  = gt[i] / (1.0f + __expf(-gt[i]));
    o16[i] = f2bf(val * gg);
  }
  uint4 ov;
  ov.x = (unsigned)o16[0] | ((unsigned)o16[1] << 16);
  ov.y = (unsigned)o16[2] | ((unsigned)o16[3] << 16);
  ov.z = (unsigned)o16[4] | ((unsigned)o16[5] << 16);
  ov.w = (unsigned)o16[6] | ((unsigned)o16[7] << 16);
  *(uint4*)(hin + (size_t)r * DI2 + c0) = ov;
}

// ---------------- superchunk state: T[gb][e][dk] = sum_t 0.9^(15-t/64) V[t][e] K[t][dk] ----------------
__global__ __launch_bounds__(256)
void state_gemm(const unsigned short* __restrict__ vt, const unsigned short* __restrict__ kt,
                unsigned short* __restrict__ Tb) {
  __shared__ char sA[8192];
  __shared__ char sB[8192];
  const int t = threadIdx.x, lane = t & 63, wid = t >> 6;
  const int wr = wid >> 1, wc = wid & 1;
  const int l15 = lane & 15, lh = lane >> 4;
  const int gb = blockIdx.z, b = gb >> 3, g = gb & 7;
  const int m0 = blockIdx.y * 128, n0 = blockIdx.x * 128;
  const int sr = t >> 2, skb = (t & 3) * 16;
  const size_t kofs = (size_t)g * 1024;
  const unsigned short* Ar0 = vt + (size_t)(b * DD + m0 + sr) * SS + kofs;
  const unsigned short* Ar1 = Ar0 + (size_t)64 * SS;
  const unsigned short* Br0 = kt + (size_t)(b * DD + n0 + sr) * SS + kofs;
  const unsigned short* Br1 = Br0 + (size_t)64 * SS;
  f32x4 acc[4][4] = {};
  for (int k0 = 0; k0 < 1024; k0 += 32) {
    const int ke = k0 + (t & 3) * 8;
    const float w = exp2f((float)(15 - (ke >> 6)) * LOG2_09);
    uint4 ra0 = scale8(*(const uint4*)(Ar0 + ke), w);
    uint4 ra1 = scale8(*(const uint4*)(Ar1 + ke), w);
    uint4 rb0 = *(const uint4*)(Br0 + ke);
    uint4 rb1 = *(const uint4*)(Br1 + ke);
    __syncthreads();
    *(uint4*)(sA + swz64(sr, skb)) = ra0;
    *(uint4*)(sA + swz64(sr + 64, skb)) = ra1;
    *(uint4*)(sB + swz64(sr, skb)) = rb0;
    *(uint4*)(sB + swz64(sr + 64, skb)) = rb1;
    __syncthreads();
    uint4 af[4], bfr[4];
#pragma unroll
    for (int i = 0; i < 4; i++) af[i]  = *(uint4*)(sA + swz64(wr * 64 + i * 16 + l15, lh * 16));
#pragma unroll
    for (int i = 0; i < 4; i++) bfr[i] = *(uint4*)(sB + swz64(wc * 64 + i * 16 + l15, lh * 16));
#pragma unroll
    for (int mf = 0; mf < 4; mf++)
#pragma unroll
      for (int nf = 0; nf < 4; nf++)
        acc[mf][nf] = MFMA(af[mf], bfr[nf], acc[mf][nf]);
  }
  unsigned short* Tg = Tb + ((size_t)gb << 20);
#pragma unroll
  for (int mf = 0; mf < 4; mf++) {
    const int r0 = m0 + wr * 64 + mf * 16 + lh * 4;
#pragma unroll
    for (int nf = 0; nf < 4; nf++) {
      const int c = n0 + wc * 64 + nf * 16 + l15;
#pragma unroll
      for (int jj = 0; jj < 4; jj++)
        Tg[(size_t)(r0 + jj) * 1024 + c] = f2bf(acc[mf][nf][jj]);
    }
  }
}

// ---------------- superchunk prefix (in-place): Minit_g = 0.9^16 Minit_{g-1} + T_{g-1} ----------------
__global__ __launch_bounds__(256)
void prefix_kernel(unsigned short* __restrict__ Tb) {
  const int tid = blockIdx.x * 256 + threadIdx.x;  // 262144 threads
  const int b = tid >> 17, i = tid & 131071;
  unsigned short* p = Tb + (((size_t)b * 8) << 20) + (size_t)i * 8;
  float acc[8] = {};
  for (int g = 0; g < 8; g++) {
    unsigned short* pg = p + ((size_t)g << 20);
    uint4 tv = *(uint4*)pg;
    float tf_[8]; unpack8(tv, tf_);
    uint4 ov;
    ov.x = (unsigned)f2bf(acc[0]) | ((unsigned)f2bf(acc[1]) << 16);
    ov.y = (unsigned)f2bf(acc[2]) | ((unsigned)f2bf(acc[3]) << 16);
    ov.z = (unsigned)f2bf(acc[4]) | ((unsigned)f2bf(acc[5]) << 16);
    ov.w = (unsigned)f2bf(acc[6]) | ((unsigned)f2bf(acc[7]) << 16);
    *(uint4*)pg = ov;
#pragma unroll
    for (int e = 0; e < 8; e++) acc[e] = LAMBDA16 * acc[e] + tf_[e];
  }
}

// ---------------- score: S[qt-block][tb-block] = decay/tril-weighted Q K^T -> sbuf bf16 ----------------
// grid (136 pairs, 16 gb); block 4 waves, wave w = 16 q-rows. Balanced.
__global__ __launch_bounds__(256)
void score_attn(const unsigned short* __restrict__ q, const unsigned short* __restrict__ k,
                unsigned short* __restrict__ sbuf) {
  __shared__ char sQ[4096];  // [64][32] bf16 linear
  __shared__ char sK[4096];
  const int p = blockIdx.x, gb = blockIdx.y;
  int qt = (int)((sqrtf(8.0f * p + 1.0f) - 1.0f) * 0.5f);
  while ((qt + 1) * (qt + 2) / 2 <= p) qt++;
  while (qt * (qt + 1) / 2 > p) qt--;
  const int tb = p - qt * (qt + 1) / 2;
  const int b = gb >> 3, g = gb & 7;
  const int t = threadIdx.x, lane = t & 63, wid = t >> 6;
  const int l15 = lane & 15, lh = lane >> 4;
  const int srow = wid * 16 + (lane >> 2), scol = (lane & 3) * 8;
  const unsigned short* qg = q + (size_t)(b * SS + g * 1024 + qt * 64 + srow) * DD + scol;
  const unsigned short* kg = k + (size_t)(b * SS + g * 1024 + tb * 64 + srow) * DD + scol;
  char* lQ = sQ + wid * 1024;
  char* lK = sK + wid * 1024;
  f32x4 s[4] = {};
  for (int k0 = 0; k0 < DD; k0 += 32) {
    glds16(qg + k0, lQ);
    glds16(kg + k0, lK);
    __syncthreads();
    uint4 aq = *(uint4*)(sQ + (wid * 16 + l15) * 64 + lh * 16);
#pragma unroll
    for (int tf = 0; tf < 4; tf++) {
      uint4 bk = *(uint4*)(sK + (tf * 16 + l15) * 64 + lh * 16);
      s[tf] = MFMA(aq, bk, s[tf]);
    }
    __syncthreads();
  }
  const bool diag = (tb == qt);
  const float w = diag ? 1.0f : exp2f((float)(qt - 1 - tb) * LOG2_09);
  unsigned short* sb = sbuf + ((size_t)(gb * 16 + qt) * 64) * 1024 + tb * 64;
#pragma unroll
  for (int tf = 0; tf < 4; tf++)
#pragma unroll
    for (int jj = 0; jj < 4; jj++) {
      const int qr = wid * 16 + lh * 4 + jj;  // 0..63
      const int tc = tf * 16 + l15;           // 0..63
      float val = s[tf][jj] * w;
      if (diag && tc > qr) val = 0.0f;
      sb[(size_t)qr * 1024 + tc] = f2bf(val);
    }
}

// ---------------- pv: O[64 q-rows][128 e] = S_strip @ V  (k = (qt+1)*64) ----------------
// grid (8 et, 16 qt, 16 gb); block 4 waves, wave w = 32-e strip.
__global__ __launch_bounds__(256)
void pv_attn(const unsigned short* __restrict__ sbuf, const unsigned short* __restrict__ vt,
             unsigned short* __restrict__ obuf) {
  __shared__ char sA[4096];  // S [64][32] linear
  __shared__ char sB[8192];  // V [128 e][32 t] linear
  const int et = blockIdx.x, qt = blockIdx.y, gb = blockIdx.z;
  const int b = gb >> 3, g = gb & 7;
  const int t = threadIdx.x, lane = t & 63, wid = t >> 6;
  const int l15 = lane & 15, lh = lane >> 4;
  const int srow = wid * 16 + (lane >> 2), scol = (lane & 3) * 8;
  const int e0 = et * 128;
  const unsigned short* Ag = sbuf + ((size_t)(gb * 16 + qt) * 64 + srow) * 1024 + scol;
  const unsigned short* Bg0 = vt + ((size_t)b * DD + e0 + srow) * SS + g * 1024 + scol;
  const unsigned short* Bg1 = Bg0 + (size_t)64 * SS;
  char* lA  = sA + wid * 1024;
  char* lB0 = sB + wid * 1024;
  char* lB1 = sB + 4096 + wid * 1024;
  const int tEnd = (qt + 1) * 64;
  f32x4 o[4][2] = {};
  for (int t0 = 0; t0 < tEnd; t0 += 32) {
    glds16(Ag + t0, lA);
    glds16(Bg0 + t0, lB0);
    glds16(Bg1 + t0, lB1);
    __syncthreads();
    uint4 af[4], vf[2];
#pragma unroll
    for (int mf = 0; mf < 4; mf++) af[mf] = *(uint4*)(sA + (mf * 16 + l15) * 64 + lh * 16);
#pragma unroll
    for (int nf = 0; nf < 2; nf++) vf[nf] = *(uint4*)(sB + (wid * 32 + nf * 16 + l15) * 64 + lh * 16);
#pragma unroll
    for (int mf = 0; mf < 4; mf++)
#pragma unroll
      for (int nf = 0; nf < 2; nf++)
        o[mf][nf] = MFMA(af[mf], vf[nf], o[mf][nf]);
    __syncthreads();
  }
  const size_t qrow0 = (size_t)b * SS + (size_t)g * 1024 + (size_t)qt * 64;
#pragma unroll
  for (int mf = 0; mf < 4; mf++)
#pragma unroll
    for (int nf = 0; nf < 2; nf++)
#pragma unroll
      for (int jj = 0; jj < 4; jj++)
        obuf[(qrow0 + mf * 16 + lh * 4 + jj) * DD + e0 + wid * 32 + nf * 16 + l15] =
            f2bf(o[mf][nf][jj]);
}

// ---------------- cross term: obuf += 0.9^cl(row) * Q @ Minit_g ----------------
__global__ __launch_bounds__(256)
void cross_gemm(const unsigned short* __restrict__ q, const unsigned short* __restrict__ Minit,
                unsigned short* __restrict__ obuf) {
  __shared__ char sA[8192];
  __shared__ char sB[8192];
  const int t = threadIdx.x, lane = t & 63, wid = t >> 6;
  const int wr = wid >> 1, wc = wid & 1;
  const int l15 = lane & 15, lh = lane >> 4;
  const int gb = blockIdx.z, b = gb >> 3, g = gb & 7;
  const int m0 = blockIdx.y * 128, n0 = blockIdx.x * 128;
  const int srow = wid * 16 + (lane >> 2), scol = (lane & 3) * 8;
  const unsigned short* Ar0 = q + (size_t)(b * SS + g * 1024 + m0 + srow) * DD + scol;
  const unsigned short* Ar1 = Ar0 + (size_t)64 * DD;
  const unsigned short* Br0 = Minit + ((size_t)gb << 20) + (size_t)(n0 + srow) * 1024 + scol;
  const unsigned short* Br1 = Br0 + (size_t)64 * 1024;
  char* lA0 = sA + wid * 1024;
  char* lA1 = sA + 4096 + wid * 1024;
  char* lB0 = sB + wid * 1024;
  char* lB1 = sB + 4096 + wid * 1024;
  f32x4 acc[4][4] = {};
  for (int k0 = 0; k0 < 1024; k0 += 32) {
    glds16(Ar0 + k0, lA0);
    glds16(Ar1 + k0, lA1);
    glds16(Br0 + k0, lB0);
    glds16(Br1 + k0, lB1);
    __syncthreads();
    uint4 af[4], bfr[4];
#pragma unroll
    for (int i = 0; i < 4; i++) af[i]  = *(uint4*)(sA + (wr * 64 + i * 16 + l15) * 64 + lh * 16);
#pragma unroll
    for (int i = 0; i < 4; i++) bfr[i] = *(uint4*)(sB + (wc * 64 + i * 16 + l15) * 64 + lh * 16);
#pragma unroll
    for (int mf = 0; mf < 4; mf++)
#pragma unroll
      for (int nf = 0; nf < 4; nf++)
        acc[mf][nf] = MFMA(af[mf], bfr[nf], acc[mf][nf]);
    __syncthreads();
  }
#pragma unroll
  for (int mf = 0; mf < 4; mf++) {
    const int rl = m0 + wr * 64 + mf * 16 + lh * 4;  // row within superchunk [0,1024)
#pragma unroll
    for (int nf = 0; nf < 4; nf++) {
      const int c = n0 + wc * 64 + nf * 16 + l15;
#pragma unroll
      for (int jj = 0; jj < 4; jj++) {
        const int r = rl + jj;
        const float rs = exp2f((float)(r >> 6) * LOG2_09);  // 0.9^chunk-local
        const size_t idx = ((size_t)b * SS + (size_t)g * 1024 + r) * DD + c;
        obuf[idx] = f2bf(bf2f(obuf[idx]) + acc[mf][nf][jj] * rs);
      }
    }
  }
}

extern "C" void kernel_launch(void* const* d_in, const int* in_sizes, int n_in,
                              void* d_out, int out_size, void* d_ws, size_t ws_size,
                              hipStream_t stream) {
  (void)in_sizes; (void)n_in; (void)out_size;
  const float* x      = (const float*)d_in[0];
  const float* norm_w = (const float*)d_in[1];
  const float* w_up   = (const float*)d_in[2];
  const float* w_gate = (const float*)d_in[3];
  const float* w_down = (const float*)d_in[4];
  const float* conv_w = (const float*)d_in[5];
  const float* conv_b = (const float*)d_in[6];
  const float* wq     = (const float*)d_in[7];
  const float* wk     = (const float*)d_in[8];
  const float* wv     = (const float*)d_in[9];
  const float* wo     = (const float*)d_in[10];
  float* out = (float*)d_out;

  const size_t MB = 1ull << 20;
  // Aliased workspace plan (212 MiB). Lifetimes:
  //   [0,32M)    ug -> hbuf -> Tbuf (after QKV gemms)
  //   [32,64M)   ug -> qbuf
  //   [64,96M)   ug -> kbuf
  //   [96,128M)  ug -> ktbuf -> sbuf (after state_gemm)
  //   [128,160M) normed -> hin -> vtbuf
  //   [160,192M) hin tail -> obuf
  //   [192,212M) weight transposes
  if (ws_size < 212 * MB) return;
  char* base = (char*)d_ws;
  unsigned short* ug     = (unsigned short*)(base + 0);
  unsigned short* hbuf   = (unsigned short*)(base + 0);
  unsigned short* Tbuf   = (unsigned short*)(base + 0);
  unsigned short* qbuf   = (unsigned short*)(base + 32 * MB);
  unsigned short* kbuf   = (unsigned short*)(base + 64 * MB);
  unsigned short* ktbuf  = (unsigned short*)(base + 96 * MB);
  unsigned short* sbuf   = (unsigned short*)(base + 96 * MB);
  unsigned short* normed = (unsigned short*)(base + 128 * MB);
  unsigned short* hin    = (unsigned short*)(base + 128 * MB);
  unsigned short* vtbuf  = (unsigned short*)(base + 128 * MB);
  unsigned short* obuf   = (unsigned short*)(base + 160 * MB);
  unsigned short* wugt   = (unsigned short*)(base + 192 * MB);
  unsigned short* wdt    = (unsigned short*)(base + 200 * MB);
  unsigned short* wqt    = (unsigned short*)(base + 204 * MB);
  unsigned short* wkt    = (unsigned short*)(base + 206 * MB);
  unsigned short* wvt    = (unsigned short*)(base + 208 * MB);
  unsigned short* wot    = (unsigned short*)(base + 210 * MB);

  dim3 tb(32, 8);
  transpose_cast<<<dim3(DI2 / 32, DD / 32), tb, 0, stream>>>(w_up,   wugt,                    DD,  DI2);
  transpose_cast<<<dim3(DI2 / 32, DD / 32), tb, 0, stream>>>(w_gate, wugt + (size_t)DI2 * DD, DD,  DI2);
  transpose_cast<<<dim3(DD / 32, DI2 / 32), tb, 0, stream>>>(w_down, wdt, DI2, DD);
  transpose_cast<<<dim3(DD / 32, DD / 32),  tb, 0, stream>>>(wq, wqt, DD, DD);
  transpose_cast<<<dim3(DD / 32, DD / 32),  tb, 0, stream>>>(wk, wkt, DD, DD);
  transpose_cast<<<dim3(DD / 32, DD / 32),  tb, 0, stream>>>(wv, wvt, DD, DD);
  transpose_cast<<<dim3(DD / 32, DD / 32),  tb, 0, stream>>>(wo, wot, DD, DD);

  rmsnorm_kernel<<<NR, 256, 0, stream>>>(x, norm_w, normed);

  gemm_bt<EP_BF16><<<dim3(4096 / 128, NR / 128), 256, 0, stream>>>(
      normed, wugt, ug, nullptr, nullptr, nullptr, NR, 4096, DD, 1.0f);

  convgate_kernel<<<NR, 256, 0, stream>>>(ug, conv_w, conv_b, hin);

  gemm_bt<EP_BF16><<<dim3(DD / 128, NR / 128), 256, 0, stream>>>(
      hin, wdt, hbuf, nullptr, nullptr, nullptr, NR, DD, DI2, 1.0f);

  gemm_bt<EP_BF16><<<dim3(DD / 128, NR / 128), 256, 0, stream>>>(
      hbuf, wqt, qbuf, nullptr, nullptr, nullptr, NR, DD, DD, 0.03125f);
  gemm_bt<EP_BF16_BOTH><<<dim3(DD / 128, NR / 128), 256, 0, stream>>>(
      hbuf, wkt, kbuf, ktbuf, nullptr, nullptr, NR, DD, DD, 1.0f);
  gemm_bt<EP_BF16_T><<<dim3(DD / 128, NR / 128), 256, 0, stream>>>(
      hbuf, wvt, nullptr, vtbuf, nullptr, nullptr, NR, DD, DD, 1.0f);

  // Hebbian memory via superchunk decomposition (16 chunks / superchunk):
  state_gemm<<<dim3(8, 8, 16), 256, 0, stream>>>(vtbuf, ktbuf, Tbuf);   // uses ktbuf, then dead
  score_attn<<<dim3(136, 16), 256, 0, stream>>>(qbuf, kbuf, sbuf);      // sbuf overlays ktbuf
  prefix_kernel<<<1024, 256, 0, stream>>>(Tbuf);
  pv_attn<<<dim3(8, 16, 16), 256, 0, stream>>>(sbuf, vtbuf, obuf);
  cross_gemm<<<dim3(8, 8, 16), 256, 0, stream>>>(qbuf, Tbuf, obuf);

  // out = obuf @ wo + x
  gemm_bt<EP_F32_RES><<<dim3(DD / 128, NR / 128), 256, 0, stream>>>(
      obuf, wot, nullptr, nullptr, out, x, NR, DD, DD, 1.0f);
}

// Round 5
// 845.985 us; speedup vs baseline: 2.5834x; 1.1109x over previous
//
#include <hip/hip_runtime.h>
#include <cstdint>
#include <cstddef>

#define SS 8192
#define DD 1024
#define DI2 2048
#define NR 16384   // B*S

#define LOG2_09 (-0.152003093445050f)   // log2(0.9)
#define LAMBDA16 0.185302018885184f     // 0.9^16

typedef __attribute__((ext_vector_type(4))) float f32x4;
typedef __attribute__((ext_vector_type(8))) __bf16 bf16x8;

union U16 { uint4 u; bf16x8 b; };

static __device__ __forceinline__ f32x4 MFMA(uint4 a, uint4 b, f32x4 c) {
  U16 ua, ub; ua.u = a; ub.u = b;
  return __builtin_amdgcn_mfma_f32_16x16x32_bf16(ua.b, ub.b, c, 0, 0, 0);
}

static __device__ __forceinline__ unsigned short f2bf(float f) {
  union { float f; unsigned u; } v; v.f = f;
  return (unsigned short)((v.u + 0x7FFFu + ((v.u >> 16) & 1u)) >> 16);
}
static __device__ __forceinline__ float bf2f(unsigned b) {
  union { unsigned u; float f; } v; v.u = b << 16; return v.f;
}
static __device__ __forceinline__ void unpack8(uint4 u, float* f) {
  f[0] = bf2f(u.x & 0xFFFFu); f[1] = bf2f(u.x >> 16);
  f[2] = bf2f(u.y & 0xFFFFu); f[3] = bf2f(u.y >> 16);
  f[4] = bf2f(u.z & 0xFFFFu); f[5] = bf2f(u.z >> 16);
  f[6] = bf2f(u.w & 0xFFFFu); f[7] = bf2f(u.w >> 16);
}
static __device__ __forceinline__ uint4 scale8(uint4 u, float w) {
  float f[8]; unpack8(u, f);
  uint4 o;
  o.x = (unsigned)f2bf(f[0] * w) | ((unsigned)f2bf(f[1] * w) << 16);
  o.y = (unsigned)f2bf(f[2] * w) | ((unsigned)f2bf(f[3] * w) << 16);
  o.z = (unsigned)f2bf(f[4] * w) | ((unsigned)f2bf(f[5] * w) << 16);
  o.w = (unsigned)f2bf(f[6] * w) | ((unsigned)f2bf(f[7] * w) << 16);
  return o;
}

// async global->LDS, 16B per lane. LDS dest is wave-uniform base + lane*16.
static __device__ __forceinline__ void glds16(const unsigned short* g, char* l) {
  __builtin_amdgcn_global_load_lds(
      (const __attribute__((address_space(1))) unsigned int*)g,
      (__attribute__((address_space(3))) unsigned int*)l, 16, 0, 0);
}

// Bijective XOR swizzle for reg-staged state_gemm tiles (64B rows).
static __device__ __forceinline__ int swz64(int row, int kb) { return ((row << 6) | kb) ^ ((row & 7) << 4); }

// ---------------- weight transpose + cast: out[c][r] = bf16(in[r][c]) ----------------
__global__ __launch_bounds__(256)
void transpose_cast(const float* __restrict__ in, unsigned short* __restrict__ out, int R, int Cc) {
  __shared__ float tile[32][33];
  const int r0 = blockIdx.y * 32, c0 = blockIdx.x * 32;
  const int tx = threadIdx.x, ty = threadIdx.y;
#pragma unroll
  for (int i = 0; i < 4; i++)
    tile[ty + i * 8][tx] = in[(size_t)(r0 + ty + i * 8) * Cc + c0 + tx];
  __syncthreads();
#pragma unroll
  for (int i = 0; i < 4; i++)
    out[(size_t)(c0 + ty + i * 8) * R + r0 + tx] = f2bf(tile[tx][ty + i * 8]);
}

// ---------------- RMSNorm (fp32 in -> bf16 out) ----------------
__global__ __launch_bounds__(256)
void rmsnorm_kernel(const float* __restrict__ x, const float* __restrict__ w,
                    unsigned short* __restrict__ out) {
  const int row = blockIdx.x, t = threadIdx.x;
  const float4 v = ((const float4*)(x + (size_t)row * DD))[t];
  float ss = v.x * v.x + v.y * v.y + v.z * v.z + v.w * v.w;
  __shared__ float sred[256];
  sred[t] = ss;
  __syncthreads();
  for (int o = 128; o > 0; o >>= 1) {
    if (t < o) sred[t] += sred[t + o];
    __syncthreads();
  }
  const float rr = rsqrtf(sred[0] * (1.0f / (float)DD) + 1e-5f);
  const float4 wv = ((const float4*)w)[t];
  uint2 pk;
  pk.x = (unsigned)f2bf(v.x * rr * wv.x) | ((unsigned)f2bf(v.y * rr * wv.y) << 16);
  pk.y = (unsigned)f2bf(v.z * rr * wv.z) | ((unsigned)f2bf(v.w * rr * wv.w) << 16);
  *(uint2*)(out + (size_t)row * DD + t * 4) = pk;
}

// ---------------- 256x256-tile deep-pipelined bf16 GEMM: C = A[M][K] @ Bt[N][K]^T ----------------
// 8 waves (512 thr), wave grid 2M x 4N (128x64 out/wave). BK=32, quadruple-buffered LDS
// (4 x (A 16KB + B 16KB) = 128KB). Counted vmcnt(8): tiles t+1,t+2 always in flight.
// T2 swizzle: linear gload_lds dest + inverse-swizzled global source col + swizzled ds_read.
enum { EP_BF16 = 0, EP_BF16_BOTH = 1, EP_BF16_T = 2, EP_F32_RES = 3 };

template <int MODE>
__global__ __launch_bounds__(512, 2)
void gemm256(const unsigned short* __restrict__ A, const unsigned short* __restrict__ Bt,
             unsigned short* __restrict__ Cb, unsigned short* __restrict__ Ct,
             float* __restrict__ Cf, const float* __restrict__ resid,
             int M, int N, int K, float scale) {
  __shared__ char sLds[131072];
  const int t = threadIdx.x, lane = t & 63, wid = t >> 6;
  const int wr = wid >> 2, wc = wid & 3;
  const int l15 = lane & 15, lh = lane >> 4;
  // XCD-aware bijective block swizzle (nwg % 8 == 0 for all our launches)
  const int nwg = gridDim.x;
  const int swz = ((int)blockIdx.x & 7) * (nwg >> 3) + ((int)blockIdx.x >> 3);
  const int mblocks = M >> 8;
  const int m0 = (swz % mblocks) << 8, n0 = (swz / mblocks) << 8;
  // staging source (inverse swizzle on the global column)
  const int srow = wid * 16 + (lane >> 2);                          // 0..127 within half
  const int scol = ((lane & 3) << 3) ^ (((srow >> 1) & 3) << 3);   // bf16 elems
  const unsigned short* pA0 = A + (size_t)(m0 + srow) * K + scol;
  const unsigned short* pA1 = pA0 + (size_t)128 * K;
  const unsigned short* pB0 = Bt + (size_t)(n0 + srow) * K + scol;
  const unsigned short* pB1 = pB0 + (size_t)128 * K;
  const int ldsW = wid * 1024;
  // swizzled read offsets (iteration-invariant)
  int offA[8], offB[4];
#pragma unroll
  for (int mf = 0; mf < 8; mf++) {
    const int r = wr * 128 + mf * 16 + l15;
    offA[mf] = r * 64 + ((lh * 16) ^ (((r >> 1) & 3) << 4));
  }
#pragma unroll
  for (int nf = 0; nf < 4; nf++) {
    const int r = wc * 64 + nf * 16 + l15;
    offB[nf] = r * 64 + ((lh * 16) ^ (((r >> 1) & 3) << 4));
  }
  const int NT = K >> 5;
#define BUFA(tt) (sLds + ((tt) & 3) * 32768)
#define BUFB(tt) (sLds + ((tt) & 3) * 32768 + 16384)
#define STAGE(tt) do { const int _k = (tt) * 32; \
    glds16(pA0 + _k, BUFA(tt) + ldsW); \
    glds16(pA1 + _k, BUFA(tt) + 8192 + ldsW); \
    glds16(pB0 + _k, BUFB(tt) + ldsW); \
    glds16(pB1 + _k, BUFB(tt) + 8192 + ldsW); } while (0)
  STAGE(0); STAGE(1); STAGE(2);
  f32x4 acc[8][4] = {};
  for (int kt = 0; kt < NT; ++kt) {
    // counted waits: own loads for tile kt done; tiles kt+1, kt+2 stay in flight
    asm volatile("s_waitcnt lgkmcnt(0)" ::: "memory");
    if (kt < NT - 2)       asm volatile("s_waitcnt vmcnt(8)" ::: "memory");
    else if (kt == NT - 2) asm volatile("s_waitcnt vmcnt(4)" ::: "memory");
    else                   asm volatile("s_waitcnt vmcnt(0)" ::: "memory");
    __builtin_amdgcn_s_barrier();
    asm volatile("" ::: "memory");  // compile fence: nothing hoists above the barrier
    if (kt + 3 < NT) STAGE(kt + 3);  // buf (kt+3)&3 == (kt-1)&3: last read pre-barrier
    const char* At  = BUFA(kt);
    const char* Bt_ = BUFB(kt);
    uint4 av[8], bv[4];
#pragma unroll
    for (int mf = 0; mf < 8; mf++) av[mf] = *(const uint4*)(At + offA[mf]);
#pragma unroll
    for (int nf = 0; nf < 4; nf++) bv[nf] = *(const uint4*)(Bt_ + offB[nf]);
    __builtin_amdgcn_s_setprio(1);
#pragma unroll
    for (int mf = 0; mf < 8; mf++)
#pragma unroll
      for (int nf = 0; nf < 4; nf++)
        acc[mf][nf] = MFMA(av[mf], bv[nf], acc[mf][nf]);
    __builtin_amdgcn_s_setprio(0);
  }
#undef STAGE
#undef BUFA
#undef BUFB
#pragma unroll
  for (int mf = 0; mf < 8; mf++) {
    const int r0 = m0 + wr * 128 + mf * 16 + lh * 4;
#pragma unroll
    for (int nf = 0; nf < 4; nf++) {
      const int c = n0 + wc * 64 + nf * 16 + l15;
      f32x4 v = acc[mf][nf] * scale;
      if constexpr (MODE == EP_F32_RES) {
#pragma unroll
        for (int jj = 0; jj < 4; jj++) {
          const size_t idx = (size_t)(r0 + jj) * N + c;
          Cf[idx] = v[jj] + resid[idx];
        }
      } else {
        if constexpr (MODE == EP_BF16 || MODE == EP_BF16_BOTH) {
#pragma unroll
          for (int jj = 0; jj < 4; jj++)
            Cb[(size_t)(r0 + jj) * N + c] = f2bf(v[jj]);
        }
        if constexpr (MODE == EP_BF16_BOTH || MODE == EP_BF16_T) {
          // transposed store: Ct[b][c][s]  (requires N == DD)
          const int bb = r0 >> 13, s0 = r0 & (SS - 1);
          uint2 pk;
          pk.x = (unsigned)f2bf(v[0]) | ((unsigned)f2bf(v[1]) << 16);
          pk.y = (unsigned)f2bf(v[2]) | ((unsigned)f2bf(v[3]) << 16);
          *(uint2*)(Ct + ((size_t)bb * DD + c) * SS + s0) = pk;
        }
      }
    }
  }
}

// ---------------- causal depthwise conv (K=4) + SiLU, gate SiLU, multiply ----------------
__global__ __launch_bounds__(256)
void convgate_kernel(const unsigned short* __restrict__ ug, const float* __restrict__ cw,
                     const float* __restrict__ cb, unsigned short* __restrict__ hin) {
  const int r = blockIdx.x;          // global row (b*S + s)
  const int c0 = threadIdx.x * 8;    // channel base [0,2048)
  const int s = r & (SS - 1);
  float acc[8];
#pragma unroll
  for (int i = 0; i < 8; i++) acc[i] = cb[c0 + i];
  for (int tap = 0; tap < 4; tap++) {
    const int ds = s - 3 + tap;
    if (ds < 0) continue;
    uint4 uv = *(const uint4*)(ug + (size_t)(r - 3 + tap) * 4096 + c0);
    float u[8]; unpack8(uv, u);
#pragma unroll
    for (int i = 0; i < 8; i++) acc[i] += u[i] * cw[tap * DI2 + c0 + i];
  }
  uint4 gv = *(const uint4*)(ug + (size_t)r * 4096 + DI2 + c0);
  float gt[8]; unpack8(gv, gt);
  unsigned short o16[8];
#pragma unroll
  for (int i = 0; i < 8; i++) {
    const float val = acc[i] / (1.0f + __expf(-acc[i]));
    const float gg  = gt[i] / (1.0f + __expf(-gt[i]));
    o16[i] = f2bf(val * gg);
  }
  uint4 ov;
  ov.x = (unsigned)o16[0] | ((unsigned)o16[1] << 16);
  ov.y = (unsigned)o16[2] | ((unsigned)o16[3] << 16);
  ov.z = (unsigned)o16[4] | ((unsigned)o16[5] << 16);
  ov.w = (unsigned)o16[6] | ((unsigned)o16[7] << 16);
  *(uint4*)(hin + (size_t)r * DI2 + c0) = ov;
}

// ---------------- superchunk state: T[gb][e][dk] = sum_t 0.9^(15-t/64) V[t][e] K[t][dk] ----------------
__global__ __launch_bounds__(256)
void state_gemm(const unsigned short* __restrict__ vt, const unsigned short* __restrict__ kt,
                unsigned short* __restrict__ Tb) {
  __shared__ char sA[8192];
  __shared__ char sB[8192];
  const int t = threadIdx.x, lane = t & 63, wid = t >> 6;
  const int wr = wid >> 1, wc = wid & 1;
  const int l15 = lane & 15, lh = lane >> 4;
  const int gb = blockIdx.z, b = gb >> 3, g = gb & 7;
  const int m0 = blockIdx.y * 128, n0 = blockIdx.x * 128;
  const int sr = t >> 2, skb = (t & 3) * 16;
  const size_t kofs = (size_t)g * 1024;
  const unsigned short* Ar0 = vt + (size_t)(b * DD + m0 + sr) * SS + kofs;
  const unsigned short* Ar1 = Ar0 + (size_t)64 * SS;
  const unsigned short* Br0 = kt + (size_t)(b * DD + n0 + sr) * SS + kofs;
  const unsigned short* Br1 = Br0 + (size_t)64 * SS;
  f32x4 acc[4][4] = {};
  for (int k0 = 0; k0 < 1024; k0 += 32) {
    const int ke = k0 + (t & 3) * 8;
    const float w = exp2f((float)(15 - (ke >> 6)) * LOG2_09);
    uint4 ra0 = scale8(*(const uint4*)(Ar0 + ke), w);
    uint4 ra1 = scale8(*(const uint4*)(Ar1 + ke), w);
    uint4 rb0 = *(const uint4*)(Br0 + ke);
    uint4 rb1 = *(const uint4*)(Br1 + ke);
    __syncthreads();
    *(uint4*)(sA + swz64(sr, skb)) = ra0;
    *(uint4*)(sA + swz64(sr + 64, skb)) = ra1;
    *(uint4*)(sB + swz64(sr, skb)) = rb0;
    *(uint4*)(sB + swz64(sr + 64, skb)) = rb1;
    __syncthreads();
    uint4 af[4], bfr[4];
#pragma unroll
    for (int i = 0; i < 4; i++) af[i]  = *(uint4*)(sA + swz64(wr * 64 + i * 16 + l15, lh * 16));
#pragma unroll
    for (int i = 0; i < 4; i++) bfr[i] = *(uint4*)(sB + swz64(wc * 64 + i * 16 + l15, lh * 16));
#pragma unroll
    for (int mf = 0; mf < 4; mf++)
#pragma unroll
      for (int nf = 0; nf < 4; nf++)
        acc[mf][nf] = MFMA(af[mf], bfr[nf], acc[mf][nf]);
  }
  unsigned short* Tg = Tb + ((size_t)gb << 20);
#pragma unroll
  for (int mf = 0; mf < 4; mf++) {
    const int r0 = m0 + wr * 64 + mf * 16 + lh * 4;
#pragma unroll
    for (int nf = 0; nf < 4; nf++) {
      const int c = n0 + wc * 64 + nf * 16 + l15;
#pragma unroll
      for (int jj = 0; jj < 4; jj++)
        Tg[(size_t)(r0 + jj) * 1024 + c] = f2bf(acc[mf][nf][jj]);
    }
  }
}

// ---------------- superchunk prefix (in-place): Minit_g = 0.9^16 Minit_{g-1} + T_{g-1} ----------------
__global__ __launch_bounds__(256)
void prefix_kernel(unsigned short* __restrict__ Tb) {
  const int tid = blockIdx.x * 256 + threadIdx.x;  // 262144 threads
  const int b = tid >> 17, i = tid & 131071;
  unsigned short* p = Tb + (((size_t)b * 8) << 20) + (size_t)i * 8;
  float acc[8] = {};
  for (int g = 0; g < 8; g++) {
    unsigned short* pg = p + ((size_t)g << 20);
    uint4 tv = *(uint4*)pg;
    float tf_[8]; unpack8(tv, tf_);
    uint4 ov;
    ov.x = (unsigned)f2bf(acc[0]) | ((unsigned)f2bf(acc[1]) << 16);
    ov.y = (unsigned)f2bf(acc[2]) | ((unsigned)f2bf(acc[3]) << 16);
    ov.z = (unsigned)f2bf(acc[4]) | ((unsigned)f2bf(acc[5]) << 16);
    ov.w = (unsigned)f2bf(acc[6]) | ((unsigned)f2bf(acc[7]) << 16);
    *(uint4*)pg = ov;
#pragma unroll
    for (int e = 0; e < 8; e++) acc[e] = LAMBDA16 * acc[e] + tf_[e];
  }
}

// ---------------- score: S[qt-block][tb-block] = decay/tril-weighted Q K^T -> sbuf bf16 ----------------
__global__ __launch_bounds__(256)
void score_attn(const unsigned short* __restrict__ q, const unsigned short* __restrict__ k,
                unsigned short* __restrict__ sbuf) {
  __shared__ char sQ[4096];  // [64][32] bf16 linear
  __shared__ char sK[4096];
  const int p = blockIdx.x, gb = blockIdx.y;
  int qt = (int)((sqrtf(8.0f * p + 1.0f) - 1.0f) * 0.5f);
  while ((qt + 1) * (qt + 2) / 2 <= p) qt++;
  while (qt * (qt + 1) / 2 > p) qt--;
  const int tb = p - qt * (qt + 1) / 2;
  const int b = gb >> 3, g = gb & 7;
  const int t = threadIdx.x, lane = t & 63, wid = t >> 6;
  const int l15 = lane & 15, lh = lane >> 4;
  const int srow = wid * 16 + (lane >> 2), scol = (lane & 3) * 8;
  const unsigned short* qg = q + (size_t)(b * SS + g * 1024 + qt * 64 + srow) * DD + scol;
  const unsigned short* kg = k + (size_t)(b * SS + g * 1024 + tb * 64 + srow) * DD + scol;
  char* lQ = sQ + wid * 1024;
  char* lK = sK + wid * 1024;
  f32x4 s[4] = {};
  for (int k0 = 0; k0 < DD; k0 += 32) {
    glds16(qg + k0, lQ);
    glds16(kg + k0, lK);
    __syncthreads();
    uint4 aq = *(uint4*)(sQ + (wid * 16 + l15) * 64 + lh * 16);
#pragma unroll
    for (int tf = 0; tf < 4; tf++) {
      uint4 bk = *(uint4*)(sK + (tf * 16 + l15) * 64 + lh * 16);
      s[tf] = MFMA(aq, bk, s[tf]);
    }
    __syncthreads();
  }
  const bool diag = (tb == qt);
  const float w = diag ? 1.0f : exp2f((float)(qt - 1 - tb) * LOG2_09);
  unsigned short* sb = sbuf + ((size_t)(gb * 16 + qt) * 64) * 1024 + tb * 64;
#pragma unroll
  for (int tf = 0; tf < 4; tf++)
#pragma unroll
    for (int jj = 0; jj < 4; jj++) {
      const int qr = wid * 16 + lh * 4 + jj;  // 0..63
      const int tc = tf * 16 + l15;           // 0..63
      float val = s[tf][jj] * w;
      if (diag && tc > qr) val = 0.0f;
      sb[(size_t)qr * 1024 + tc] = f2bf(val);
    }
}

// ---------------- pv: O[64 q-rows][128 e] = S_strip @ V  (k = (qt+1)*64) ----------------
__global__ __launch_bounds__(256)
void pv_attn(const unsigned short* __restrict__ sbuf, const unsigned short* __restrict__ vt,
             unsigned short* __restrict__ obuf) {
  __shared__ char sA[4096];  // S [64][32] linear
  __shared__ char sB[8192];  // V [128 e][32 t] linear
  const int et = blockIdx.x, qt = blockIdx.y, gb = blockIdx.z;
  const int b = gb >> 3, g = gb & 7;
  const int t = threadIdx.x, lane = t & 63, wid = t >> 6;
  const int l15 = lane & 15, lh = lane >> 4;
  const int srow = wid * 16 + (lane >> 2), scol = (lane & 3) * 8;
  const int e0 = et * 128;
  const unsigned short* Ag = sbuf + ((size_t)(gb * 16 + qt) * 64 + srow) * 1024 + scol;
  const unsigned short* Bg0 = vt + ((size_t)b * DD + e0 + srow) * SS + g * 1024 + scol;
  const unsigned short* Bg1 = Bg0 + (size_t)64 * SS;
  char* lA  = sA + wid * 1024;
  char* lB0 = sB + wid * 1024;
  char* lB1 = sB + 4096 + wid * 1024;
  const int tEnd = (qt + 1) * 64;
  f32x4 o[4][2] = {};
  for (int t0 = 0; t0 < tEnd; t0 += 32) {
    glds16(Ag + t0, lA);
    glds16(Bg0 + t0, lB0);
    glds16(Bg1 + t0, lB1);
    __syncthreads();
    uint4 af[4], vf[2];
#pragma unroll
    for (int mf = 0; mf < 4; mf++) af[mf] = *(uint4*)(sA + (mf * 16 + l15) * 64 + lh * 16);
#pragma unroll
    for (int nf = 0; nf < 2; nf++) vf[nf] = *(uint4*)(sB + (wid * 32 + nf * 16 + l15) * 64 + lh * 16);
#pragma unroll
    for (int mf = 0; mf < 4; mf++)
#pragma unroll
      for (int nf = 0; nf < 2; nf++)
        o[mf][nf] = MFMA(af[mf], vf[nf], o[mf][nf]);
    __syncthreads();
  }
  const size_t qrow0 = (size_t)b * SS + (size_t)g * 1024 + (size_t)qt * 64;
#pragma unroll
  for (int mf = 0; mf < 4; mf++)
#pragma unroll
    for (int nf = 0; nf < 2; nf++)
#pragma unroll
      for (int jj = 0; jj < 4; jj++)
        obuf[(qrow0 + mf * 16 + lh * 4 + jj) * DD + e0 + wid * 32 + nf * 16 + l15] =
            f2bf(o[mf][nf][jj]);
}

// ---------------- cross term: obuf += 0.9^cl(row) * Q @ Minit_g ----------------
__global__ __launch_bounds__(256)
void cross_gemm(const unsigned short* __restrict__ q, const unsigned short* __restrict__ Minit,
                unsigned short* __restrict__ obuf) {
  __shared__ char sA[8192];
  __shared__ char sB[8192];
  const int t = threadIdx.x, lane = t & 63, wid = t >> 6;
  const int wr = wid >> 1, wc = wid & 1;
  const int l15 = lane & 15, lh = lane >> 4;
  const int gb = blockIdx.z, b = gb >> 3, g = gb & 7;
  const int m0 = blockIdx.y * 128, n0 = blockIdx.x * 128;
  const int srow = wid * 16 + (lane >> 2), scol = (lane & 3) * 8;
  const unsigned short* Ar0 = q + (size_t)(b * SS + g * 1024 + m0 + srow) * DD + scol;
  const unsigned short* Ar1 = Ar0 + (size_t)64 * DD;
  const unsigned short* Br0 = Minit + ((size_t)gb << 20) + (size_t)(n0 + srow) * 1024 + scol;
  const unsigned short* Br1 = Br0 + (size_t)64 * 1024;
  char* lA0 = sA + wid * 1024;
  char* lA1 = sA + 4096 + wid * 1024;
  char* lB0 = sB + wid * 1024;
  char* lB1 = sB + 4096 + wid * 1024;
  f32x4 acc[4][4] = {};
  for (int k0 = 0; k0 < 1024; k0 += 32) {
    glds16(Ar0 + k0, lA0);
    glds16(Ar1 + k0, lA1);
    glds16(Br0 + k0, lB0);
    glds16(Br1 + k0, lB1);
    __syncthreads();
    uint4 af[4], bfr[4];
#pragma unroll
    for (int i = 0; i < 4; i++) af[i]  = *(uint4*)(sA + (wr * 64 + i * 16 + l15) * 64 + lh * 16);
#pragma unroll
    for (int i = 0; i < 4; i++) bfr[i] = *(uint4*)(sB + (wc * 64 + i * 16 + l15) * 64 + lh * 16);
#pragma unroll
    for (int mf = 0; mf < 4; mf++)
#pragma unroll
      for (int nf = 0; nf < 4; nf++)
        acc[mf][nf] = MFMA(af[mf], bfr[nf], acc[mf][nf]);
    __syncthreads();
  }
#pragma unroll
  for (int mf = 0; mf < 4; mf++) {
    const int rl = m0 + wr * 64 + mf * 16 + lh * 4;  // row within superchunk [0,1024)
#pragma unroll
    for (int nf = 0; nf < 4; nf++) {
      const int c = n0 + wc * 64 + nf * 16 + l15;
#pragma unroll
      for (int jj = 0; jj < 4; jj++) {
        const int r = rl + jj;
        const float rs = exp2f((float)(r >> 6) * LOG2_09);  // 0.9^chunk-local
        const size_t idx = ((size_t)b * SS + (size_t)g * 1024 + r) * DD + c;
        obuf[idx] = f2bf(bf2f(obuf[idx]) + acc[mf][nf][jj] * rs);
      }
    }
  }
}

extern "C" void kernel_launch(void* const* d_in, const int* in_sizes, int n_in,
                              void* d_out, int out_size, void* d_ws, size_t ws_size,
                              hipStream_t stream) {
  (void)in_sizes; (void)n_in; (void)out_size;
  const float* x      = (const float*)d_in[0];
  const float* norm_w = (const float*)d_in[1];
  const float* w_up   = (const float*)d_in[2];
  const float* w_gate = (const float*)d_in[3];
  const float* w_down = (const float*)d_in[4];
  const float* conv_w = (const float*)d_in[5];
  const float* conv_b = (const float*)d_in[6];
  const float* wq     = (const float*)d_in[7];
  const float* wk     = (const float*)d_in[8];
  const float* wv     = (const float*)d_in[9];
  const float* wo     = (const float*)d_in[10];
  float* out = (float*)d_out;

  const size_t MB = 1ull << 20;
  // Aliased workspace plan (212 MiB). Lifetimes:
  //   [0,32M)    ug -> hbuf -> Tbuf (after QKV gemms)
  //   [32,64M)   ug -> qbuf
  //   [64,96M)   ug -> kbuf
  //   [96,128M)  ug -> ktbuf -> sbuf (after state_gemm)
  //   [128,160M) normed -> hin -> vtbuf
  //   [160,192M) hin tail -> obuf
  //   [192,212M) weight transposes
  if (ws_size < 212 * MB) return;
  char* base = (char*)d_ws;
  unsigned short* ug     = (unsigned short*)(base + 0);
  unsigned short* hbuf   = (unsigned short*)(base + 0);
  unsigned short* Tbuf   = (unsigned short*)(base + 0);
  unsigned short* qbuf   = (unsigned short*)(base + 32 * MB);
  unsigned short* kbuf   = (unsigned short*)(base + 64 * MB);
  unsigned short* ktbuf  = (unsigned short*)(base + 96 * MB);
  unsigned short* sbuf   = (unsigned short*)(base + 96 * MB);
  unsigned short* normed = (unsigned short*)(base + 128 * MB);
  unsigned short* hin    = (unsigned short*)(base + 128 * MB);
  unsigned short* vtbuf  = (unsigned short*)(base + 128 * MB);
  unsigned short* obuf   = (unsigned short*)(base + 160 * MB);
  unsigned short* wugt   = (unsigned short*)(base + 192 * MB);
  unsigned short* wdt    = (unsigned short*)(base + 200 * MB);
  unsigned short* wqt    = (unsigned short*)(base + 204 * MB);
  unsigned short* wkt    = (unsigned short*)(base + 206 * MB);
  unsigned short* wvt    = (unsigned short*)(base + 208 * MB);
  unsigned short* wot    = (unsigned short*)(base + 210 * MB);

  dim3 tb(32, 8);
  transpose_cast<<<dim3(DI2 / 32, DD / 32), tb, 0, stream>>>(w_up,   wugt,                    DD,  DI2);
  transpose_cast<<<dim3(DI2 / 32, DD / 32), tb, 0, stream>>>(w_gate, wugt + (size_t)DI2 * DD, DD,  DI2);
  transpose_cast<<<dim3(DD / 32, DI2 / 32), tb, 0, stream>>>(w_down, wdt, DI2, DD);
  transpose_cast<<<dim3(DD / 32, DD / 32),  tb, 0, stream>>>(wq, wqt, DD, DD);
  transpose_cast<<<dim3(DD / 32, DD / 32),  tb, 0, stream>>>(wk, wkt, DD, DD);
  transpose_cast<<<dim3(DD / 32, DD / 32),  tb, 0, stream>>>(wv, wvt, DD, DD);
  transpose_cast<<<dim3(DD / 32, DD / 32),  tb, 0, stream>>>(wo, wot, DD, DD);

  rmsnorm_kernel<<<NR, 256, 0, stream>>>(x, norm_w, normed);

  // [16384,1024] @ [1024,4096] -> ug (u | gate_pre); grid 64*16 = 1024 blocks
  gemm256<EP_BF16><<<dim3((NR / 256) * (4096 / 256)), 512, 0, stream>>>(
      normed, wugt, ug, nullptr, nullptr, nullptr, NR, 4096, DD, 1.0f);

  convgate_kernel<<<NR, 256, 0, stream>>>(ug, conv_w, conv_b, hin);

  // [16384,2048] @ [2048,1024] -> h; grid 64*4 = 256
  gemm256<EP_BF16><<<dim3((NR / 256) * (DD / 256)), 512, 0, stream>>>(
      hin, wdt, hbuf, nullptr, nullptr, nullptr, NR, DD, DI2, 1.0f);

  gemm256<EP_BF16><<<dim3((NR / 256) * (DD / 256)), 512, 0, stream>>>(
      hbuf, wqt, qbuf, nullptr, nullptr, nullptr, NR, DD, DD, 0.03125f);
  gemm256<EP_BF16_BOTH><<<dim3((NR / 256) * (DD / 256)), 512, 0, stream>>>(
      hbuf, wkt, kbuf, ktbuf, nullptr, nullptr, NR, DD, DD, 1.0f);
  gemm256<EP_BF16_T><<<dim3((NR / 256) * (DD / 256)), 512, 0, stream>>>(
      hbuf, wvt, nullptr, vtbuf, nullptr, nullptr, NR, DD, DD, 1.0f);

  // Hebbian memory via superchunk decomposition (16 chunks / superchunk):
  state_gemm<<<dim3(8, 8, 16), 256, 0, stream>>>(vtbuf, ktbuf, Tbuf);   // uses ktbuf, then dead
  score_attn<<<dim3(136, 16), 256, 0, stream>>>(qbuf, kbuf, sbuf);      // sbuf overlays ktbuf
  prefix_kernel<<<1024, 256, 0, stream>>>(Tbuf);
  pv_attn<<<dim3(8, 16, 16), 256, 0, stream>>>(sbuf, vtbuf, obuf);
  cross_gemm<<<dim3(8, 8, 16), 256, 0, stream>>>(qbuf, Tbuf, obuf);

  // out = obuf @ wo + x; grid 256
  gemm256<EP_F32_RES><<<dim3((NR / 256) * (DD / 256)), 512, 0, stream>>>(
      obuf, wot, nullptr, nullptr, out, x, NR, DD, DD, 1.0f);
}

// Round 6
// 827.509 us; speedup vs baseline: 2.6411x; 1.0223x over previous
//
#include <hip/hip_runtime.h>
#include <cstdint>
#include <cstddef>

#define SS 8192
#define DD 1024
#define DI2 2048
#define NR 16384   // B*S

#define LOG2_09 (-0.152003093445050f)   // log2(0.9)
#define LAMBDA16 0.185302018885184f     // 0.9^16

typedef __attribute__((ext_vector_type(4))) float f32x4;
typedef __attribute__((ext_vector_type(8))) __bf16 bf16x8;

union U16 { uint4 u; bf16x8 b; };

static __device__ __forceinline__ f32x4 MFMA(uint4 a, uint4 b, f32x4 c) {
  U16 ua, ub; ua.u = a; ub.u = b;
  return __builtin_amdgcn_mfma_f32_16x16x32_bf16(ua.b, ub.b, c, 0, 0, 0);
}

static __device__ __forceinline__ unsigned short f2bf(float f) {
  union { float f; unsigned u; } v; v.f = f;
  return (unsigned short)((v.u + 0x7FFFu + ((v.u >> 16) & 1u)) >> 16);
}
static __device__ __forceinline__ float bf2f(unsigned b) {
  union { unsigned u; float f; } v; v.u = b << 16; return v.f;
}
static __device__ __forceinline__ void unpack8(uint4 u, float* f) {
  f[0] = bf2f(u.x & 0xFFFFu); f[1] = bf2f(u.x >> 16);
  f[2] = bf2f(u.y & 0xFFFFu); f[3] = bf2f(u.y >> 16);
  f[4] = bf2f(u.z & 0xFFFFu); f[5] = bf2f(u.z >> 16);
  f[6] = bf2f(u.w & 0xFFFFu); f[7] = bf2f(u.w >> 16);
}
static __device__ __forceinline__ uint4 scale8(uint4 u, float w) {
  float f[8]; unpack8(u, f);
  uint4 o;
  o.x = (unsigned)f2bf(f[0] * w) | ((unsigned)f2bf(f[1] * w) << 16);
  o.y = (unsigned)f2bf(f[2] * w) | ((unsigned)f2bf(f[3] * w) << 16);
  o.z = (unsigned)f2bf(f[4] * w) | ((unsigned)f2bf(f[5] * w) << 16);
  o.w = (unsigned)f2bf(f[6] * w) | ((unsigned)f2bf(f[7] * w) << 16);
  return o;
}

// async global->LDS, 16B per lane. LDS dest is wave-uniform base + lane*16.
static __device__ __forceinline__ void glds16(const unsigned short* g, char* l) {
  __builtin_amdgcn_global_load_lds(
      (const __attribute__((address_space(1))) unsigned int*)g,
      (__attribute__((address_space(3))) unsigned int*)l, 16, 0, 0);
}

// Bijective XOR swizzle for reg-staged state_gemm tiles (64B rows).
static __device__ __forceinline__ int swz64(int row, int kb) { return ((row << 6) | kb) ^ ((row & 7) << 4); }

// ---------------- weight transpose + cast: out[c][r] = bf16(in[r][c]) ----------------
__global__ __launch_bounds__(256)
void transpose_cast(const float* __restrict__ in, unsigned short* __restrict__ out, int R, int Cc) {
  __shared__ float tile[32][33];
  const int r0 = blockIdx.y * 32, c0 = blockIdx.x * 32;
  const int tx = threadIdx.x, ty = threadIdx.y;
#pragma unroll
  for (int i = 0; i < 4; i++)
    tile[ty + i * 8][tx] = in[(size_t)(r0 + ty + i * 8) * Cc + c0 + tx];
  __syncthreads();
#pragma unroll
  for (int i = 0; i < 4; i++)
    out[(size_t)(c0 + ty + i * 8) * R + r0 + tx] = f2bf(tile[tx][ty + i * 8]);
}

// ---------------- RMSNorm (fp32 in -> bf16 out) ----------------
__global__ __launch_bounds__(256)
void rmsnorm_kernel(const float* __restrict__ x, const float* __restrict__ w,
                    unsigned short* __restrict__ out) {
  const int row = blockIdx.x, t = threadIdx.x;
  const float4 v = ((const float4*)(x + (size_t)row * DD))[t];
  float ss = v.x * v.x + v.y * v.y + v.z * v.z + v.w * v.w;
  __shared__ float sred[256];
  sred[t] = ss;
  __syncthreads();
  for (int o = 128; o > 0; o >>= 1) {
    if (t < o) sred[t] += sred[t + o];
    __syncthreads();
  }
  const float rr = rsqrtf(sred[0] * (1.0f / (float)DD) + 1e-5f);
  const float4 wv = ((const float4*)w)[t];
  uint2 pk;
  pk.x = (unsigned)f2bf(v.x * rr * wv.x) | ((unsigned)f2bf(v.y * rr * wv.y) << 16);
  pk.y = (unsigned)f2bf(v.z * rr * wv.z) | ((unsigned)f2bf(v.w * rr * wv.w) << 16);
  *(uint2*)(out + (size_t)row * DD + t * 4) = pk;
}

// ---------------- 256x256-tile deep-pipelined bf16 GEMM: C = A[M][K] @ Bt[N][K]^T ----------------
// 8 waves (512 thr), wave grid 2M x 4N (128x64 out/wave). BK=32, quadruple-buffered LDS.
// Counted vmcnt(8): tiles t+1,t+2 always in flight. T2 swizzle both-sides.
// XCD-locality remap: each XCD owns an m-slice x all n, so its concurrent A working set
// (8 panels = 4MB) fits the per-XCD L2 and A is HBM-fetched once chip-wide.
enum { EP_BF16 = 0, EP_BF16_BOTH = 1, EP_BF16_T = 2, EP_F32_RES = 3 };

template <int MODE>
__global__ __launch_bounds__(512, 2)
void gemm256(const unsigned short* __restrict__ A, const unsigned short* __restrict__ Bt,
             unsigned short* __restrict__ Cb, unsigned short* __restrict__ Ct,
             float* __restrict__ Cf, const float* __restrict__ resid,
             int M, int N, int K, float scale) {
  __shared__ char sLds[131072];
  const int t = threadIdx.x, lane = t & 63, wid = t >> 6;
  const int wr = wid >> 2, wc = wid & 3;
  const int l15 = lane & 15, lh = lane >> 4;
  // XCD m-slice remap (requires mblocks % 8 == 0; true for M=16384 -> 64)
  const int mblocks = M >> 8;
  const int msl = mblocks >> 3;
  const int xcd = (int)blockIdx.x & 7, loc = (int)blockIdx.x >> 3;
  const int m0 = (xcd * msl + (loc % msl)) << 8;
  const int n0 = (loc / msl) << 8;
  // staging source (inverse swizzle on the global column)
  const int srow = wid * 16 + (lane >> 2);                          // 0..127 within half
  const int scol = ((lane & 3) << 3) ^ (((srow >> 1) & 3) << 3);   // bf16 elems
  const unsigned short* pA0 = A + (size_t)(m0 + srow) * K + scol;
  const unsigned short* pA1 = pA0 + (size_t)128 * K;
  const unsigned short* pB0 = Bt + (size_t)(n0 + srow) * K + scol;
  const unsigned short* pB1 = pB0 + (size_t)128 * K;
  const int ldsW = wid * 1024;
  // swizzled read offsets (iteration-invariant)
  int offA[8], offB[4];
#pragma unroll
  for (int mf = 0; mf < 8; mf++) {
    const int r = wr * 128 + mf * 16 + l15;
    offA[mf] = r * 64 + ((lh * 16) ^ (((r >> 1) & 3) << 4));
  }
#pragma unroll
  for (int nf = 0; nf < 4; nf++) {
    const int r = wc * 64 + nf * 16 + l15;
    offB[nf] = r * 64 + ((lh * 16) ^ (((r >> 1) & 3) << 4));
  }
  const int NT = K >> 5;
#define BUFA(tt) (sLds + ((tt) & 3) * 32768)
#define BUFB(tt) (sLds + ((tt) & 3) * 32768 + 16384)
#define STAGE(tt) do { const int _k = (tt) * 32; \
    glds16(pA0 + _k, BUFA(tt) + ldsW); \
    glds16(pA1 + _k, BUFA(tt) + 8192 + ldsW); \
    glds16(pB0 + _k, BUFB(tt) + ldsW); \
    glds16(pB1 + _k, BUFB(tt) + 8192 + ldsW); } while (0)
  STAGE(0); STAGE(1); STAGE(2);
  f32x4 acc[8][4] = {};
  for (int kt = 0; kt < NT; ++kt) {
    // counted waits: own loads for tile kt done; tiles kt+1, kt+2 stay in flight
    asm volatile("s_waitcnt lgkmcnt(0)" ::: "memory");
    if (kt < NT - 2)       asm volatile("s_waitcnt vmcnt(8)" ::: "memory");
    else if (kt == NT - 2) asm volatile("s_waitcnt vmcnt(4)" ::: "memory");
    else                   asm volatile("s_waitcnt vmcnt(0)" ::: "memory");
    __builtin_amdgcn_s_barrier();
    asm volatile("" ::: "memory");  // compile fence: nothing hoists above the barrier
    if (kt + 3 < NT) STAGE(kt + 3);  // buf (kt+3)&3 == (kt-1)&3: last read pre-barrier
    const char* At  = BUFA(kt);
    const char* Bt_ = BUFB(kt);
    uint4 av[8], bv[4];
#pragma unroll
    for (int mf = 0; mf < 8; mf++) av[mf] = *(const uint4*)(At + offA[mf]);
#pragma unroll
    for (int nf = 0; nf < 4; nf++) bv[nf] = *(const uint4*)(Bt_ + offB[nf]);
    __builtin_amdgcn_s_setprio(1);
#pragma unroll
    for (int mf = 0; mf < 8; mf++)
#pragma unroll
      for (int nf = 0; nf < 4; nf++)
        acc[mf][nf] = MFMA(av[mf], bv[nf], acc[mf][nf]);
    __builtin_amdgcn_s_setprio(0);
  }
#undef STAGE
#undef BUFA
#undef BUFB
#pragma unroll
  for (int mf = 0; mf < 8; mf++) {
    const int r0 = m0 + wr * 128 + mf * 16 + lh * 4;
#pragma unroll
    for (int nf = 0; nf < 4; nf++) {
      const int c = n0 + wc * 64 + nf * 16 + l15;
      f32x4 v = acc[mf][nf] * scale;
      if constexpr (MODE == EP_F32_RES) {
#pragma unroll
        for (int jj = 0; jj < 4; jj++) {
          const size_t idx = (size_t)(r0 + jj) * N + c;
          Cf[idx] = v[jj] + resid[idx];
        }
      } else {
        if constexpr (MODE == EP_BF16 || MODE == EP_BF16_BOTH) {
#pragma unroll
          for (int jj = 0; jj < 4; jj++)
            Cb[(size_t)(r0 + jj) * N + c] = f2bf(v[jj]);
        }
        if constexpr (MODE == EP_BF16_BOTH || MODE == EP_BF16_T) {
          // transposed store: Ct[b][c][s]  (requires N == DD)
          const int bb = r0 >> 13, s0 = r0 & (SS - 1);
          uint2 pk;
          pk.x = (unsigned)f2bf(v[0]) | ((unsigned)f2bf(v[1]) << 16);
          pk.y = (unsigned)f2bf(v[2]) | ((unsigned)f2bf(v[3]) << 16);
          *(uint2*)(Ct + ((size_t)bb * DD + c) * SS + s0) = pk;
        }
      }
    }
  }
}

// ---------------- causal depthwise conv (K=4) + SiLU, gate SiLU, multiply ----------------
__global__ __launch_bounds__(256)
void convgate_kernel(const unsigned short* __restrict__ ug, const float* __restrict__ cw,
                     const float* __restrict__ cb, unsigned short* __restrict__ hin) {
  const int r = blockIdx.x;          // global row (b*S + s)
  const int c0 = threadIdx.x * 8;    // channel base [0,2048)
  const int s = r & (SS - 1);
  float acc[8];
#pragma unroll
  for (int i = 0; i < 8; i++) acc[i] = cb[c0 + i];
  for (int tap = 0; tap < 4; tap++) {
    const int ds = s - 3 + tap;
    if (ds < 0) continue;
    uint4 uv = *(const uint4*)(ug + (size_t)(r - 3 + tap) * 4096 + c0);
    float u[8]; unpack8(uv, u);
#pragma unroll
    for (int i = 0; i < 8; i++) acc[i] += u[i] * cw[tap * DI2 + c0 + i];
  }
  uint4 gv = *(const uint4*)(ug + (size_t)r * 4096 + DI2 + c0);
  float gt[8]; unpack8(gv, gt);
  unsigned short o16[8];
#pragma unroll
  for (int i = 0; i < 8; i++) {
    const float val = acc[i] / (1.0f + __expf(-acc[i]));
    const float gg  = gt[i] / (1.0f + __expf(-gt[i]));
    o16[i] = f2bf(val * gg);
  }
  uint4 ov;
  ov.x = (unsigned)o16[0] | ((unsigned)o16[1] << 16);
  ov.y = (unsigned)o16[2] | ((unsigned)o16[3] << 16);
  ov.z = (unsigned)o16[4] | ((unsigned)o16[5] << 16);
  ov.w = (unsigned)o16[6] | ((unsigned)o16[7] << 16);
  *(uint4*)(hin + (size_t)r * DI2 + c0) = ov;
}

// ---------------- superchunk state: T[gb][e][dk] = sum_t 0.9^(15-t/64) V[t][e] K[t][dk] ----------------
__global__ __launch_bounds__(256)
void state_gemm(const unsigned short* __restrict__ vt, const unsigned short* __restrict__ kt,
                unsigned short* __restrict__ Tb) {
  __shared__ char sA[8192];
  __shared__ char sB[8192];
  const int t = threadIdx.x, lane = t & 63, wid = t >> 6;
  const int wr = wid >> 1, wc = wid & 1;
  const int l15 = lane & 15, lh = lane >> 4;
  const int gb = blockIdx.z, b = gb >> 3, g = gb & 7;
  const int m0 = blockIdx.y * 128, n0 = blockIdx.x * 128;
  const int sr = t >> 2, skb = (t & 3) * 16;
  const size_t kofs = (size_t)g * 1024;
  const unsigned short* Ar0 = vt + (size_t)(b * DD + m0 + sr) * SS + kofs;
  const unsigned short* Ar1 = Ar0 + (size_t)64 * SS;
  const unsigned short* Br0 = kt + (size_t)(b * DD + n0 + sr) * SS + kofs;
  const unsigned short* Br1 = Br0 + (size_t)64 * SS;
  f32x4 acc[4][4] = {};
  for (int k0 = 0; k0 < 1024; k0 += 32) {
    const int ke = k0 + (t & 3) * 8;
    const float w = exp2f((float)(15 - (ke >> 6)) * LOG2_09);
    uint4 ra0 = scale8(*(const uint4*)(Ar0 + ke), w);
    uint4 ra1 = scale8(*(const uint4*)(Ar1 + ke), w);
    uint4 rb0 = *(const uint4*)(Br0 + ke);
    uint4 rb1 = *(const uint4*)(Br1 + ke);
    __syncthreads();
    *(uint4*)(sA + swz64(sr, skb)) = ra0;
    *(uint4*)(sA + swz64(sr + 64, skb)) = ra1;
    *(uint4*)(sB + swz64(sr, skb)) = rb0;
    *(uint4*)(sB + swz64(sr + 64, skb)) = rb1;
    __syncthreads();
    uint4 af[4], bfr[4];
#pragma unroll
    for (int i = 0; i < 4; i++) af[i]  = *(uint4*)(sA + swz64(wr * 64 + i * 16 + l15, lh * 16));
#pragma unroll
    for (int i = 0; i < 4; i++) bfr[i] = *(uint4*)(sB + swz64(wc * 64 + i * 16 + l15, lh * 16));
#pragma unroll
    for (int mf = 0; mf < 4; mf++)
#pragma unroll
      for (int nf = 0; nf < 4; nf++)
        acc[mf][nf] = MFMA(af[mf], bfr[nf], acc[mf][nf]);
  }
  unsigned short* Tg = Tb + ((size_t)gb << 20);
#pragma unroll
  for (int mf = 0; mf < 4; mf++) {
    const int r0 = m0 + wr * 64 + mf * 16 + lh * 4;
#pragma unroll
    for (int nf = 0; nf < 4; nf++) {
      const int c = n0 + wc * 64 + nf * 16 + l15;
#pragma unroll
      for (int jj = 0; jj < 4; jj++)
        Tg[(size_t)(r0 + jj) * 1024 + c] = f2bf(acc[mf][nf][jj]);
    }
  }
}

// ---------------- superchunk prefix (in-place): Minit_g = 0.9^16 Minit_{g-1} + T_{g-1} ----------------
__global__ __launch_bounds__(256)
void prefix_kernel(unsigned short* __restrict__ Tb) {
  const int tid = blockIdx.x * 256 + threadIdx.x;  // 262144 threads
  const int b = tid >> 17, i = tid & 131071;
  unsigned short* p = Tb + (((size_t)b * 8) << 20) + (size_t)i * 8;
  float acc[8] = {};
  for (int g = 0; g < 8; g++) {
    unsigned short* pg = p + ((size_t)g << 20);
    uint4 tv = *(uint4*)pg;
    float tf_[8]; unpack8(tv, tf_);
    uint4 ov;
    ov.x = (unsigned)f2bf(acc[0]) | ((unsigned)f2bf(acc[1]) << 16);
    ov.y = (unsigned)f2bf(acc[2]) | ((unsigned)f2bf(acc[3]) << 16);
    ov.z = (unsigned)f2bf(acc[4]) | ((unsigned)f2bf(acc[5]) << 16);
    ov.w = (unsigned)f2bf(acc[6]) | ((unsigned)f2bf(acc[7]) << 16);
    *(uint4*)pg = ov;
#pragma unroll
    for (int e = 0; e < 8; e++) acc[e] = LAMBDA16 * acc[e] + tf_[e];
  }
}

// ---------------- score: S[qt-block][tb-block] = decay/tril-weighted Q K^T -> sbuf bf16 ----------------
__global__ __launch_bounds__(256)
void score_attn(const unsigned short* __restrict__ q, const unsigned short* __restrict__ k,
                unsigned short* __restrict__ sbuf) {
  __shared__ char sQ[4096];  // [64][32] bf16 linear
  __shared__ char sK[4096];
  const int p = blockIdx.x, gb = blockIdx.y;
  int qt = (int)((sqrtf(8.0f * p + 1.0f) - 1.0f) * 0.5f);
  while ((qt + 1) * (qt + 2) / 2 <= p) qt++;
  while (qt * (qt + 1) / 2 > p) qt--;
  const int tb = p - qt * (qt + 1) / 2;
  const int b = gb >> 3, g = gb & 7;
  const int t = threadIdx.x, lane = t & 63, wid = t >> 6;
  const int l15 = lane & 15, lh = lane >> 4;
  const int srow = wid * 16 + (lane >> 2), scol = (lane & 3) * 8;
  const unsigned short* qg = q + (size_t)(b * SS + g * 1024 + qt * 64 + srow) * DD + scol;
  const unsigned short* kg = k + (size_t)(b * SS + g * 1024 + tb * 64 + srow) * DD + scol;
  char* lQ = sQ + wid * 1024;
  char* lK = sK + wid * 1024;
  f32x4 s[4] = {};
  for (int k0 = 0; k0 < DD; k0 += 32) {
    glds16(qg + k0, lQ);
    glds16(kg + k0, lK);
    __syncthreads();
    uint4 aq = *(uint4*)(sQ + (wid * 16 + l15) * 64 + lh * 16);
#pragma unroll
    for (int tf = 0; tf < 4; tf++) {
      uint4 bk = *(uint4*)(sK + (tf * 16 + l15) * 64 + lh * 16);
      s[tf] = MFMA(aq, bk, s[tf]);
    }
    __syncthreads();
  }
  const bool diag = (tb == qt);
  const float w = diag ? 1.0f : exp2f((float)(qt - 1 - tb) * LOG2_09);
  unsigned short* sb = sbuf + ((size_t)(gb * 16 + qt) * 64) * 1024 + tb * 64;
#pragma unroll
  for (int tf = 0; tf < 4; tf++)
#pragma unroll
    for (int jj = 0; jj < 4; jj++) {
      const int qr = wid * 16 + lh * 4 + jj;  // 0..63
      const int tc = tf * 16 + l15;           // 0..63
      float val = s[tf][jj] * w;
      if (diag && tc > qr) val = 0.0f;
      sb[(size_t)qr * 1024 + tc] = f2bf(val);
    }
}

// ---------------- pv: O[64 q-rows][128 e] = S_strip @ V  (k = (qt+1)*64) ----------------
__global__ __launch_bounds__(256)
void pv_attn(const unsigned short* __restrict__ sbuf, const unsigned short* __restrict__ vt,
             unsigned short* __restrict__ obuf) {
  __shared__ char sA[4096];  // S [64][32] linear
  __shared__ char sB[8192];  // V [128 e][32 t] linear
  const int et = blockIdx.x, qt = blockIdx.y, gb = blockIdx.z;
  const int b = gb >> 3, g = gb & 7;
  const int t = threadIdx.x, lane = t & 63, wid = t >> 6;
  const int l15 = lane & 15, lh = lane >> 4;
  const int srow = wid * 16 + (lane >> 2), scol = (lane & 3) * 8;
  const int e0 = et * 128;
  const unsigned short* Ag = sbuf + ((size_t)(gb * 16 + qt) * 64 + srow) * 1024 + scol;
  const unsigned short* Bg0 = vt + ((size_t)b * DD + e0 + srow) * SS + g * 1024 + scol;
  const unsigned short* Bg1 = Bg0 + (size_t)64 * SS;
  char* lA  = sA + wid * 1024;
  char* lB0 = sB + wid * 1024;
  char* lB1 = sB + 4096 + wid * 1024;
  const int tEnd = (qt + 1) * 64;
  f32x4 o[4][2] = {};
  for (int t0 = 0; t0 < tEnd; t0 += 32) {
    glds16(Ag + t0, lA);
    glds16(Bg0 + t0, lB0);
    glds16(Bg1 + t0, lB1);
    __syncthreads();
    uint4 af[4], vf[2];
#pragma unroll
    for (int mf = 0; mf < 4; mf++) af[mf] = *(uint4*)(sA + (mf * 16 + l15) * 64 + lh * 16);
#pragma unroll
    for (int nf = 0; nf < 2; nf++) vf[nf] = *(uint4*)(sB + (wid * 32 + nf * 16 + l15) * 64 + lh * 16);
#pragma unroll
    for (int mf = 0; mf < 4; mf++)
#pragma unroll
      for (int nf = 0; nf < 2; nf++)
        o[mf][nf] = MFMA(af[mf], vf[nf], o[mf][nf]);
    __syncthreads();
  }
  const size_t qrow0 = (size_t)b * SS + (size_t)g * 1024 + (size_t)qt * 64;
#pragma unroll
  for (int mf = 0; mf < 4; mf++)
#pragma unroll
    for (int nf = 0; nf < 2; nf++)
#pragma unroll
      for (int jj = 0; jj < 4; jj++)
        obuf[(qrow0 + mf * 16 + lh * 4 + jj) * DD + e0 + wid * 32 + nf * 16 + l15] =
            f2bf(o[mf][nf][jj]);
}

// ---------------- cross term: obuf += 0.9^cl(row) * Q @ Minit_g ----------------
__global__ __launch_bounds__(256)
void cross_gemm(const unsigned short* __restrict__ q, const unsigned short* __restrict__ Minit,
                unsigned short* __restrict__ obuf) {
  __shared__ char sA[8192];
  __shared__ char sB[8192];
  const int t = threadIdx.x, lane = t & 63, wid = t >> 6;
  const int wr = wid >> 1, wc = wid & 1;
  const int l15 = lane & 15, lh = lane >> 4;
  const int gb = blockIdx.z, b = gb >> 3, g = gb & 7;
  const int m0 = blockIdx.y * 128, n0 = blockIdx.x * 128;
  const int srow = wid * 16 + (lane >> 2), scol = (lane & 3) * 8;
  const unsigned short* Ar0 = q + (size_t)(b * SS + g * 1024 + m0 + srow) * DD + scol;
  const unsigned short* Ar1 = Ar0 + (size_t)64 * DD;
  const unsigned short* Br0 = Minit + ((size_t)gb << 20) + (size_t)(n0 + srow) * 1024 + scol;
  const unsigned short* Br1 = Br0 + (size_t)64 * 1024;
  char* lA0 = sA + wid * 1024;
  char* lA1 = sA + 4096 + wid * 1024;
  char* lB0 = sB + wid * 1024;
  char* lB1 = sB + 4096 + wid * 1024;
  f32x4 acc[4][4] = {};
  for (int k0 = 0; k0 < 1024; k0 += 32) {
    glds16(Ar0 + k0, lA0);
    glds16(Ar1 + k0, lA1);
    glds16(Br0 + k0, lB0);
    glds16(Br1 + k0, lB1);
    __syncthreads();
    uint4 af[4], bfr[4];
#pragma unroll
    for (int i = 0; i < 4; i++) af[i]  = *(uint4*)(sA + (wr * 64 + i * 16 + l15) * 64 + lh * 16);
#pragma unroll
    for (int i = 0; i < 4; i++) bfr[i] = *(uint4*)(sB + (wc * 64 + i * 16 + l15) * 64 + lh * 16);
#pragma unroll
    for (int mf = 0; mf < 4; mf++)
#pragma unroll
      for (int nf = 0; nf < 4; nf++)
        acc[mf][nf] = MFMA(af[mf], bfr[nf], acc[mf][nf]);
    __syncthreads();
  }
#pragma unroll
  for (int mf = 0; mf < 4; mf++) {
    const int rl = m0 + wr * 64 + mf * 16 + lh * 4;  // row within superchunk [0,1024)
#pragma unroll
    for (int nf = 0; nf < 4; nf++) {
      const int c = n0 + wc * 64 + nf * 16 + l15;
#pragma unroll
      for (int jj = 0; jj < 4; jj++) {
        const int r = rl + jj;
        const float rs = exp2f((float)(r >> 6) * LOG2_09);  // 0.9^chunk-local
        const size_t idx = ((size_t)b * SS + (size_t)g * 1024 + r) * DD + c;
        obuf[idx] = f2bf(bf2f(obuf[idx]) + acc[mf][nf][jj] * rs);
      }
    }
  }
}

extern "C" void kernel_launch(void* const* d_in, const int* in_sizes, int n_in,
                              void* d_out, int out_size, void* d_ws, size_t ws_size,
                              hipStream_t stream) {
  (void)in_sizes; (void)n_in; (void)out_size;
  const float* x      = (const float*)d_in[0];
  const float* norm_w = (const float*)d_in[1];
  const float* w_up   = (const float*)d_in[2];
  const float* w_gate = (const float*)d_in[3];
  const float* w_down = (const float*)d_in[4];
  const float* conv_w = (const float*)d_in[5];
  const float* conv_b = (const float*)d_in[6];
  const float* wq     = (const float*)d_in[7];
  const float* wk     = (const float*)d_in[8];
  const float* wv     = (const float*)d_in[9];
  const float* wo     = (const float*)d_in[10];
  float* out = (float*)d_out;

  const size_t MB = 1ull << 20;
  // Aliased workspace plan (212 MiB). Lifetimes:
  //   [0,32M)    ug -> hbuf -> Tbuf (after QKV gemms)
  //   [32,64M)   ug -> qbuf
  //   [64,96M)   ug -> kbuf
  //   [96,128M)  ug -> ktbuf -> sbuf (after state_gemm)
  //   [128,160M) normed -> hin -> vtbuf
  //   [160,192M) hin tail -> obuf
  //   [192,212M) weight transposes
  if (ws_size < 212 * MB) return;
  char* base = (char*)d_ws;
  unsigned short* ug     = (unsigned short*)(base + 0);
  unsigned short* hbuf   = (unsigned short*)(base + 0);
  unsigned short* Tbuf   = (unsigned short*)(base + 0);
  unsigned short* qbuf   = (unsigned short*)(base + 32 * MB);
  unsigned short* kbuf   = (unsigned short*)(base + 64 * MB);
  unsigned short* ktbuf  = (unsigned short*)(base + 96 * MB);
  unsigned short* sbuf   = (unsigned short*)(base + 96 * MB);
  unsigned short* normed = (unsigned short*)(base + 128 * MB);
  unsigned short* hin    = (unsigned short*)(base + 128 * MB);
  unsigned short* vtbuf  = (unsigned short*)(base + 128 * MB);
  unsigned short* obuf   = (unsigned short*)(base + 160 * MB);
  unsigned short* wugt   = (unsigned short*)(base + 192 * MB);
  unsigned short* wdt    = (unsigned short*)(base + 200 * MB);
  unsigned short* wqt    = (unsigned short*)(base + 204 * MB);
  unsigned short* wkt    = (unsigned short*)(base + 206 * MB);
  unsigned short* wvt    = (unsigned short*)(base + 208 * MB);
  unsigned short* wot    = (unsigned short*)(base + 210 * MB);

  dim3 tb(32, 8);
  transpose_cast<<<dim3(DI2 / 32, DD / 32), tb, 0, stream>>>(w_up,   wugt,                    DD,  DI2);
  transpose_cast<<<dim3(DI2 / 32, DD / 32), tb, 0, stream>>>(w_gate, wugt + (size_t)DI2 * DD, DD,  DI2);
  transpose_cast<<<dim3(DD / 32, DI2 / 32), tb, 0, stream>>>(w_down, wdt, DI2, DD);
  transpose_cast<<<dim3(DD / 32, DD / 32),  tb, 0, stream>>>(wq, wqt, DD, DD);
  transpose_cast<<<dim3(DD / 32, DD / 32),  tb, 0, stream>>>(wk, wkt, DD, DD);
  transpose_cast<<<dim3(DD / 32, DD / 32),  tb, 0, stream>>>(wv, wvt, DD, DD);
  transpose_cast<<<dim3(DD / 32, DD / 32),  tb, 0, stream>>>(wo, wot, DD, DD);

  rmsnorm_kernel<<<NR, 256, 0, stream>>>(x, norm_w, normed);

  // [16384,1024] @ [1024,4096] -> ug (u | gate_pre); grid 64*16 = 1024 blocks
  gemm256<EP_BF16><<<dim3((NR / 256) * (4096 / 256)), 512, 0, stream>>>(
      normed, wugt, ug, nullptr, nullptr, nullptr, NR, 4096, DD, 1.0f);

  convgate_kernel<<<NR, 256, 0, stream>>>(ug, conv_w, conv_b, hin);

  // [16384,2048] @ [2048,1024] -> h; grid 64*4 = 256
  gemm256<EP_BF16><<<dim3((NR / 256) * (DD / 256)), 512, 0, stream>>>(
      hin, wdt, hbuf, nullptr, nullptr, nullptr, NR, DD, DI2, 1.0f);

  gemm256<EP_BF16><<<dim3((NR / 256) * (DD / 256)), 512, 0, stream>>>(
      hbuf, wqt, qbuf, nullptr, nullptr, nullptr, NR, DD, DD, 0.03125f);
  gemm256<EP_BF16_BOTH><<<dim3((NR / 256) * (DD / 256)), 512, 0, stream>>>(
      hbuf, wkt, kbuf, ktbuf, nullptr, nullptr, NR, DD, DD, 1.0f);
  gemm256<EP_BF16_T><<<dim3((NR / 256) * (DD / 256)), 512, 0, stream>>>(
      hbuf, wvt, nullptr, vtbuf, nullptr, nullptr, NR, DD, DD, 1.0f);

  // Hebbian memory via superchunk decomposition (16 chunks / superchunk):
  state_gemm<<<dim3(8, 8, 16), 256, 0, stream>>>(vtbuf, ktbuf, Tbuf);   // uses ktbuf, then dead
  score_attn<<<dim3(136, 16), 256, 0, stream>>>(qbuf, kbuf, sbuf);      // sbuf overlays ktbuf
  prefix_kernel<<<1024, 256, 0, stream>>>(Tbuf);
  pv_attn<<<dim3(8, 16, 16), 256, 0, stream>>>(sbuf, vtbuf, obuf);
  cross_gemm<<<dim3(8, 8, 16), 256, 0, stream>>>(qbuf, Tbuf, obuf);

  // out = obuf @ wo + x; grid 256
  gemm256<EP_F32_RES><<<dim3((NR / 256) * (DD / 256)), 512, 0, stream>>>(
      obuf, wot, nullptr, nullptr, out, x, NR, DD, DD, 1.0f);
}

// Round 7
// 760.466 us; speedup vs baseline: 2.8740x; 1.0882x over previous
//
#include <hip/hip_runtime.h>
#include <cstdint>
#include <cstddef>

#define SS 8192
#define DD 1024
#define DI2 2048
#define NR 16384   // B*S

#define LOG2_09 (-0.152003093445050f)   // log2(0.9)
#define LAMBDA16 0.185302018885184f     // 0.9^16

typedef __attribute__((ext_vector_type(4))) float f32x4;
typedef __attribute__((ext_vector_type(8))) __bf16 bf16x8;

union U16 { uint4 u; bf16x8 b; };

static __device__ __forceinline__ f32x4 MFMA(uint4 a, uint4 b, f32x4 c) {
  U16 ua, ub; ua.u = a; ub.u = b;
  return __builtin_amdgcn_mfma_f32_16x16x32_bf16(ua.b, ub.b, c, 0, 0, 0);
}

static __device__ __forceinline__ unsigned short f2bf(float f) {
  union { float f; unsigned u; } v; v.f = f;
  return (unsigned short)((v.u + 0x7FFFu + ((v.u >> 16) & 1u)) >> 16);
}
static __device__ __forceinline__ float bf2f(unsigned b) {
  union { unsigned u; float f; } v; v.u = b << 16; return v.f;
}
static __device__ __forceinline__ void unpack8(uint4 u, float* f) {
  f[0] = bf2f(u.x & 0xFFFFu); f[1] = bf2f(u.x >> 16);
  f[2] = bf2f(u.y & 0xFFFFu); f[3] = bf2f(u.y >> 16);
  f[4] = bf2f(u.z & 0xFFFFu); f[5] = bf2f(u.z >> 16);
  f[6] = bf2f(u.w & 0xFFFFu); f[7] = bf2f(u.w >> 16);
}
static __device__ __forceinline__ uint4 scale8(uint4 u, float w) {
  float f[8]; unpack8(u, f);
  uint4 o;
  o.x = (unsigned)f2bf(f[0] * w) | ((unsigned)f2bf(f[1] * w) << 16);
  o.y = (unsigned)f2bf(f[2] * w) | ((unsigned)f2bf(f[3] * w) << 16);
  o.z = (unsigned)f2bf(f[4] * w) | ((unsigned)f2bf(f[5] * w) << 16);
  o.w = (unsigned)f2bf(f[6] * w) | ((unsigned)f2bf(f[7] * w) << 16);
  return o;
}

// async global->LDS, 16B per lane. LDS dest is wave-uniform base + lane*16.
static __device__ __forceinline__ void glds16(const unsigned short* g, char* l) {
  __builtin_amdgcn_global_load_lds(
      (const __attribute__((address_space(1))) unsigned int*)g,
      (__attribute__((address_space(3))) unsigned int*)l, 16, 0, 0);
}

// Bijective XOR swizzle for reg-staged state_gemm tiles (64B rows).
static __device__ __forceinline__ int swz64(int row, int kb) { return ((row << 6) | kb) ^ ((row & 7) << 4); }

// ---------------- weight transpose + cast: out[c][r] = bf16(in[r][c]) ----------------
__global__ __launch_bounds__(256)
void transpose_cast(const float* __restrict__ in, unsigned short* __restrict__ out, int R, int Cc) {
  __shared__ float tile[32][33];
  const int r0 = blockIdx.y * 32, c0 = blockIdx.x * 32;
  const int tx = threadIdx.x, ty = threadIdx.y;
#pragma unroll
  for (int i = 0; i < 4; i++)
    tile[ty + i * 8][tx] = in[(size_t)(r0 + ty + i * 8) * Cc + c0 + tx];
  __syncthreads();
#pragma unroll
  for (int i = 0; i < 4; i++)
    out[(size_t)(c0 + ty + i * 8) * R + r0 + tx] = f2bf(tile[tx][ty + i * 8]);
}

// ---------------- RMSNorm (fp32 in -> bf16 out) ----------------
__global__ __launch_bounds__(256)
void rmsnorm_kernel(const float* __restrict__ x, const float* __restrict__ w,
                    unsigned short* __restrict__ out) {
  const int row = blockIdx.x, t = threadIdx.x;
  const float4 v = ((const float4*)(x + (size_t)row * DD))[t];
  float ss = v.x * v.x + v.y * v.y + v.z * v.z + v.w * v.w;
  __shared__ float sred[256];
  sred[t] = ss;
  __syncthreads();
  for (int o = 128; o > 0; o >>= 1) {
    if (t < o) sred[t] += sred[t + o];
    __syncthreads();
  }
  const float rr = rsqrtf(sred[0] * (1.0f / (float)DD) + 1e-5f);
  const float4 wv = ((const float4*)w)[t];
  uint2 pk;
  pk.x = (unsigned)f2bf(v.x * rr * wv.x) | ((unsigned)f2bf(v.y * rr * wv.y) << 16);
  pk.y = (unsigned)f2bf(v.z * rr * wv.z) | ((unsigned)f2bf(v.w * rr * wv.w) << 16);
  *(uint2*)(out + (size_t)row * DD + t * 4) = pk;
}

// ---------------- 256x256-tile deep-pipelined bf16 GEMM: C = A[M][K] @ Bt[N][K]^T ----------------
// 8 waves (512 thr), wave grid 2M x 4N (128x64 out/wave). BK=32, quad-buffered LDS (128KB),
// depth-3 prefetch, counted vmcnt(8). Phase-split per K-tile: 2 phases x 16 MFMA with
// {reads || stage -> barrier -> lgkmcnt(0) -> setprio MFMA -> barrier} (m201 rhythm).
// XCD m-slice remap: per-XCD A working set = 4MB = L2.
enum { EP_BF16 = 0, EP_BF16_BOTH = 1, EP_BF16_T = 2, EP_F32_RES = 3 };

template <int MODE>
__global__ __launch_bounds__(512, 2)
void gemm256(const unsigned short* __restrict__ A, const unsigned short* __restrict__ Bt,
             unsigned short* __restrict__ Cb, unsigned short* __restrict__ Ct,
             float* __restrict__ Cf, const float* __restrict__ resid,
             int M, int N, int K, float scale) {
  __shared__ char sLds[131072];
  const int t = threadIdx.x, lane = t & 63, wid = t >> 6;
  const int wr = wid >> 2, wc = wid & 3;
  const int l15 = lane & 15, lh = lane >> 4;
  // XCD m-slice remap (requires mblocks % 8 == 0; true for M=16384 -> 64)
  const int mblocks = M >> 8;
  const int msl = mblocks >> 3;
  const int xcd = (int)blockIdx.x & 7, loc = (int)blockIdx.x >> 3;
  const int m0 = (xcd * msl + (loc % msl)) << 8;
  const int n0 = (loc / msl) << 8;
  // staging source (inverse swizzle on the global column)
  const int srow = wid * 16 + (lane >> 2);                          // 0..127 within half
  const int scol = ((lane & 3) << 3) ^ (((srow >> 1) & 3) << 3);   // bf16 elems
  const unsigned short* pA0 = A + (size_t)(m0 + srow) * K + scol;
  const unsigned short* pA1 = pA0 + (size_t)128 * K;
  const unsigned short* pB0 = Bt + (size_t)(n0 + srow) * K + scol;
  const unsigned short* pB1 = pB0 + (size_t)128 * K;
  const int ldsW = wid * 1024;
  // swizzled read offsets (iteration-invariant)
  int offA[8], offB[4];
#pragma unroll
  for (int mf = 0; mf < 8; mf++) {
    const int r = wr * 128 + mf * 16 + l15;
    offA[mf] = r * 64 + ((lh * 16) ^ (((r >> 1) & 3) << 4));
  }
#pragma unroll
  for (int nf = 0; nf < 4; nf++) {
    const int r = wc * 64 + nf * 16 + l15;
    offB[nf] = r * 64 + ((lh * 16) ^ (((r >> 1) & 3) << 4));
  }
  const int NT = K >> 5;
#define BUFA(tt) (sLds + ((tt) & 3) * 32768)
#define BUFB(tt) (sLds + ((tt) & 3) * 32768 + 16384)
#define STAGEA(tt) do { const int _k = (tt) * 32; \
    glds16(pA0 + _k, BUFA(tt) + ldsW); \
    glds16(pA1 + _k, BUFA(tt) + 8192 + ldsW); } while (0)
#define STAGEB(tt) do { const int _k = (tt) * 32; \
    glds16(pB0 + _k, BUFB(tt) + ldsW); \
    glds16(pB1 + _k, BUFB(tt) + 8192 + ldsW); } while (0)
  STAGEA(0); STAGEB(0); STAGEA(1); STAGEB(1); STAGEA(2); STAGEB(2);
  asm volatile("s_waitcnt vmcnt(8)" ::: "memory");   // tile 0 landed (own); barrier -> all waves'
  __builtin_amdgcn_s_barrier();
  f32x4 acc[8][4] = {};
  for (int kt = 0; kt < NT; ++kt) {
    const char* At  = BUFA(kt);
    const char* Bt_ = BUFB(kt);
    uint4 av[4], bv[4], av2[4];
    // ---- phase 0: reads(A0-3,B0-3) || stage-A(kt+3) -> bar -> MFMA mf0-3 ----
#pragma unroll
    for (int i = 0; i < 4; i++) av[i] = *(const uint4*)(At + offA[i]);
#pragma unroll
    for (int i = 0; i < 4; i++) bv[i] = *(const uint4*)(Bt_ + offB[i]);
    if (kt + 3 < NT) STAGEA(kt + 3);   // writes buf (kt-1)&3: all reads of it completed last iter
    asm volatile("s_waitcnt lgkmcnt(0)" ::: "memory");
    __builtin_amdgcn_sched_barrier(0);
    __builtin_amdgcn_s_setprio(1);
#pragma unroll
    for (int mf = 0; mf < 4; mf++)
#pragma unroll
      for (int nf = 0; nf < 4; nf++)
        acc[mf][nf] = MFMA(av[mf], bv[nf], acc[mf][nf]);
    __builtin_amdgcn_s_setprio(0);
    __builtin_amdgcn_s_barrier();
    // ---- phase 1: reads(A4-7) || stage-B(kt+3) -> MFMA mf4-7 (bv held in regs) ----
#pragma unroll
    for (int i = 0; i < 4; i++) av2[i] = *(const uint4*)(At + offA[4 + i]);
    if (kt + 3 < NT) STAGEB(kt + 3);
    asm volatile("s_waitcnt lgkmcnt(0)" ::: "memory");
    __builtin_amdgcn_sched_barrier(0);
    __builtin_amdgcn_s_setprio(1);
#pragma unroll
    for (int mf = 0; mf < 4; mf++)
#pragma unroll
      for (int nf = 0; nf < 4; nf++)
        acc[4 + mf][nf] = MFMA(av2[mf], bv[nf], acc[4 + mf][nf]);
    __builtin_amdgcn_s_setprio(0);
    // counted wait for next tile, BEFORE the end barrier (all waves then have their DMA landed)
    if (kt < NT - 3)       { asm volatile("s_waitcnt vmcnt(8)" ::: "memory"); }
    else if (kt == NT - 3) { asm volatile("s_waitcnt vmcnt(4)" ::: "memory"); }
    else if (kt == NT - 2) { asm volatile("s_waitcnt vmcnt(0)" ::: "memory"); }
    __builtin_amdgcn_s_barrier();
  }
#undef STAGEA
#undef STAGEB
#undef BUFA
#undef BUFB
#pragma unroll
  for (int mf = 0; mf < 8; mf++) {
    const int r0 = m0 + wr * 128 + mf * 16 + lh * 4;
#pragma unroll
    for (int nf = 0; nf < 4; nf++) {
      const int c = n0 + wc * 64 + nf * 16 + l15;
      f32x4 v = acc[mf][nf] * scale;
      if constexpr (MODE == EP_F32_RES) {
#pragma unroll
        for (int jj = 0; jj < 4; jj++) {
          const size_t idx = (size_t)(r0 + jj) * N + c;
          Cf[idx] = v[jj] + resid[idx];
        }
      } else {
        if constexpr (MODE == EP_BF16 || MODE == EP_BF16_BOTH) {
#pragma unroll
          for (int jj = 0; jj < 4; jj++)
            Cb[(size_t)(r0 + jj) * N + c] = f2bf(v[jj]);
        }
        if constexpr (MODE == EP_BF16_BOTH || MODE == EP_BF16_T) {
          // transposed store: Ct[b][c][s]  (requires N == DD)
          const int bb = r0 >> 13, s0 = r0 & (SS - 1);
          uint2 pk;
          pk.x = (unsigned)f2bf(v[0]) | ((unsigned)f2bf(v[1]) << 16);
          pk.y = (unsigned)f2bf(v[2]) | ((unsigned)f2bf(v[3]) << 16);
          *(uint2*)(Ct + ((size_t)bb * DD + c) * SS + s0) = pk;
        }
      }
    }
  }
}

// ---------------- causal depthwise conv (K=4) + SiLU, gate SiLU, multiply ----------------
__global__ __launch_bounds__(256)
void convgate_kernel(const unsigned short* __restrict__ ug, const float* __restrict__ cw,
                     const float* __restrict__ cb, unsigned short* __restrict__ hin) {
  const int r = blockIdx.x;          // global row (b*S + s)
  const int c0 = threadIdx.x * 8;    // channel base [0,2048)
  const int s = r & (SS - 1);
  float acc[8];
#pragma unroll
  for (int i = 0; i < 8; i++) acc[i] = cb[c0 + i];
  for (int tap = 0; tap < 4; tap++) {
    const int ds = s - 3 + tap;
    if (ds < 0) continue;
    uint4 uv = *(const uint4*)(ug + (size_t)(r - 3 + tap) * 4096 + c0);
    float u[8]; unpack8(uv, u);
#pragma unroll
    for (int i = 0; i < 8; i++) acc[i] += u[i] * cw[tap * DI2 + c0 + i];
  }
  uint4 gv = *(const uint4*)(ug + (size_t)r * 4096 + DI2 + c0);
  float gt[8]; unpack8(gv, gt);
  unsigned short o16[8];
#pragma unroll
  for (int i = 0; i < 8; i++) {
    const float val = acc[i] / (1.0f + __expf(-acc[i]));
    const float gg  = gt[i] / (1.0f + __expf(-gt[i]));
    o16[i] = f2bf(val * gg);
  }
  uint4 ov;
  ov.x = (unsigned)o16[0] | ((unsigned)o16[1] << 16);
  ov.y = (unsigned)o16[2] | ((unsigned)o16[3] << 16);
  ov.z = (unsigned)o16[4] | ((unsigned)o16[5] << 16);
  ov.w = (unsigned)o16[6] | ((unsigned)o16[7] << 16);
  *(uint4*)(hin + (size_t)r * DI2 + c0) = ov;
}

// ---------------- superchunk state: T[gb][e][dk] = sum_t 0.9^(15-t/64) V[t][e] K[t][dk] ----------------
__global__ __launch_bounds__(256)
void state_gemm(const unsigned short* __restrict__ vt, const unsigned short* __restrict__ kt,
                unsigned short* __restrict__ Tb) {
  __shared__ char sA[8192];
  __shared__ char sB[8192];
  const int t = threadIdx.x, lane = t & 63, wid = t >> 6;
  const int wr = wid >> 1, wc = wid & 1;
  const int l15 = lane & 15, lh = lane >> 4;
  const int gb = blockIdx.z, b = gb >> 3, g = gb & 7;
  const int m0 = blockIdx.y * 128, n0 = blockIdx.x * 128;
  const int sr = t >> 2, skb = (t & 3) * 16;
  const size_t kofs = (size_t)g * 1024;
  const unsigned short* Ar0 = vt + (size_t)(b * DD + m0 + sr) * SS + kofs;
  const unsigned short* Ar1 = Ar0 + (size_t)64 * SS;
  const unsigned short* Br0 = kt + (size_t)(b * DD + n0 + sr) * SS + kofs;
  const unsigned short* Br1 = Br0 + (size_t)64 * SS;
  f32x4 acc[4][4] = {};
  for (int k0 = 0; k0 < 1024; k0 += 32) {
    const int ke = k0 + (t & 3) * 8;
    const float w = exp2f((float)(15 - (ke >> 6)) * LOG2_09);
    uint4 ra0 = scale8(*(const uint4*)(Ar0 + ke), w);
    uint4 ra1 = scale8(*(const uint4*)(Ar1 + ke), w);
    uint4 rb0 = *(const uint4*)(Br0 + ke);
    uint4 rb1 = *(const uint4*)(Br1 + ke);
    __syncthreads();
    *(uint4*)(sA + swz64(sr, skb)) = ra0;
    *(uint4*)(sA + swz64(sr + 64, skb)) = ra1;
    *(uint4*)(sB + swz64(sr, skb)) = rb0;
    *(uint4*)(sB + swz64(sr + 64, skb)) = rb1;
    __syncthreads();
    uint4 af[4], bfr[4];
#pragma unroll
    for (int i = 0; i < 4; i++) af[i]  = *(uint4*)(sA + swz64(wr * 64 + i * 16 + l15, lh * 16));
#pragma unroll
    for (int i = 0; i < 4; i++) bfr[i] = *(uint4*)(sB + swz64(wc * 64 + i * 16 + l15, lh * 16));
#pragma unroll
    for (int mf = 0; mf < 4; mf++)
#pragma unroll
      for (int nf = 0; nf < 4; nf++)
        acc[mf][nf] = MFMA(af[mf], bfr[nf], acc[mf][nf]);
  }
  unsigned short* Tg = Tb + ((size_t)gb << 20);
#pragma unroll
  for (int mf = 0; mf < 4; mf++) {
    const int r0 = m0 + wr * 64 + mf * 16 + lh * 4;
#pragma unroll
    for (int nf = 0; nf < 4; nf++) {
      const int c = n0 + wc * 64 + nf * 16 + l15;
#pragma unroll
      for (int jj = 0; jj < 4; jj++)
        Tg[(size_t)(r0 + jj) * 1024 + c] = f2bf(acc[mf][nf][jj]);
    }
  }
}

// ---------------- superchunk prefix (in-place): Minit_g = 0.9^16 Minit_{g-1} + T_{g-1} ----------------
__global__ __launch_bounds__(256)
void prefix_kernel(unsigned short* __restrict__ Tb) {
  const int tid = blockIdx.x * 256 + threadIdx.x;  // 262144 threads
  const int b = tid >> 17, i = tid & 131071;
  unsigned short* p = Tb + (((size_t)b * 8) << 20) + (size_t)i * 8;
  float acc[8] = {};
  for (int g = 0; g < 8; g++) {
    unsigned short* pg = p + ((size_t)g << 20);
    uint4 tv = *(uint4*)pg;
    float tf_[8]; unpack8(tv, tf_);
    uint4 ov;
    ov.x = (unsigned)f2bf(acc[0]) | ((unsigned)f2bf(acc[1]) << 16);
    ov.y = (unsigned)f2bf(acc[2]) | ((unsigned)f2bf(acc[3]) << 16);
    ov.z = (unsigned)f2bf(acc[4]) | ((unsigned)f2bf(acc[5]) << 16);
    ov.w = (unsigned)f2bf(acc[6]) | ((unsigned)f2bf(acc[7]) << 16);
    *(uint4*)pg = ov;
#pragma unroll
    for (int e = 0; e < 8; e++) acc[e] = LAMBDA16 * acc[e] + tf_[e];
  }
}

// ---------------- score: S[qt-block][tb-block] = decay/tril-weighted Q K^T -> sbuf bf16 ----------------
__global__ __launch_bounds__(256)
void score_attn(const unsigned short* __restrict__ q, const unsigned short* __restrict__ k,
                unsigned short* __restrict__ sbuf) {
  __shared__ char sQ[4096];  // [64][32] bf16 linear
  __shared__ char sK[4096];
  const int p = blockIdx.x, gb = blockIdx.y;
  int qt = (int)((sqrtf(8.0f * p + 1.0f) - 1.0f) * 0.5f);
  while ((qt + 1) * (qt + 2) / 2 <= p) qt++;
  while (qt * (qt + 1) / 2 > p) qt--;
  const int tb = p - qt * (qt + 1) / 2;
  const int b = gb >> 3, g = gb & 7;
  const int t = threadIdx.x, lane = t & 63, wid = t >> 6;
  const int l15 = lane & 15, lh = lane >> 4;
  const int srow = wid * 16 + (lane >> 2), scol = (lane & 3) * 8;
  const unsigned short* qg = q + (size_t)(b * SS + g * 1024 + qt * 64 + srow) * DD + scol;
  const unsigned short* kg = k + (size_t)(b * SS + g * 1024 + tb * 64 + srow) * DD + scol;
  char* lQ = sQ + wid * 1024;
  char* lK = sK + wid * 1024;
  f32x4 s[4] = {};
  for (int k0 = 0; k0 < DD; k0 += 32) {
    glds16(qg + k0, lQ);
    glds16(kg + k0, lK);
    __syncthreads();
    uint4 aq = *(uint4*)(sQ + (wid * 16 + l15) * 64 + lh * 16);
#pragma unroll
    for (int tf = 0; tf < 4; tf++) {
      uint4 bk = *(uint4*)(sK + (tf * 16 + l15) * 64 + lh * 16);
      s[tf] = MFMA(aq, bk, s[tf]);
    }
    __syncthreads();
  }
  const bool diag = (tb == qt);
  const float w = diag ? 1.0f : exp2f((float)(qt - 1 - tb) * LOG2_09);
  unsigned short* sb = sbuf + ((size_t)(gb * 16 + qt) * 64) * 1024 + tb * 64;
#pragma unroll
  for (int tf = 0; tf < 4; tf++)
#pragma unroll
    for (int jj = 0; jj < 4; jj++) {
      const int qr = wid * 16 + lh * 4 + jj;  // 0..63
      const int tc = tf * 16 + l15;           // 0..63
      float val = s[tf][jj] * w;
      if (diag && tc > qr) val = 0.0f;
      sb[(size_t)qr * 1024 + tc] = f2bf(val);
    }
}

// ---------------- pv: O[64 q-rows][128 e] = S_strip @ V  (k = (qt+1)*64) ----------------
__global__ __launch_bounds__(256)
void pv_attn(const unsigned short* __restrict__ sbuf, const unsigned short* __restrict__ vt,
             unsigned short* __restrict__ obuf) {
  __shared__ char sA[4096];  // S [64][32] linear
  __shared__ char sB[8192];  // V [128 e][32 t] linear
  const int et = blockIdx.x, qt = blockIdx.y, gb = blockIdx.z;
  const int b = gb >> 3, g = gb & 7;
  const int t = threadIdx.x, lane = t & 63, wid = t >> 6;
  const int l15 = lane & 15, lh = lane >> 4;
  const int srow = wid * 16 + (lane >> 2), scol = (lane & 3) * 8;
  const int e0 = et * 128;
  const unsigned short* Ag = sbuf + ((size_t)(gb * 16 + qt) * 64 + srow) * 1024 + scol;
  const unsigned short* Bg0 = vt + ((size_t)b * DD + e0 + srow) * SS + g * 1024 + scol;
  const unsigned short* Bg1 = Bg0 + (size_t)64 * SS;
  char* lA  = sA + wid * 1024;
  char* lB0 = sB + wid * 1024;
  char* lB1 = sB + 4096 + wid * 1024;
  const int tEnd = (qt + 1) * 64;
  f32x4 o[4][2] = {};
  for (int t0 = 0; t0 < tEnd; t0 += 32) {
    glds16(Ag + t0, lA);
    glds16(Bg0 + t0, lB0);
    glds16(Bg1 + t0, lB1);
    __syncthreads();
    uint4 af[4], vf[2];
#pragma unroll
    for (int mf = 0; mf < 4; mf++) af[mf] = *(uint4*)(sA + (mf * 16 + l15) * 64 + lh * 16);
#pragma unroll
    for (int nf = 0; nf < 2; nf++) vf[nf] = *(uint4*)(sB + (wid * 32 + nf * 16 + l15) * 64 + lh * 16);
#pragma unroll
    for (int mf = 0; mf < 4; mf++)
#pragma unroll
      for (int nf = 0; nf < 2; nf++)
        o[mf][nf] = MFMA(af[mf], vf[nf], o[mf][nf]);
    __syncthreads();
  }
  const size_t qrow0 = (size_t)b * SS + (size_t)g * 1024 + (size_t)qt * 64;
#pragma unroll
  for (int mf = 0; mf < 4; mf++)
#pragma unroll
    for (int nf = 0; nf < 2; nf++)
#pragma unroll
      for (int jj = 0; jj < 4; jj++)
        obuf[(qrow0 + mf * 16 + lh * 4 + jj) * DD + e0 + wid * 32 + nf * 16 + l15] =
            f2bf(o[mf][nf][jj]);
}

// ---------------- cross term: obuf += 0.9^cl(row) * Q @ Minit_g ----------------
__global__ __launch_bounds__(256)
void cross_gemm(const unsigned short* __restrict__ q, const unsigned short* __restrict__ Minit,
                unsigned short* __restrict__ obuf) {
  __shared__ char sA[8192];
  __shared__ char sB[8192];
  const int t = threadIdx.x, lane = t & 63, wid = t >> 6;
  const int wr = wid >> 1, wc = wid & 1;
  const int l15 = lane & 15, lh = lane >> 4;
  const int gb = blockIdx.z, b = gb >> 3, g = gb & 7;
  const int m0 = blockIdx.y * 128, n0 = blockIdx.x * 128;
  const int srow = wid * 16 + (lane >> 2), scol = (lane & 3) * 8;
  const unsigned short* Ar0 = q + (size_t)(b * SS + g * 1024 + m0 + srow) * DD + scol;
  const unsigned short* Ar1 = Ar0 + (size_t)64 * DD;
  const unsigned short* Br0 = Minit + ((size_t)gb << 20) + (size_t)(n0 + srow) * 1024 + scol;
  const unsigned short* Br1 = Br0 + (size_t)64 * 1024;
  char* lA0 = sA + wid * 1024;
  char* lA1 = sA + 4096 + wid * 1024;
  char* lB0 = sB + wid * 1024;
  char* lB1 = sB + 4096 + wid * 1024;
  f32x4 acc[4][4] = {};
  for (int k0 = 0; k0 < 1024; k0 += 32) {
    glds16(Ar0 + k0, lA0);
    glds16(Ar1 + k0, lA1);
    glds16(Br0 + k0, lB0);
    glds16(Br1 + k0, lB1);
    __syncthreads();
    uint4 af[4], bfr[4];
#pragma unroll
    for (int i = 0; i < 4; i++) af[i]  = *(uint4*)(sA + (wr * 64 + i * 16 + l15) * 64 + lh * 16);
#pragma unroll
    for (int i = 0; i < 4; i++) bfr[i] = *(uint4*)(sB + (wc * 64 + i * 16 + l15) * 64 + lh * 16);
#pragma unroll
    for (int mf = 0; mf < 4; mf++)
#pragma unroll
      for (int nf = 0; nf < 4; nf++)
        acc[mf][nf] = MFMA(af[mf], bfr[nf], acc[mf][nf]);
    __syncthreads();
  }
#pragma unroll
  for (int mf = 0; mf < 4; mf++) {
    const int rl = m0 + wr * 64 + mf * 16 + lh * 4;  // row within superchunk [0,1024)
#pragma unroll
    for (int nf = 0; nf < 4; nf++) {
      const int c = n0 + wc * 64 + nf * 16 + l15;
#pragma unroll
      for (int jj = 0; jj < 4; jj++) {
        const int r = rl + jj;
        const float rs = exp2f((float)(r >> 6) * LOG2_09);  // 0.9^chunk-local
        const size_t idx = ((size_t)b * SS + (size_t)g * 1024 + r) * DD + c;
        obuf[idx] = f2bf(bf2f(obuf[idx]) + acc[mf][nf][jj] * rs);
      }
    }
  }
}

extern "C" void kernel_launch(void* const* d_in, const int* in_sizes, int n_in,
                              void* d_out, int out_size, void* d_ws, size_t ws_size,
                              hipStream_t stream) {
  (void)in_sizes; (void)n_in; (void)out_size;
  const float* x      = (const float*)d_in[0];
  const float* norm_w = (const float*)d_in[1];
  const float* w_up   = (const float*)d_in[2];
  const float* w_gate = (const float*)d_in[3];
  const float* w_down = (const float*)d_in[4];
  const float* conv_w = (const float*)d_in[5];
  const float* conv_b = (const float*)d_in[6];
  const float* wq     = (const float*)d_in[7];
  const float* wk     = (const float*)d_in[8];
  const float* wv     = (const float*)d_in[9];
  const float* wo     = (const float*)d_in[10];
  float* out = (float*)d_out;

  const size_t MB = 1ull << 20;
  // Aliased workspace plan (212 MiB). Lifetimes:
  //   [0,32M)    ug -> hbuf -> Tbuf (after QKV gemms)
  //   [32,64M)   ug -> qbuf
  //   [64,96M)   ug -> kbuf
  //   [96,128M)  ug -> ktbuf -> sbuf (after state_gemm)
  //   [128,160M) normed -> hin -> vtbuf
  //   [160,192M) hin tail -> obuf
  //   [192,212M) weight transposes
  if (ws_size < 212 * MB) return;
  char* base = (char*)d_ws;
  unsigned short* ug     = (unsigned short*)(base + 0);
  unsigned short* hbuf   = (unsigned short*)(base + 0);
  unsigned short* Tbuf   = (unsigned short*)(base + 0);
  unsigned short* qbuf   = (unsigned short*)(base + 32 * MB);
  unsigned short* kbuf   = (unsigned short*)(base + 64 * MB);
  unsigned short* ktbuf  = (unsigned short*)(base + 96 * MB);
  unsigned short* sbuf   = (unsigned short*)(base + 96 * MB);
  unsigned short* normed = (unsigned short*)(base + 128 * MB);
  unsigned short* hin    = (unsigned short*)(base + 128 * MB);
  unsigned short* vtbuf  = (unsigned short*)(base + 128 * MB);
  unsigned short* obuf   = (unsigned short*)(base + 160 * MB);
  unsigned short* wugt   = (unsigned short*)(base + 192 * MB);
  unsigned short* wdt    = (unsigned short*)(base + 200 * MB);
  unsigned short* wqt    = (unsigned short*)(base + 204 * MB);
  unsigned short* wkt    = (unsigned short*)(base + 206 * MB);
  unsigned short* wvt    = (unsigned short*)(base + 208 * MB);
  unsigned short* wot    = (unsigned short*)(base + 210 * MB);

  dim3 tb(32, 8);
  transpose_cast<<<dim3(DI2 / 32, DD / 32), tb, 0, stream>>>(w_up,   wugt,                    DD,  DI2);
  transpose_cast<<<dim3(DI2 / 32, DD / 32), tb, 0, stream>>>(w_gate, wugt + (size_t)DI2 * DD, DD,  DI2);
  transpose_cast<<<dim3(DD / 32, DI2 / 32), tb, 0, stream>>>(w_down, wdt, DI2, DD);
  transpose_cast<<<dim3(DD / 32, DD / 32),  tb, 0, stream>>>(wq, wqt, DD, DD);
  transpose_cast<<<dim3(DD / 32, DD / 32),  tb, 0, stream>>>(wk, wkt, DD, DD);
  transpose_cast<<<dim3(DD / 32, DD / 32),  tb, 0, stream>>>(wv, wvt, DD, DD);
  transpose_cast<<<dim3(DD / 32, DD / 32),  tb, 0, stream>>>(wo, wot, DD, DD);

  rmsnorm_kernel<<<NR, 256, 0, stream>>>(x, norm_w, normed);

  // [16384,1024] @ [1024,4096] -> ug (u | gate_pre); grid 64*16 = 1024 blocks
  gemm256<EP_BF16><<<dim3((NR / 256) * (4096 / 256)), 512, 0, stream>>>(
      normed, wugt, ug, nullptr, nullptr, nullptr, NR, 4096, DD, 1.0f);

  convgate_kernel<<<NR, 256, 0, stream>>>(ug, conv_w, conv_b, hin);

  // [16384,2048] @ [2048,1024] -> h; grid 64*4 = 256
  gemm256<EP_BF16><<<dim3((NR / 256) * (DD / 256)), 512, 0, stream>>>(
      hin, wdt, hbuf, nullptr, nullptr, nullptr, NR, DD, DI2, 1.0f);

  gemm256<EP_BF16><<<dim3((NR / 256) * (DD / 256)), 512, 0, stream>>>(
      hbuf, wqt, qbuf, nullptr, nullptr, nullptr, NR, DD, DD, 0.03125f);
  gemm256<EP_BF16_BOTH><<<dim3((NR / 256) * (DD / 256)), 512, 0, stream>>>(
      hbuf, wkt, kbuf, ktbuf, nullptr, nullptr, NR, DD, DD, 1.0f);
  gemm256<EP_BF16_T><<<dim3((NR / 256) * (DD / 256)), 512, 0, stream>>>(
      hbuf, wvt, nullptr, vtbuf, nullptr, nullptr, NR, DD, DD, 1.0f);

  // Hebbian memory via superchunk decomposition (16 chunks / superchunk):
  state_gemm<<<dim3(8, 8, 16), 256, 0, stream>>>(vtbuf, ktbuf, Tbuf);   // uses ktbuf, then dead
  score_attn<<<dim3(136, 16), 256, 0, stream>>>(qbuf, kbuf, sbuf);      // sbuf overlays ktbuf
  prefix_kernel<<<1024, 256, 0, stream>>>(Tbuf);
  pv_attn<<<dim3(8, 16, 16), 256, 0, stream>>>(sbuf, vtbuf, obuf);
  cross_gemm<<<dim3(8, 8, 16), 256, 0, stream>>>(qbuf, Tbuf, obuf);

  // out = obuf @ wo + x; grid 256
  gemm256<EP_F32_RES><<<dim3((NR / 256) * (DD / 256)), 512, 0, stream>>>(
      obuf, wot, nullptr, nullptr, out, x, NR, DD, DD, 1.0f);
}

// Round 8
// 742.979 us; speedup vs baseline: 2.9416x; 1.0235x over previous
//
#include <hip/hip_runtime.h>
#include <cstdint>
#include <cstddef>

#define SS 8192
#define DD 1024
#define DI2 2048
#define NR 16384   // B*S

#define LOG2_09 (-0.152003093445050f)   // log2(0.9)
#define LAMBDA16 0.185302018885184f     // 0.9^16

typedef __attribute__((ext_vector_type(4))) float f32x4;
typedef __attribute__((ext_vector_type(8))) __bf16 bf16x8;

union U16 { uint4 u; bf16x8 b; };

static __device__ __forceinline__ f32x4 MFMA(uint4 a, uint4 b, f32x4 c) {
  U16 ua, ub; ua.u = a; ub.u = b;
  return __builtin_amdgcn_mfma_f32_16x16x32_bf16(ua.b, ub.b, c, 0, 0, 0);
}

static __device__ __forceinline__ unsigned short f2bf(float f) {
  union { float f; unsigned u; } v; v.f = f;
  return (unsigned short)((v.u + 0x7FFFu + ((v.u >> 16) & 1u)) >> 16);
}
static __device__ __forceinline__ float bf2f(unsigned b) {
  union { unsigned u; float f; } v; v.u = b << 16; return v.f;
}
static __device__ __forceinline__ void unpack8(uint4 u, float* f) {
  f[0] = bf2f(u.x & 0xFFFFu); f[1] = bf2f(u.x >> 16);
  f[2] = bf2f(u.y & 0xFFFFu); f[3] = bf2f(u.y >> 16);
  f[4] = bf2f(u.z & 0xFFFFu); f[5] = bf2f(u.z >> 16);
  f[6] = bf2f(u.w & 0xFFFFu); f[7] = bf2f(u.w >> 16);
}

// async global->LDS, 16B per lane. LDS dest is wave-uniform base + lane*16.
static __device__ __forceinline__ void glds16(const unsigned short* g, char* l) {
  __builtin_amdgcn_global_load_lds(
      (const __attribute__((address_space(1))) unsigned int*)g,
      (__attribute__((address_space(3))) unsigned int*)l, 16, 0, 0);
}

// ---------------- weight transpose + cast: out[c][r] = bf16(in[r][c]) ----------------
__global__ __launch_bounds__(256)
void transpose_cast(const float* __restrict__ in, unsigned short* __restrict__ out, int R, int Cc) {
  __shared__ float tile[32][33];
  const int r0 = blockIdx.y * 32, c0 = blockIdx.x * 32;
  const int tx = threadIdx.x, ty = threadIdx.y;
#pragma unroll
  for (int i = 0; i < 4; i++)
    tile[ty + i * 8][tx] = in[(size_t)(r0 + ty + i * 8) * Cc + c0 + tx];
  __syncthreads();
#pragma unroll
  for (int i = 0; i < 4; i++)
    out[(size_t)(c0 + ty + i * 8) * R + r0 + tx] = f2bf(tile[tx][ty + i * 8]);
}

// ---------------- RMSNorm (fp32 in -> bf16 out) ----------------
__global__ __launch_bounds__(256)
void rmsnorm_kernel(const float* __restrict__ x, const float* __restrict__ w,
                    unsigned short* __restrict__ out) {
  const int row = blockIdx.x, t = threadIdx.x;
  const float4 v = ((const float4*)(x + (size_t)row * DD))[t];
  float ss = v.x * v.x + v.y * v.y + v.z * v.z + v.w * v.w;
  __shared__ float sred[256];
  sred[t] = ss;
  __syncthreads();
  for (int o = 128; o > 0; o >>= 1) {
    if (t < o) sred[t] += sred[t + o];
    __syncthreads();
  }
  const float rr = rsqrtf(sred[0] * (1.0f / (float)DD) + 1e-5f);
  const float4 wv = ((const float4*)w)[t];
  uint2 pk;
  pk.x = (unsigned)f2bf(v.x * rr * wv.x) | ((unsigned)f2bf(v.y * rr * wv.y) << 16);
  pk.y = (unsigned)f2bf(v.z * rr * wv.z) | ((unsigned)f2bf(v.w * rr * wv.w) << 16);
  *(uint2*)(out + (size_t)row * DD + t * 4) = pk;
}

// ---------------- 256x256-tile deep-pipelined bf16 GEMM: C = A[M][.] @ Bt[N][.]^T ----------------
// 8 waves (512 thr), wave grid 2M x 4N (128x64 out/wave). BK=32, quad-buffered LDS (128KB),
// depth-3 prefetch, counted vmcnt(8). Per K-tile: 2 phases x 16 MFMA, each phase
// {reads || stage -> barrier -> lgkmcnt(0) -> setprio MFMA -> barrier} (m201 rhythm, 4 bars/tile).
// XCD m-slice remap when mblocks%8==0 (per-XCD A working set = 4MB = L2).
// EP_STATE / EP_CROSS: z-batched small GEMMs over 16 superchunks (runtime lda/ldb/kLen).
enum { EP_BF16 = 0, EP_BF16_BOTH = 1, EP_BF16_T = 2, EP_F32_RES = 3, EP_STATE = 4, EP_CROSS = 5 };

template <int MODE>
__global__ __launch_bounds__(512, 2)
void gemm256(const unsigned short* __restrict__ A, const unsigned short* __restrict__ Bt,
             unsigned short* __restrict__ Cb, unsigned short* __restrict__ Ct,
             float* __restrict__ Cf, const float* __restrict__ resid,
             int M, int N, int kLen, int lda, int ldb, float scale) {
  __shared__ char sLds[131072];
  const int t = threadIdx.x, lane = t & 63, wid = t >> 6;
  const int wr = wid >> 2, wc = wid & 3;
  const int l15 = lane & 15, lh = lane >> 4;
  // block -> (m0, n0)
  const int mblocks = M >> 8;
  int m0, n0;
  if ((mblocks & 7) == 0) {   // XCD m-slice remap
    const int msl = mblocks >> 3;
    const int xcd = (int)blockIdx.x & 7, loc = (int)blockIdx.x >> 3;
    m0 = (xcd * msl + (loc % msl)) << 8;
    n0 = (loc / msl) << 8;
  } else {
    m0 = ((int)blockIdx.x % mblocks) << 8;
    n0 = ((int)blockIdx.x / mblocks) << 8;
  }
  // z-batched bases (state/cross)
  int zb = 0, zg = 0;
  const unsigned short* Abase = A;
  const unsigned short* Bbase = Bt;
  if constexpr (MODE == EP_STATE || MODE == EP_CROSS) {
    const int gb = blockIdx.z;
    zb = gb >> 3; zg = gb & 7;
    if constexpr (MODE == EP_STATE) {
      Abase = A + (size_t)zb * DD * SS + (size_t)zg * 1024;
      Bbase = Bt + (size_t)zb * DD * SS + (size_t)zg * 1024;
    } else {
      Abase = A + ((size_t)zb * SS + (size_t)zg * 1024) * (size_t)lda;
      Bbase = Bt + ((size_t)blockIdx.z << 20);
    }
  }
  // staging source (inverse swizzle on the global column)
  const int srow = wid * 16 + (lane >> 2);                          // 0..127 within half
  const int scol = ((lane & 3) << 3) ^ (((srow >> 1) & 3) << 3);   // bf16 elems
  const unsigned short* pA0 = Abase + (size_t)(m0 + srow) * lda + scol;
  const unsigned short* pA1 = pA0 + (size_t)128 * lda;
  const unsigned short* pB0 = Bbase + (size_t)(n0 + srow) * ldb + scol;
  const unsigned short* pB1 = pB0 + (size_t)128 * ldb;
  const int ldsW = wid * 1024;
  // swizzled read offsets (iteration-invariant)
  int offA[8], offB[4];
#pragma unroll
  for (int mf = 0; mf < 8; mf++) {
    const int r = wr * 128 + mf * 16 + l15;
    offA[mf] = r * 64 + ((lh * 16) ^ (((r >> 1) & 3) << 4));
  }
#pragma unroll
  for (int nf = 0; nf < 4; nf++) {
    const int r = wc * 64 + nf * 16 + l15;
    offB[nf] = r * 64 + ((lh * 16) ^ (((r >> 1) & 3) << 4));
  }
  const int NT = kLen >> 5;
#define BUFA(tt) (sLds + ((tt) & 3) * 32768)
#define BUFB(tt) (sLds + ((tt) & 3) * 32768 + 16384)
#define STAGEA(tt) do { const int _k = (tt) * 32; \
    glds16(pA0 + _k, BUFA(tt) + ldsW); \
    glds16(pA1 + _k, BUFA(tt) + 8192 + ldsW); } while (0)
#define STAGEB(tt) do { const int _k = (tt) * 32; \
    glds16(pB0 + _k, BUFB(tt) + ldsW); \
    glds16(pB1 + _k, BUFB(tt) + 8192 + ldsW); } while (0)
  STAGEA(0); STAGEB(0); STAGEA(1); STAGEB(1); STAGEA(2); STAGEB(2);
  asm volatile("s_waitcnt vmcnt(8)" ::: "memory");   // tile 0 landed (own); barrier -> all waves'
  __builtin_amdgcn_s_barrier();
  f32x4 acc[8][4] = {};
  for (int kt = 0; kt < NT; ++kt) {
    const char* At  = BUFA(kt);
    const char* Bt_ = BUFB(kt);
    uint4 av[4], bv[4], av2[4];
    // ---- phase 0: reads(A0-3,B0-3) || stage-A(kt+3) -> bar -> lgkm -> MFMA mf0-3 -> bar ----
#pragma unroll
    for (int i = 0; i < 4; i++) av[i] = *(const uint4*)(At + offA[i]);
#pragma unroll
    for (int i = 0; i < 4; i++) bv[i] = *(const uint4*)(Bt_ + offB[i]);
    if (kt + 3 < NT) STAGEA(kt + 3);   // writes buf (kt-1)&3: all reads of it done last iter
    __builtin_amdgcn_s_barrier();
    asm volatile("s_waitcnt lgkmcnt(0)" ::: "memory");
    __builtin_amdgcn_sched_barrier(0);
    __builtin_amdgcn_s_setprio(1);
#pragma unroll
    for (int mf = 0; mf < 4; mf++)
#pragma unroll
      for (int nf = 0; nf < 4; nf++)
        acc[mf][nf] = MFMA(av[mf], bv[nf], acc[mf][nf]);
    __builtin_amdgcn_s_setprio(0);
    __builtin_amdgcn_s_barrier();
    // ---- phase 1: reads(A4-7) || stage-B(kt+3) -> bar -> lgkm -> MFMA mf4-7 -> vmcnt -> bar ----
#pragma unroll
    for (int i = 0; i < 4; i++) av2[i] = *(const uint4*)(At + offA[4 + i]);
    if (kt + 3 < NT) STAGEB(kt + 3);
    __builtin_amdgcn_s_barrier();
    asm volatile("s_waitcnt lgkmcnt(0)" ::: "memory");
    __builtin_amdgcn_sched_barrier(0);
    __builtin_amdgcn_s_setprio(1);
#pragma unroll
    for (int mf = 0; mf < 4; mf++)
#pragma unroll
      for (int nf = 0; nf < 4; nf++)
        acc[4 + mf][nf] = MFMA(av2[mf], bv[nf], acc[4 + mf][nf]);
    __builtin_amdgcn_s_setprio(0);
    // counted wait for next tile, BEFORE the end barrier (all waves' DMA then landed)
    if (kt < NT - 3)       { asm volatile("s_waitcnt vmcnt(8)" ::: "memory"); }
    else if (kt == NT - 3) { asm volatile("s_waitcnt vmcnt(4)" ::: "memory"); }
    else if (kt == NT - 2) { asm volatile("s_waitcnt vmcnt(0)" ::: "memory"); }
    __builtin_amdgcn_s_barrier();
  }
#undef STAGEA
#undef STAGEB
#undef BUFA
#undef BUFB
#pragma unroll
  for (int mf = 0; mf < 8; mf++) {
    const int r0 = m0 + wr * 128 + mf * 16 + lh * 4;
#pragma unroll
    for (int nf = 0; nf < 4; nf++) {
      const int c = n0 + wc * 64 + nf * 16 + l15;
      f32x4 v = acc[mf][nf] * scale;
      if constexpr (MODE == EP_F32_RES) {
#pragma unroll
        for (int jj = 0; jj < 4; jj++) {
          const size_t idx = (size_t)(r0 + jj) * N + c;
          Cf[idx] = v[jj] + resid[idx];
        }
      } else if constexpr (MODE == EP_STATE) {
        unsigned short* Tg = Cb + ((size_t)blockIdx.z << 20);
#pragma unroll
        for (int jj = 0; jj < 4; jj++)
          Tg[(size_t)(r0 + jj) * 1024 + c] = f2bf(v[jj]);
      } else if constexpr (MODE == EP_CROSS) {
        const float rs = exp2f((float)(r0 >> 6) * LOG2_09);  // 0.9^chunk-local (rows 4-aligned)
#pragma unroll
        for (int jj = 0; jj < 4; jj++) {
          const size_t idx = ((size_t)zb * SS + (size_t)zg * 1024 + r0 + jj) * DD + c;
          Cb[idx] = f2bf(bf2f(Cb[idx]) + v[jj] * rs);
        }
      } else {
        if constexpr (MODE == EP_BF16 || MODE == EP_BF16_BOTH) {
#pragma unroll
          for (int jj = 0; jj < 4; jj++)
            Cb[(size_t)(r0 + jj) * N + c] = f2bf(v[jj]);
        }
        if constexpr (MODE == EP_BF16_BOTH || MODE == EP_BF16_T) {
          // transposed store: Ct[b][c][s]  (requires N == DD).
          // BOTH (k-proj): pre-scale kt by 0.9^(15-cl) so state_gemm is a plain GEMM.
          const int bb = r0 >> 13, s0 = r0 & (SS - 1);
          float wt = 1.0f;
          if constexpr (MODE == EP_BF16_BOTH)
            wt = exp2f((float)(15 - ((s0 >> 6) & 15)) * LOG2_09);
          uint2 pk;
          pk.x = (unsigned)f2bf(v[0] * wt) | ((unsigned)f2bf(v[1] * wt) << 16);
          pk.y = (unsigned)f2bf(v[2] * wt) | ((unsigned)f2bf(v[3] * wt) << 16);
          *(uint2*)(Ct + ((size_t)bb * DD + c) * SS + s0) = pk;
        }
      }
    }
  }
}

// ---------------- causal depthwise conv (K=4) + SiLU, gate SiLU, multiply ----------------
__global__ __launch_bounds__(256)
void convgate_kernel(const unsigned short* __restrict__ ug, const float* __restrict__ cw,
                     const float* __restrict__ cb, unsigned short* __restrict__ hin) {
  const int r = blockIdx.x;          // global row (b*S + s)
  const int c0 = threadIdx.x * 8;    // channel base [0,2048)
  const int s = r & (SS - 1);
  float acc[8];
#pragma unroll
  for (int i = 0; i < 8; i++) acc[i] = cb[c0 + i];
  for (int tap = 0; tap < 4; tap++) {
    const int ds = s - 3 + tap;
    if (ds < 0) continue;
    uint4 uv = *(const uint4*)(ug + (size_t)(r - 3 + tap) * 4096 + c0);
    float u[8]; unpack8(uv, u);
#pragma unroll
    for (int i = 0; i < 8; i++) acc[i] += u[i] * cw[tap * DI2 + c0 + i];
  }
  uint4 gv = *(const uint4*)(ug + (size_t)r * 4096 + DI2 + c0);
  float gt[8]; unpack8(gv, gt);
  unsigned short o16[8];
#pragma unroll
  for (int i = 0; i < 8; i++) {
    const float val = acc[i] / (1.0f + __expf(-acc[i]));
    const float gg  = gt[i] / (1.0f + __expf(-gt[i]));
    o16[i] = f2bf(val * gg);
  }
  uint4 ov;
  ov.x = (unsigned)o16[0] | ((unsigned)o16[1] << 16);
  ov.y = (unsigned)o16[2] | ((unsigned)o16[3] << 16);
  ov.z = (unsigned)o16[4] | ((unsigned)o16[5] << 16);
  ov.w = (unsigned)o16[6] | ((unsigned)o16[7] << 16);
  *(uint4*)(hin + (size_t)r * DI2 + c0) = ov;
}

// ---------------- superchunk prefix (in-place): Minit_g = 0.9^16 Minit_{g-1} + T_{g-1} ----------------
__global__ __launch_bounds__(256)
void prefix_kernel(unsigned short* __restrict__ Tb) {
  const int tid = blockIdx.x * 256 + threadIdx.x;  // 262144 threads
  const int b = tid >> 17, i = tid & 131071;
  unsigned short* p = Tb + (((size_t)b * 8) << 20) + (size_t)i * 8;
  float acc[8] = {};
  for (int g = 0; g < 8; g++) {
    unsigned short* pg = p + ((size_t)g << 20);
    uint4 tv = *(uint4*)pg;
    float tf_[8]; unpack8(tv, tf_);
    uint4 ov;
    ov.x = (unsigned)f2bf(acc[0]) | ((unsigned)f2bf(acc[1]) << 16);
    ov.y = (unsigned)f2bf(acc[2]) | ((unsigned)f2bf(acc[3]) << 16);
    ov.z = (unsigned)f2bf(acc[4]) | ((unsigned)f2bf(acc[5]) << 16);
    ov.w = (unsigned)f2bf(acc[6]) | ((unsigned)f2bf(acc[7]) << 16);
    *(uint4*)pg = ov;
#pragma unroll
    for (int e = 0; e < 8; e++) acc[e] = LAMBDA16 * acc[e] + tf_[e];
  }
}

// ---------------- score: S[qt-block][tb-block] = decay/tril-weighted Q K^T -> sbuf bf16 ----------------
__global__ __launch_bounds__(256)
void score_attn(const unsigned short* __restrict__ q, const unsigned short* __restrict__ k,
                unsigned short* __restrict__ sbuf) {
  __shared__ char sQ[4096];  // [64][32] bf16 linear
  __shared__ char sK[4096];
  const int p = blockIdx.x, gb = blockIdx.y;
  int qt = (int)((sqrtf(8.0f * p + 1.0f) - 1.0f) * 0.5f);
  while ((qt + 1) * (qt + 2) / 2 <= p) qt++;
  while (qt * (qt + 1) / 2 > p) qt--;
  const int tb = p - qt * (qt + 1) / 2;
  const int b = gb >> 3, g = gb & 7;
  const int t = threadIdx.x, lane = t & 63, wid = t >> 6;
  const int l15 = lane & 15, lh = lane >> 4;
  const int srow = wid * 16 + (lane >> 2), scol = (lane & 3) * 8;
  const unsigned short* qg = q + (size_t)(b * SS + g * 1024 + qt * 64 + srow) * DD + scol;
  const unsigned short* kg = k + (size_t)(b * SS + g * 1024 + tb * 64 + srow) * DD + scol;
  char* lQ = sQ + wid * 1024;
  char* lK = sK + wid * 1024;
  f32x4 s[4] = {};
  for (int k0 = 0; k0 < DD; k0 += 32) {
    glds16(qg + k0, lQ);
    glds16(kg + k0, lK);
    __syncthreads();
    uint4 aq = *(uint4*)(sQ + (wid * 16 + l15) * 64 + lh * 16);
#pragma unroll
    for (int tf = 0; tf < 4; tf++) {
      uint4 bk = *(uint4*)(sK + (tf * 16 + l15) * 64 + lh * 16);
      s[tf] = MFMA(aq, bk, s[tf]);
    }
    __syncthreads();
  }
  const bool diag = (tb == qt);
  const float w = diag ? 1.0f : exp2f((float)(qt - 1 - tb) * LOG2_09);
  unsigned short* sb = sbuf + ((size_t)(gb * 16 + qt) * 64) * 1024 + tb * 64;
#pragma unroll
  for (int tf = 0; tf < 4; tf++)
#pragma unroll
    for (int jj = 0; jj < 4; jj++) {
      const int qr = wid * 16 + lh * 4 + jj;  // 0..63
      const int tc = tf * 16 + l15;           // 0..63
      float val = s[tf][jj] * w;
      if (diag && tc > qr) val = 0.0f;
      sb[(size_t)qr * 1024 + tc] = f2bf(val);
    }
}

// ---------------- pv: O[64 q-rows][128 e] = S_strip @ V  (k = (qt+1)*64) ----------------
__global__ __launch_bounds__(256)
void pv_attn(const unsigned short* __restrict__ sbuf, const unsigned short* __restrict__ vt,
             unsigned short* __restrict__ obuf) {
  __shared__ char sA[4096];  // S [64][32] linear
  __shared__ char sB[8192];  // V [128 e][32 t] linear
  const int et = blockIdx.x, qt = blockIdx.y, gb = blockIdx.z;
  const int b = gb >> 3, g = gb & 7;
  const int t = threadIdx.x, lane = t & 63, wid = t >> 6;
  const int l15 = lane & 15, lh = lane >> 4;
  const int srow = wid * 16 + (lane >> 2), scol = (lane & 3) * 8;
  const int e0 = et * 128;
  const unsigned short* Ag = sbuf + ((size_t)(gb * 16 + qt) * 64 + srow) * 1024 + scol;
  const unsigned short* Bg0 = vt + ((size_t)b * DD + e0 + srow) * SS + g * 1024 + scol;
  const unsigned short* Bg1 = Bg0 + (size_t)64 * SS;
  char* lA  = sA + wid * 1024;
  char* lB0 = sB + wid * 1024;
  char* lB1 = sB + 4096 + wid * 1024;
  const int tEnd = (qt + 1) * 64;
  f32x4 o[4][2] = {};
  for (int t0 = 0; t0 < tEnd; t0 += 32) {
    glds16(Ag + t0, lA);
    glds16(Bg0 + t0, lB0);
    glds16(Bg1 + t0, lB1);
    __syncthreads();
    uint4 af[4], vf[2];
#pragma unroll
    for (int mf = 0; mf < 4; mf++) af[mf] = *(uint4*)(sA + (mf * 16 + l15) * 64 + lh * 16);
#pragma unroll
    for (int nf = 0; nf < 2; nf++) vf[nf] = *(uint4*)(sB + (wid * 32 + nf * 16 + l15) * 64 + lh * 16);
#pragma unroll
    for (int mf = 0; mf < 4; mf++)
#pragma unroll
      for (int nf = 0; nf < 2; nf++)
        o[mf][nf] = MFMA(af[mf], vf[nf], o[mf][nf]);
    __syncthreads();
  }
  const size_t qrow0 = (size_t)b * SS + (size_t)g * 1024 + (size_t)qt * 64;
#pragma unroll
  for (int mf = 0; mf < 4; mf++)
#pragma unroll
    for (int nf = 0; nf < 2; nf++)
#pragma unroll
      for (int jj = 0; jj < 4; jj++)
        obuf[(qrow0 + mf * 16 + lh * 4 + jj) * DD + e0 + wid * 32 + nf * 16 + l15] =
            f2bf(o[mf][nf][jj]);
}

extern "C" void kernel_launch(void* const* d_in, const int* in_sizes, int n_in,
                              void* d_out, int out_size, void* d_ws, size_t ws_size,
                              hipStream_t stream) {
  (void)in_sizes; (void)n_in; (void)out_size;
  const float* x      = (const float*)d_in[0];
  const float* norm_w = (const float*)d_in[1];
  const float* w_up   = (const float*)d_in[2];
  const float* w_gate = (const float*)d_in[3];
  const float* w_down = (const float*)d_in[4];
  const float* conv_w = (const float*)d_in[5];
  const float* conv_b = (const float*)d_in[6];
  const float* wq     = (const float*)d_in[7];
  const float* wk     = (const float*)d_in[8];
  const float* wv     = (const float*)d_in[9];
  const float* wo     = (const float*)d_in[10];
  float* out = (float*)d_out;

  const size_t MB = 1ull << 20;
  // Aliased workspace plan (212 MiB). Lifetimes:
  //   [0,32M)    ug -> hbuf -> Tbuf (after QKV gemms)
  //   [32,64M)   ug -> qbuf
  //   [64,96M)   ug -> kbuf
  //   [96,128M)  ug -> ktbuf (pre-scaled by decay) -> sbuf (after state_gemm)
  //   [128,160M) normed -> hin -> vtbuf
  //   [160,192M) hin tail -> obuf
  //   [192,212M) weight transposes
  if (ws_size < 212 * MB) return;
  char* base = (char*)d_ws;
  unsigned short* ug     = (unsigned short*)(base + 0);
  unsigned short* hbuf   = (unsigned short*)(base + 0);
  unsigned short* Tbuf   = (unsigned short*)(base + 0);
  unsigned short* qbuf   = (unsigned short*)(base + 32 * MB);
  unsigned short* kbuf   = (unsigned short*)(base + 64 * MB);
  unsigned short* ktbuf  = (unsigned short*)(base + 96 * MB);
  unsigned short* sbuf   = (unsigned short*)(base + 96 * MB);
  unsigned short* normed = (unsigned short*)(base + 128 * MB);
  unsigned short* hin    = (unsigned short*)(base + 128 * MB);
  unsigned short* vtbuf  = (unsigned short*)(base + 128 * MB);
  unsigned short* obuf   = (unsigned short*)(base + 160 * MB);
  unsigned short* wugt   = (unsigned short*)(base + 192 * MB);
  unsigned short* wdt    = (unsigned short*)(base + 200 * MB);
  unsigned short* wqt    = (unsigned short*)(base + 204 * MB);
  unsigned short* wkt    = (unsigned short*)(base + 206 * MB);
  unsigned short* wvt    = (unsigned short*)(base + 208 * MB);
  unsigned short* wot    = (unsigned short*)(base + 210 * MB);

  dim3 tb(32, 8);
  transpose_cast<<<dim3(DI2 / 32, DD / 32), tb, 0, stream>>>(w_up,   wugt,                    DD,  DI2);
  transpose_cast<<<dim3(DI2 / 32, DD / 32), tb, 0, stream>>>(w_gate, wugt + (size_t)DI2 * DD, DD,  DI2);
  transpose_cast<<<dim3(DD / 32, DI2 / 32), tb, 0, stream>>>(w_down, wdt, DI2, DD);
  transpose_cast<<<dim3(DD / 32, DD / 32),  tb, 0, stream>>>(wq, wqt, DD, DD);
  transpose_cast<<<dim3(DD / 32, DD / 32),  tb, 0, stream>>>(wk, wkt, DD, DD);
  transpose_cast<<<dim3(DD / 32, DD / 32),  tb, 0, stream>>>(wv, wvt, DD, DD);
  transpose_cast<<<dim3(DD / 32, DD / 32),  tb, 0, stream>>>(wo, wot, DD, DD);

  rmsnorm_kernel<<<NR, 256, 0, stream>>>(x, norm_w, normed);

  // [16384,1024] @ [1024,4096] -> ug (u | gate_pre); grid 64*16 = 1024 blocks
  gemm256<EP_BF16><<<dim3((NR / 256) * (4096 / 256)), 512, 0, stream>>>(
      normed, wugt, ug, nullptr, nullptr, nullptr, NR, 4096, DD, DD, DD, 1.0f);

  convgate_kernel<<<NR, 256, 0, stream>>>(ug, conv_w, conv_b, hin);

  // [16384,2048] @ [2048,1024] -> h; grid 64*4 = 256
  gemm256<EP_BF16><<<dim3((NR / 256) * (DD / 256)), 512, 0, stream>>>(
      hin, wdt, hbuf, nullptr, nullptr, nullptr, NR, DD, DI2, DI2, DI2, 1.0f);

  gemm256<EP_BF16><<<dim3((NR / 256) * (DD / 256)), 512, 0, stream>>>(
      hbuf, wqt, qbuf, nullptr, nullptr, nullptr, NR, DD, DD, DD, DD, 0.03125f);
  gemm256<EP_BF16_BOTH><<<dim3((NR / 256) * (DD / 256)), 512, 0, stream>>>(
      hbuf, wkt, kbuf, ktbuf, nullptr, nullptr, NR, DD, DD, DD, DD, 1.0f);
  gemm256<EP_BF16_T><<<dim3((NR / 256) * (DD / 256)), 512, 0, stream>>>(
      hbuf, wvt, nullptr, vtbuf, nullptr, nullptr, NR, DD, DD, DD, DD, 1.0f);

  // Hebbian memory via superchunk decomposition (16 chunks / superchunk):
  // T[gb] = (decayed V^T) @ K-slice  — ktbuf already carries the decay weights.
  gemm256<EP_STATE><<<dim3(16, 1, 16), 512, 0, stream>>>(
      vtbuf, ktbuf, Tbuf, nullptr, nullptr, nullptr, 1024, 1024, 1024, SS, SS, 1.0f);
  score_attn<<<dim3(136, 16), 256, 0, stream>>>(qbuf, kbuf, sbuf);      // sbuf overlays ktbuf
  prefix_kernel<<<1024, 256, 0, stream>>>(Tbuf);
  pv_attn<<<dim3(8, 16, 16), 256, 0, stream>>>(sbuf, vtbuf, obuf);
  gemm256<EP_CROSS><<<dim3(16, 1, 16), 512, 0, stream>>>(
      qbuf, Tbuf, obuf, nullptr, nullptr, nullptr, 1024, 1024, 1024, DD, 1024, 1.0f);

  // out = obuf @ wo + x; grid 256
  gemm256<EP_F32_RES><<<dim3((NR / 256) * (DD / 256)), 512, 0, stream>>>(
      obuf, wot, nullptr, nullptr, out, x, NR, DD, DD, DD, DD, 1.0f);
}

// Round 9
// 732.904 us; speedup vs baseline: 2.9820x; 1.0137x over previous
//
#include <hip/hip_runtime.h>
#include <cstdint>
#include <cstddef>

#define SS 8192
#define DD 1024
#define DI2 2048
#define NR 16384   // B*S

#define LOG2_09 (-0.152003093445050f)   // log2(0.9)
#define LAMBDA16 0.185302018885184f     // 0.9^16

typedef __attribute__((ext_vector_type(4))) float f32x4;
typedef __attribute__((ext_vector_type(8))) __bf16 bf16x8;

union U16 { uint4 u; bf16x8 b; };

static __device__ __forceinline__ f32x4 MFMA(uint4 a, uint4 b, f32x4 c) {
  U16 ua, ub; ua.u = a; ub.u = b;
  return __builtin_amdgcn_mfma_f32_16x16x32_bf16(ua.b, ub.b, c, 0, 0, 0);
}

static __device__ __forceinline__ unsigned short f2bf(float f) {
  union { float f; unsigned u; } v; v.f = f;
  return (unsigned short)((v.u + 0x7FFFu + ((v.u >> 16) & 1u)) >> 16);
}
static __device__ __forceinline__ float bf2f(unsigned b) {
  union { unsigned u; float f; } v; v.u = b << 16; return v.f;
}
static __device__ __forceinline__ void unpack8(uint4 u, float* f) {
  f[0] = bf2f(u.x & 0xFFFFu); f[1] = bf2f(u.x >> 16);
  f[2] = bf2f(u.y & 0xFFFFu); f[3] = bf2f(u.y >> 16);
  f[4] = bf2f(u.z & 0xFFFFu); f[5] = bf2f(u.z >> 16);
  f[6] = bf2f(u.w & 0xFFFFu); f[7] = bf2f(u.w >> 16);
}

// async global->LDS, 16B per lane. LDS dest is wave-uniform base + lane*16.
static __device__ __forceinline__ void glds16(const unsigned short* g, char* l) {
  __builtin_amdgcn_global_load_lds(
      (const __attribute__((address_space(1))) unsigned int*)g,
      (__attribute__((address_space(3))) unsigned int*)l, 16, 0, 0);
}

// ---------------- weight transpose + cast: out[c][r] = bf16(in[r][c]) ----------------
__global__ __launch_bounds__(256)
void transpose_cast(const float* __restrict__ in, unsigned short* __restrict__ out, int R, int Cc) {
  __shared__ float tile[32][33];
  const int r0 = blockIdx.y * 32, c0 = blockIdx.x * 32;
  const int tx = threadIdx.x, ty = threadIdx.y;
#pragma unroll
  for (int i = 0; i < 4; i++)
    tile[ty + i * 8][tx] = in[(size_t)(r0 + ty + i * 8) * Cc + c0 + tx];
  __syncthreads();
#pragma unroll
  for (int i = 0; i < 4; i++)
    out[(size_t)(c0 + ty + i * 8) * R + r0 + tx] = f2bf(tile[tx][ty + i * 8]);
}

// ---------------- RMSNorm (fp32 in -> bf16 out) ----------------
__global__ __launch_bounds__(256)
void rmsnorm_kernel(const float* __restrict__ x, const float* __restrict__ w,
                    unsigned short* __restrict__ out) {
  const int row = blockIdx.x, t = threadIdx.x;
  const float4 v = ((const float4*)(x + (size_t)row * DD))[t];
  float ss = v.x * v.x + v.y * v.y + v.z * v.z + v.w * v.w;
  __shared__ float sred[256];
  sred[t] = ss;
  __syncthreads();
  for (int o = 128; o > 0; o >>= 1) {
    if (t < o) sred[t] += sred[t + o];
    __syncthreads();
  }
  const float rr = rsqrtf(sred[0] * (1.0f / (float)DD) + 1e-5f);
  const float4 wv = ((const float4*)w)[t];
  uint2 pk;
  pk.x = (unsigned)f2bf(v.x * rr * wv.x) | ((unsigned)f2bf(v.y * rr * wv.y) << 16);
  pk.y = (unsigned)f2bf(v.z * rr * wv.z) | ((unsigned)f2bf(v.w * rr * wv.w) << 16);
  *(uint2*)(out + (size_t)row * DD + t * 4) = pk;
}

// ---------------- 256x256-tile deep-pipelined bf16 GEMM: C = A[M][.] @ Bt[N][.]^T ----------------
// 8 waves (512 thr), wave grid 2M x 4N (128x64 out/wave). BK=32, quad-buffered LDS (128KB),
// depth-3 prefetch, counted vmcnt(8). Per K-tile: 2 phases x 16 MFMA, each phase
// {reads || stage -> lgkm -> setprio MFMA -> barrier} (round-7 rhythm, 2 bars/tile —
// the 4-bar variant regressed: r8 upgate 162 vs 152 us).
// XCD m-slice remap when mblocks%8==0 (per-XCD A working set = 4MB = L2).
// EP_STATE / EP_CROSS: z-batched small GEMMs over 16 superchunks (runtime lda/ldb/kLen).
enum { EP_BF16 = 0, EP_BF16_BOTH = 1, EP_BF16_T = 2, EP_F32_RES = 3, EP_STATE = 4, EP_CROSS = 5 };

template <int MODE>
__global__ __launch_bounds__(512, 2)
void gemm256(const unsigned short* __restrict__ A, const unsigned short* __restrict__ Bt,
             unsigned short* __restrict__ Cb, unsigned short* __restrict__ Ct,
             float* __restrict__ Cf, const float* __restrict__ resid,
             int M, int N, int kLen, int lda, int ldb, float scale) {
  __shared__ char sLds[131072];
  const int t = threadIdx.x, lane = t & 63, wid = t >> 6;
  const int wr = wid >> 2, wc = wid & 3;
  const int l15 = lane & 15, lh = lane >> 4;
  // block -> (m0, n0)
  const int mblocks = M >> 8;
  int m0, n0;
  if ((mblocks & 7) == 0) {   // XCD m-slice remap
    const int msl = mblocks >> 3;
    const int xcd = (int)blockIdx.x & 7, loc = (int)blockIdx.x >> 3;
    m0 = (xcd * msl + (loc % msl)) << 8;
    n0 = (loc / msl) << 8;
  } else {
    m0 = ((int)blockIdx.x % mblocks) << 8;
    n0 = ((int)blockIdx.x / mblocks) << 8;
  }
  // z-batched bases (state/cross)
  int zb = 0, zg = 0;
  const unsigned short* Abase = A;
  const unsigned short* Bbase = Bt;
  if constexpr (MODE == EP_STATE || MODE == EP_CROSS) {
    const int gb = blockIdx.z;
    zb = gb >> 3; zg = gb & 7;
    if constexpr (MODE == EP_STATE) {
      Abase = A + (size_t)zb * DD * SS + (size_t)zg * 1024;
      Bbase = Bt + (size_t)zb * DD * SS + (size_t)zg * 1024;
    } else {
      Abase = A + ((size_t)zb * SS + (size_t)zg * 1024) * (size_t)lda;
      Bbase = Bt + ((size_t)blockIdx.z << 20);
    }
  }
  // staging source (inverse swizzle on the global column)
  const int srow = wid * 16 + (lane >> 2);                          // 0..127 within half
  const int scol = ((lane & 3) << 3) ^ (((srow >> 1) & 3) << 3);   // bf16 elems
  const unsigned short* pA0 = Abase + (size_t)(m0 + srow) * lda + scol;
  const unsigned short* pA1 = pA0 + (size_t)128 * lda;
  const unsigned short* pB0 = Bbase + (size_t)(n0 + srow) * ldb + scol;
  const unsigned short* pB1 = pB0 + (size_t)128 * ldb;
  const int ldsW = wid * 1024;
  // swizzled read offsets (iteration-invariant)
  int offA[8], offB[4];
#pragma unroll
  for (int mf = 0; mf < 8; mf++) {
    const int r = wr * 128 + mf * 16 + l15;
    offA[mf] = r * 64 + ((lh * 16) ^ (((r >> 1) & 3) << 4));
  }
#pragma unroll
  for (int nf = 0; nf < 4; nf++) {
    const int r = wc * 64 + nf * 16 + l15;
    offB[nf] = r * 64 + ((lh * 16) ^ (((r >> 1) & 3) << 4));
  }
  const int NT = kLen >> 5;
#define BUFA(tt) (sLds + ((tt) & 3) * 32768)
#define BUFB(tt) (sLds + ((tt) & 3) * 32768 + 16384)
#define STAGEA(tt) do { const int _k = (tt) * 32; \
    glds16(pA0 + _k, BUFA(tt) + ldsW); \
    glds16(pA1 + _k, BUFA(tt) + 8192 + ldsW); } while (0)
#define STAGEB(tt) do { const int _k = (tt) * 32; \
    glds16(pB0 + _k, BUFB(tt) + ldsW); \
    glds16(pB1 + _k, BUFB(tt) + 8192 + ldsW); } while (0)
  STAGEA(0); STAGEB(0); STAGEA(1); STAGEB(1); STAGEA(2); STAGEB(2);
  asm volatile("s_waitcnt vmcnt(8)" ::: "memory");   // tile 0 landed (own); barrier -> all waves'
  __builtin_amdgcn_s_barrier();
  f32x4 acc[8][4] = {};
  for (int kt = 0; kt < NT; ++kt) {
    const char* At  = BUFA(kt);
    const char* Bt_ = BUFB(kt);
    uint4 av[4], bv[4], av2[4];
    // ---- phase 0: reads(A0-3,B0-3) || stage-A(kt+3) -> lgkm -> MFMA mf0-3 -> bar ----
#pragma unroll
    for (int i = 0; i < 4; i++) av[i] = *(const uint4*)(At + offA[i]);
#pragma unroll
    for (int i = 0; i < 4; i++) bv[i] = *(const uint4*)(Bt_ + offB[i]);
    if (kt + 3 < NT) STAGEA(kt + 3);   // writes buf (kt-1)&3: all reads of it done last iter
    asm volatile("s_waitcnt lgkmcnt(0)" ::: "memory");
    __builtin_amdgcn_sched_barrier(0);
    __builtin_amdgcn_s_setprio(1);
#pragma unroll
    for (int mf = 0; mf < 4; mf++)
#pragma unroll
      for (int nf = 0; nf < 4; nf++)
        acc[mf][nf] = MFMA(av[mf], bv[nf], acc[mf][nf]);
    __builtin_amdgcn_s_setprio(0);
    __builtin_amdgcn_s_barrier();
    // ---- phase 1: reads(A4-7) || stage-B(kt+3) -> lgkm -> MFMA mf4-7 -> vmcnt -> bar ----
#pragma unroll
    for (int i = 0; i < 4; i++) av2[i] = *(const uint4*)(At + offA[4 + i]);
    if (kt + 3 < NT) STAGEB(kt + 3);
    asm volatile("s_waitcnt lgkmcnt(0)" ::: "memory");
    __builtin_amdgcn_sched_barrier(0);
    __builtin_amdgcn_s_setprio(1);
#pragma unroll
    for (int mf = 0; mf < 4; mf++)
#pragma unroll
      for (int nf = 0; nf < 4; nf++)
        acc[4 + mf][nf] = MFMA(av2[mf], bv[nf], acc[4 + mf][nf]);
    __builtin_amdgcn_s_setprio(0);
    // counted wait for next tile, BEFORE the end barrier (all waves' DMA then landed)
    if (kt < NT - 3)       { asm volatile("s_waitcnt vmcnt(8)" ::: "memory"); }
    else if (kt == NT - 3) { asm volatile("s_waitcnt vmcnt(4)" ::: "memory"); }
    else if (kt == NT - 2) { asm volatile("s_waitcnt vmcnt(0)" ::: "memory"); }
    __builtin_amdgcn_s_barrier();
  }
#undef STAGEA
#undef STAGEB
#undef BUFA
#undef BUFB
#pragma unroll
  for (int mf = 0; mf < 8; mf++) {
    const int r0 = m0 + wr * 128 + mf * 16 + lh * 4;
#pragma unroll
    for (int nf = 0; nf < 4; nf++) {
      const int c = n0 + wc * 64 + nf * 16 + l15;
      f32x4 v = acc[mf][nf] * scale;
      if constexpr (MODE == EP_F32_RES) {
#pragma unroll
        for (int jj = 0; jj < 4; jj++) {
          const size_t idx = (size_t)(r0 + jj) * N + c;
          Cf[idx] = v[jj] + resid[idx];
        }
      } else if constexpr (MODE == EP_STATE) {
        unsigned short* Tg = Cb + ((size_t)blockIdx.z << 20);
#pragma unroll
        for (int jj = 0; jj < 4; jj++)
          Tg[(size_t)(r0 + jj) * 1024 + c] = f2bf(v[jj]);
      } else if constexpr (MODE == EP_CROSS) {
        const float rs = exp2f((float)(r0 >> 6) * LOG2_09);  // 0.9^chunk-local (rows 4-aligned)
#pragma unroll
        for (int jj = 0; jj < 4; jj++) {
          const size_t idx = ((size_t)zb * SS + (size_t)zg * 1024 + r0 + jj) * DD + c;
          Cb[idx] = f2bf(bf2f(Cb[idx]) + v[jj] * rs);
        }
      } else {
        if constexpr (MODE == EP_BF16 || MODE == EP_BF16_BOTH) {
#pragma unroll
          for (int jj = 0; jj < 4; jj++)
            Cb[(size_t)(r0 + jj) * N + c] = f2bf(v[jj]);
        }
        if constexpr (MODE == EP_BF16_BOTH || MODE == EP_BF16_T) {
          // transposed store: Ct[b][c][s]  (requires N == DD).
          // BOTH (k-proj): pre-scale kt by 0.9^(15-cl) so state_gemm is a plain GEMM.
          const int bb = r0 >> 13, s0 = r0 & (SS - 1);
          float wt = 1.0f;
          if constexpr (MODE == EP_BF16_BOTH)
            wt = exp2f((float)(15 - ((s0 >> 6) & 15)) * LOG2_09);
          uint2 pk;
          pk.x = (unsigned)f2bf(v[0] * wt) | ((unsigned)f2bf(v[1] * wt) << 16);
          pk.y = (unsigned)f2bf(v[2] * wt) | ((unsigned)f2bf(v[3] * wt) << 16);
          *(uint2*)(Ct + ((size_t)bb * DD + c) * SS + s0) = pk;
        }
      }
    }
  }
}

// ---------------- causal depthwise conv (K=4) + SiLU, gate SiLU, multiply ----------------
__global__ __launch_bounds__(256)
void convgate_kernel(const unsigned short* __restrict__ ug, const float* __restrict__ cw,
                     const float* __restrict__ cb, unsigned short* __restrict__ hin) {
  const int r = blockIdx.x;          // global row (b*S + s)
  const int c0 = threadIdx.x * 8;    // channel base [0,2048)
  const int s = r & (SS - 1);
  float acc[8];
#pragma unroll
  for (int i = 0; i < 8; i++) acc[i] = cb[c0 + i];
  for (int tap = 0; tap < 4; tap++) {
    const int ds = s - 3 + tap;
    if (ds < 0) continue;
    uint4 uv = *(const uint4*)(ug + (size_t)(r - 3 + tap) * 4096 + c0);
    float u[8]; unpack8(uv, u);
#pragma unroll
    for (int i = 0; i < 8; i++) acc[i] += u[i] * cw[tap * DI2 + c0 + i];
  }
  uint4 gv = *(const uint4*)(ug + (size_t)r * 4096 + DI2 + c0);
  float gt[8]; unpack8(gv, gt);
  unsigned short o16[8];
#pragma unroll
  for (int i = 0; i < 8; i++) {
    const float val = acc[i] / (1.0f + __expf(-acc[i]));
    const float gg  = gt[i] / (1.0f + __expf(-gt[i]));
    o16[i] = f2bf(val * gg);
  }
  uint4 ov;
  ov.x = (unsigned)o16[0] | ((unsigned)o16[1] << 16);
  ov.y = (unsigned)o16[2] | ((unsigned)o16[3] << 16);
  ov.z = (unsigned)o16[4] | ((unsigned)o16[5] << 16);
  ov.w = (unsigned)o16[6] | ((unsigned)o16[7] << 16);
  *(uint4*)(hin + (size_t)r * DI2 + c0) = ov;
}

// ---------------- superchunk prefix (in-place): Minit_g = 0.9^16 Minit_{g-1} + T_{g-1} ----------------
__global__ __launch_bounds__(256)
void prefix_kernel(unsigned short* __restrict__ Tb) {
  const int tid = blockIdx.x * 256 + threadIdx.x;  // 262144 threads
  const int b = tid >> 17, i = tid & 131071;
  unsigned short* p = Tb + (((size_t)b * 8) << 20) + (size_t)i * 8;
  float acc[8] = {};
  for (int g = 0; g < 8; g++) {
    unsigned short* pg = p + ((size_t)g << 20);
    uint4 tv = *(uint4*)pg;
    float tf_[8]; unpack8(tv, tf_);
    uint4 ov;
    ov.x = (unsigned)f2bf(acc[0]) | ((unsigned)f2bf(acc[1]) << 16);
    ov.y = (unsigned)f2bf(acc[2]) | ((unsigned)f2bf(acc[3]) << 16);
    ov.z = (unsigned)f2bf(acc[4]) | ((unsigned)f2bf(acc[5]) << 16);
    ov.w = (unsigned)f2bf(acc[6]) | ((unsigned)f2bf(acc[7]) << 16);
    *(uint4*)pg = ov;
#pragma unroll
    for (int e = 0; e < 8; e++) acc[e] = LAMBDA16 * acc[e] + tf_[e];
  }
}

// ---------------- score: S[qt-block][tb-block] = decay/tril-weighted Q K^T -> sbuf bf16 ----------------
__global__ __launch_bounds__(256)
void score_attn(const unsigned short* __restrict__ q, const unsigned short* __restrict__ k,
                unsigned short* __restrict__ sbuf) {
  __shared__ char sQ[4096];  // [64][32] bf16 linear
  __shared__ char sK[4096];
  const int p = blockIdx.x, gb = blockIdx.y;
  int qt = (int)((sqrtf(8.0f * p + 1.0f) - 1.0f) * 0.5f);
  while ((qt + 1) * (qt + 2) / 2 <= p) qt++;
  while (qt * (qt + 1) / 2 > p) qt--;
  const int tb = p - qt * (qt + 1) / 2;
  const int b = gb >> 3, g = gb & 7;
  const int t = threadIdx.x, lane = t & 63, wid = t >> 6;
  const int l15 = lane & 15, lh = lane >> 4;
  const int srow = wid * 16 + (lane >> 2), scol = (lane & 3) * 8;
  const unsigned short* qg = q + (size_t)(b * SS + g * 1024 + qt * 64 + srow) * DD + scol;
  const unsigned short* kg = k + (size_t)(b * SS + g * 1024 + tb * 64 + srow) * DD + scol;
  char* lQ = sQ + wid * 1024;
  char* lK = sK + wid * 1024;
  f32x4 s[4] = {};
  for (int k0 = 0; k0 < DD; k0 += 32) {
    glds16(qg + k0, lQ);
    glds16(kg + k0, lK);
    __syncthreads();
    uint4 aq = *(uint4*)(sQ + (wid * 16 + l15) * 64 + lh * 16);
#pragma unroll
    for (int tf = 0; tf < 4; tf++) {
      uint4 bk = *(uint4*)(sK + (tf * 16 + l15) * 64 + lh * 16);
      s[tf] = MFMA(aq, bk, s[tf]);
    }
    __syncthreads();
  }
  const bool diag = (tb == qt);
  const float w = diag ? 1.0f : exp2f((float)(qt - 1 - tb) * LOG2_09);
  unsigned short* sb = sbuf + ((size_t)(gb * 16 + qt) * 64) * 1024 + tb * 64;
#pragma unroll
  for (int tf = 0; tf < 4; tf++)
#pragma unroll
    for (int jj = 0; jj < 4; jj++) {
      const int qr = wid * 16 + lh * 4 + jj;  // 0..63
      const int tc = tf * 16 + l15;           // 0..63
      float val = s[tf][jj] * w;
      if (diag && tc > qr) val = 0.0f;
      sb[(size_t)qr * 1024 + tc] = f2bf(val);
    }
}

// ---------------- pv: O[64 q-rows][128 e] = S_strip @ V  (k = (qt+1)*64) ----------------
__global__ __launch_bounds__(256)
void pv_attn(const unsigned short* __restrict__ sbuf, const unsigned short* __restrict__ vt,
             unsigned short* __restrict__ obuf) {
  __shared__ char sA[4096];  // S [64][32] linear
  __shared__ char sB[8192];  // V [128 e][32 t] linear
  const int et = blockIdx.x, qt = blockIdx.y, gb = blockIdx.z;
  const int b = gb >> 3, g = gb & 7;
  const int t = threadIdx.x, lane = t & 63, wid = t >> 6;
  const int l15 = lane & 15, lh = lane >> 4;
  const int srow = wid * 16 + (lane >> 2), scol = (lane & 3) * 8;
  const int e0 = et * 128;
  const unsigned short* Ag = sbuf + ((size_t)(gb * 16 + qt) * 64 + srow) * 1024 + scol;
  const unsigned short* Bg0 = vt + ((size_t)b * DD + e0 + srow) * SS + g * 1024 + scol;
  const unsigned short* Bg1 = Bg0 + (size_t)64 * SS;
  char* lA  = sA + wid * 1024;
  char* lB0 = sB + wid * 1024;
  char* lB1 = sB + 4096 + wid * 1024;
  const int tEnd = (qt + 1) * 64;
  f32x4 o[4][2] = {};
  for (int t0 = 0; t0 < tEnd; t0 += 32) {
    glds16(Ag + t0, lA);
    glds16(Bg0 + t0, lB0);
    glds16(Bg1 + t0, lB1);
    __syncthreads();
    uint4 af[4], vf[2];
#pragma unroll
    for (int mf = 0; mf < 4; mf++) af[mf] = *(uint4*)(sA + (mf * 16 + l15) * 64 + lh * 16);
#pragma unroll
    for (int nf = 0; nf < 2; nf++) vf[nf] = *(uint4*)(sB + (wid * 32 + nf * 16 + l15) * 64 + lh * 16);
#pragma unroll
    for (int mf = 0; mf < 4; mf++)
#pragma unroll
      for (int nf = 0; nf < 2; nf++)
        o[mf][nf] = MFMA(af[mf], vf[nf], o[mf][nf]);
    __syncthreads();
  }
  const size_t qrow0 = (size_t)b * SS + (size_t)g * 1024 + (size_t)qt * 64;
#pragma unroll
  for (int mf = 0; mf < 4; mf++)
#pragma unroll
    for (int nf = 0; nf < 2; nf++)
#pragma unroll
      for (int jj = 0; jj < 4; jj++)
        obuf[(qrow0 + mf * 16 + lh * 4 + jj) * DD + e0 + wid * 32 + nf * 16 + l15] =
            f2bf(o[mf][nf][jj]);
}

extern "C" void kernel_launch(void* const* d_in, const int* in_sizes, int n_in,
                              void* d_out, int out_size, void* d_ws, size_t ws_size,
                              hipStream_t stream) {
  (void)in_sizes; (void)n_in; (void)out_size;
  const float* x      = (const float*)d_in[0];
  const float* norm_w = (const float*)d_in[1];
  const float* w_up   = (const float*)d_in[2];
  const float* w_gate = (const float*)d_in[3];
  const float* w_down = (const float*)d_in[4];
  const float* conv_w = (const float*)d_in[5];
  const float* conv_b = (const float*)d_in[6];
  const float* wq     = (const float*)d_in[7];
  const float* wk     = (const float*)d_in[8];
  const float* wv     = (const float*)d_in[9];
  const float* wo     = (const float*)d_in[10];
  float* out = (float*)d_out;

  const size_t MB = 1ull << 20;
  // Aliased workspace plan (212 MiB). Lifetimes:
  //   [0,32M)    ug -> hbuf -> Tbuf (after QKV gemms)
  //   [32,64M)   ug -> qbuf
  //   [64,96M)   ug -> kbuf
  //   [96,128M)  ug -> ktbuf (pre-scaled by decay) -> sbuf (after state_gemm)
  //   [128,160M) normed -> hin -> vtbuf
  //   [160,192M) hin tail -> obuf
  //   [192,212M) weight transposes
  if (ws_size < 212 * MB) return;
  char* base = (char*)d_ws;
  unsigned short* ug     = (unsigned short*)(base + 0);
  unsigned short* hbuf   = (unsigned short*)(base + 0);
  unsigned short* Tbuf   = (unsigned short*)(base + 0);
  unsigned short* qbuf   = (unsigned short*)(base + 32 * MB);
  unsigned short* kbuf   = (unsigned short*)(base + 64 * MB);
  unsigned short* ktbuf  = (unsigned short*)(base + 96 * MB);
  unsigned short* sbuf   = (unsigned short*)(base + 96 * MB);
  unsigned short* normed = (unsigned short*)(base + 128 * MB);
  unsigned short* hin    = (unsigned short*)(base + 128 * MB);
  unsigned short* vtbuf  = (unsigned short*)(base + 128 * MB);
  unsigned short* obuf   = (unsigned short*)(base + 160 * MB);
  unsigned short* wugt   = (unsigned short*)(base + 192 * MB);
  unsigned short* wdt    = (unsigned short*)(base + 200 * MB);
  unsigned short* wqt    = (unsigned short*)(base + 204 * MB);
  unsigned short* wkt    = (unsigned short*)(base + 206 * MB);
  unsigned short* wvt    = (unsigned short*)(base + 208 * MB);
  unsigned short* wot    = (unsigned short*)(base + 210 * MB);

  dim3 tb(32, 8);
  transpose_cast<<<dim3(DI2 / 32, DD / 32), tb, 0, stream>>>(w_up,   wugt,                    DD,  DI2);
  transpose_cast<<<dim3(DI2 / 32, DD / 32), tb, 0, stream>>>(w_gate, wugt + (size_t)DI2 * DD, DD,  DI2);
  transpose_cast<<<dim3(DD / 32, DI2 / 32), tb, 0, stream>>>(w_down, wdt, DI2, DD);
  transpose_cast<<<dim3(DD / 32, DD / 32),  tb, 0, stream>>>(wq, wqt, DD, DD);
  transpose_cast<<<dim3(DD / 32, DD / 32),  tb, 0, stream>>>(wk, wkt, DD, DD);
  transpose_cast<<<dim3(DD / 32, DD / 32),  tb, 0, stream>>>(wv, wvt, DD, DD);
  transpose_cast<<<dim3(DD / 32, DD / 32),  tb, 0, stream>>>(wo, wot, DD, DD);

  rmsnorm_kernel<<<NR, 256, 0, stream>>>(x, norm_w, normed);

  // [16384,1024] @ [1024,4096] -> ug (u | gate_pre); grid 64*16 = 1024 blocks
  gemm256<EP_BF16><<<dim3((NR / 256) * (4096 / 256)), 512, 0, stream>>>(
      normed, wugt, ug, nullptr, nullptr, nullptr, NR, 4096, DD, DD, DD, 1.0f);

  convgate_kernel<<<NR, 256, 0, stream>>>(ug, conv_w, conv_b, hin);

  // [16384,2048] @ [2048,1024] -> h; grid 64*4 = 256
  gemm256<EP_BF16><<<dim3((NR / 256) * (DD / 256)), 512, 0, stream>>>(
      hin, wdt, hbuf, nullptr, nullptr, nullptr, NR, DD, DI2, DI2, DI2, 1.0f);

  gemm256<EP_BF16><<<dim3((NR / 256) * (DD / 256)), 512, 0, stream>>>(
      hbuf, wqt, qbuf, nullptr, nullptr, nullptr, NR, DD, DD, DD, DD, 0.03125f);
  gemm256<EP_BF16_BOTH><<<dim3((NR / 256) * (DD / 256)), 512, 0, stream>>>(
      hbuf, wkt, kbuf, ktbuf, nullptr, nullptr, NR, DD, DD, DD, DD, 1.0f);
  gemm256<EP_BF16_T><<<dim3((NR / 256) * (DD / 256)), 512, 0, stream>>>(
      hbuf, wvt, nullptr, vtbuf, nullptr, nullptr, NR, DD, DD, DD, DD, 1.0f);

  // Hebbian memory via superchunk decomposition (16 chunks / superchunk):
  // T[gb] = (decayed V^T) @ K-slice  — ktbuf already carries the decay weights.
  gemm256<EP_STATE><<<dim3(16, 1, 16), 512, 0, stream>>>(
      vtbuf, ktbuf, Tbuf, nullptr, nullptr, nullptr, 1024, 1024, 1024, SS, SS, 1.0f);
  score_attn<<<dim3(136, 16), 256, 0, stream>>>(qbuf, kbuf, sbuf);      // sbuf overlays ktbuf
  prefix_kernel<<<1024, 256, 0, stream>>>(Tbuf);
  pv_attn<<<dim3(8, 16, 16), 256, 0, stream>>>(sbuf, vtbuf, obuf);
  gemm256<EP_CROSS><<<dim3(16, 1, 16), 512, 0, stream>>>(
      qbuf, Tbuf, obuf, nullptr, nullptr, nullptr, 1024, 1024, 1024, DD, 1024, 1.0f);

  // out = obuf @ wo + x; grid 256
  gemm256<EP_F32_RES><<<dim3((NR / 256) * (DD / 256)), 512, 0, stream>>>(
      obuf, wot, nullptr, nullptr, out, x, NR, DD, DD, DD, DD, 1.0f);
}

// Round 10
// 697.265 us; speedup vs baseline: 3.1345x; 1.0511x over previous
//
#include <hip/hip_runtime.h>
#include <cstdint>
#include <cstddef>

#define SS 8192
#define DD 1024
#define DI2 2048
#define NR 16384   // B*S

#define LOG2_09 (-0.152003093445050f)   // log2(0.9)
#define LAMBDA16 0.185302018885184f     // 0.9^16

typedef __attribute__((ext_vector_type(4))) float f32x4;
typedef __attribute__((ext_vector_type(8))) __bf16 bf16x8;

union U16 { uint4 u; bf16x8 b; };

static __device__ __forceinline__ f32x4 MFMA(uint4 a, uint4 b, f32x4 c) {
  U16 ua, ub; ua.u = a; ub.u = b;
  return __builtin_amdgcn_mfma_f32_16x16x32_bf16(ua.b, ub.b, c, 0, 0, 0);
}

static __device__ __forceinline__ unsigned short f2bf(float f) {
  union { float f; unsigned u; } v; v.f = f;
  return (unsigned short)((v.u + 0x7FFFu + ((v.u >> 16) & 1u)) >> 16);
}
static __device__ __forceinline__ float bf2f(unsigned b) {
  union { unsigned u; float f; } v; v.u = b << 16; return v.f;
}
static __device__ __forceinline__ void unpack8(uint4 u, float* f) {
  f[0] = bf2f(u.x & 0xFFFFu); f[1] = bf2f(u.x >> 16);
  f[2] = bf2f(u.y & 0xFFFFu); f[3] = bf2f(u.y >> 16);
  f[4] = bf2f(u.z & 0xFFFFu); f[5] = bf2f(u.z >> 16);
  f[6] = bf2f(u.w & 0xFFFFu); f[7] = bf2f(u.w >> 16);
}

// async global->LDS, 16B per lane. LDS dest is wave-uniform base + lane*16.
static __device__ __forceinline__ void glds16(const unsigned short* g, char* l) {
  __builtin_amdgcn_global_load_lds(
      (const __attribute__((address_space(1))) unsigned int*)g,
      (__attribute__((address_space(3))) unsigned int*)l, 16, 0, 0);
}

// ---------------- weight transpose + cast: out[c][r] = bf16(in[r][c]) ----------------
__global__ __launch_bounds__(256)
void transpose_cast(const float* __restrict__ in, unsigned short* __restrict__ out, int R, int Cc) {
  __shared__ float tile[32][33];
  const int r0 = blockIdx.y * 32, c0 = blockIdx.x * 32;
  const int tx = threadIdx.x, ty = threadIdx.y;
#pragma unroll
  for (int i = 0; i < 4; i++)
    tile[ty + i * 8][tx] = in[(size_t)(r0 + ty + i * 8) * Cc + c0 + tx];
  __syncthreads();
#pragma unroll
  for (int i = 0; i < 4; i++)
    out[(size_t)(c0 + ty + i * 8) * R + r0 + tx] = f2bf(tile[tx][ty + i * 8]);
}

// ---------------- RMSNorm (fp32 in -> bf16 out) ----------------
__global__ __launch_bounds__(256)
void rmsnorm_kernel(const float* __restrict__ x, const float* __restrict__ w,
                    unsigned short* __restrict__ out) {
  const int row = blockIdx.x, t = threadIdx.x;
  const float4 v = ((const float4*)(x + (size_t)row * DD))[t];
  float ss = v.x * v.x + v.y * v.y + v.z * v.z + v.w * v.w;
  __shared__ float sred[256];
  sred[t] = ss;
  __syncthreads();
  for (int o = 128; o > 0; o >>= 1) {
    if (t < o) sred[t] += sred[t + o];
    __syncthreads();
  }
  const float rr = rsqrtf(sred[0] * (1.0f / (float)DD) + 1e-5f);
  const float4 wv = ((const float4*)w)[t];
  uint2 pk;
  pk.x = (unsigned)f2bf(v.x * rr * wv.x) | ((unsigned)f2bf(v.y * rr * wv.y) << 16);
  pk.y = (unsigned)f2bf(v.z * rr * wv.z) | ((unsigned)f2bf(v.w * rr * wv.w) << 16);
  *(uint2*)(out + (size_t)row * DD + t * 4) = pk;
}

// ---------------- 256x256-tile deep-pipelined bf16 GEMM: C = A[M][.] @ Bt[N][.]^T ----------------
// 8 waves (512 thr), wave grid 2M x 4N (128x64 out/wave). BK=32, quad-buffered LDS (128KB),
// depth-3 prefetch, counted vmcnt(8). Per K-tile: 2 phases x 16 MFMA; NO lgkm pin — the
// compiler emits fine-grained per-dependency lgkmcnt (m97), pinning was over-sync.
// XCD m-slice remap when mblocks%8==0 (per-XCD A working set = 4MB = L2).
// EP_STATE/EP_CROSS/EP_SCORE/EP_PV: z-batched per-superchunk GEMMs (runtime lda/ldb/kLen).
enum { EP_BF16 = 0, EP_BF16_BOTH = 1, EP_BF16_T = 2, EP_F32_RES = 3, EP_STATE = 4,
       EP_CROSS = 5, EP_SCORE = 6, EP_PV = 7 };

template <int MODE>
__global__ __launch_bounds__(512, 2)
void gemm256(const unsigned short* __restrict__ A, const unsigned short* __restrict__ Bt,
             unsigned short* __restrict__ Cb, unsigned short* __restrict__ Ct,
             float* __restrict__ Cf, const float* __restrict__ resid,
             int M, int N, int kLen, int lda, int ldb, float scale) {
  __shared__ char sLds[131072];
  const int t = threadIdx.x, lane = t & 63, wid = t >> 6;
  const int wr = wid >> 2, wc = wid & 3;
  const int l15 = lane & 15, lh = lane >> 4;
  // block -> (m0, n0)
  const int mblocks = M >> 8;
  int m0, n0;
  if constexpr (MODE == EP_SCORE) {
    // triangular tile grid: only lower-or-diagonal 256^2 tiles (10 of 16)
    const int p = (int)blockIdx.x;
    const int mt = (p >= 6) ? 3 : (p >= 3) ? 2 : (p >= 1) ? 1 : 0;
    const int nt = p - ((mt * (mt + 1)) >> 1);
    m0 = mt << 8; n0 = nt << 8;
  } else if ((mblocks & 7) == 0) {   // XCD m-slice remap
    const int msl = mblocks >> 3;
    const int xcd = (int)blockIdx.x & 7, loc = (int)blockIdx.x >> 3;
    m0 = (xcd * msl + (loc % msl)) << 8;
    n0 = (loc / msl) << 8;
  } else {
    m0 = ((int)blockIdx.x % mblocks) << 8;
    n0 = ((int)blockIdx.x / mblocks) << 8;
  }
  // z-batched bases (superchunk modes)
  int zb = 0, zg = 0;
  const unsigned short* Abase = A;
  const unsigned short* Bbase = Bt;
  if constexpr (MODE == EP_STATE || MODE == EP_CROSS || MODE == EP_SCORE || MODE == EP_PV) {
    const int gb = blockIdx.z;
    zb = gb >> 3; zg = gb & 7;
    if constexpr (MODE == EP_STATE) {
      Abase = A + (size_t)zb * DD * SS + (size_t)zg * 1024;
      Bbase = Bt + (size_t)zb * DD * SS + (size_t)zg * 1024;
    } else if constexpr (MODE == EP_CROSS) {
      Abase = A + ((size_t)zb * SS + (size_t)zg * 1024) * (size_t)lda;
      Bbase = Bt + ((size_t)blockIdx.z << 20);
    } else if constexpr (MODE == EP_SCORE) {
      Abase = A + ((size_t)zb * SS + (size_t)zg * 1024) * (size_t)lda;
      Bbase = Bt + ((size_t)zb * SS + (size_t)zg * 1024) * (size_t)ldb;
    } else {  // EP_PV: A = sbuf[gb] (row-major 1024), B = vt rows (e), cols (t)
      Abase = A + ((size_t)blockIdx.z << 20);
      Bbase = Bt + (size_t)zb * DD * SS + (size_t)zg * 1024;
    }
  }
  // staging source (inverse swizzle on the global column)
  const int srow = wid * 16 + (lane >> 2);                          // 0..127 within half
  const int scol = ((lane & 3) << 3) ^ (((srow >> 1) & 3) << 3);   // bf16 elems
  const unsigned short* pA0 = Abase + (size_t)(m0 + srow) * lda + scol;
  const unsigned short* pA1 = pA0 + (size_t)128 * lda;
  const unsigned short* pB0 = Bbase + (size_t)(n0 + srow) * ldb + scol;
  const unsigned short* pB1 = pB0 + (size_t)128 * ldb;
  const int ldsW = wid * 1024;
  // swizzled read offsets (iteration-invariant)
  int offA[8], offB[4];
#pragma unroll
  for (int mf = 0; mf < 8; mf++) {
    const int r = wr * 128 + mf * 16 + l15;
    offA[mf] = r * 64 + ((lh * 16) ^ (((r >> 1) & 3) << 4));
  }
#pragma unroll
  for (int nf = 0; nf < 4; nf++) {
    const int r = wc * 64 + nf * 16 + l15;
    offB[nf] = r * 64 + ((lh * 16) ^ (((r >> 1) & 3) << 4));
  }
  int NT = kLen >> 5;
  if constexpr (MODE == EP_PV) NT = ((m0 >> 8) + 1) << 3;  // banded: k <= (mt+1)*256
#define BUFA(tt) (sLds + ((tt) & 3) * 32768)
#define BUFB(tt) (sLds + ((tt) & 3) * 32768 + 16384)
#define STAGEA(tt) do { const int _k = (tt) * 32; \
    glds16(pA0 + _k, BUFA(tt) + ldsW); \
    glds16(pA1 + _k, BUFA(tt) + 8192 + ldsW); } while (0)
#define STAGEB(tt) do { const int _k = (tt) * 32; \
    glds16(pB0 + _k, BUFB(tt) + ldsW); \
    glds16(pB1 + _k, BUFB(tt) + 8192 + ldsW); } while (0)
  STAGEA(0); STAGEB(0); STAGEA(1); STAGEB(1); STAGEA(2); STAGEB(2);
  asm volatile("s_waitcnt vmcnt(8)" ::: "memory");   // tile 0 landed (own); barrier -> all waves'
  __builtin_amdgcn_s_barrier();
  f32x4 acc[8][4] = {};
  for (int kt = 0; kt < NT; ++kt) {
    const char* At  = BUFA(kt);
    const char* Bt_ = BUFB(kt);
    uint4 av[4], bv[4], av2[4];
    // ---- phase 0: reads(A0-3,B0-3) || stage-A(kt+3) -> MFMA mf0-3 -> bar ----
#pragma unroll
    for (int i = 0; i < 4; i++) av[i] = *(const uint4*)(At + offA[i]);
#pragma unroll
    for (int i = 0; i < 4; i++) bv[i] = *(const uint4*)(Bt_ + offB[i]);
    if (kt + 3 < NT) STAGEA(kt + 3);   // writes buf (kt-1)&3: all reads of it done last iter
    __builtin_amdgcn_s_setprio(1);
#pragma unroll
    for (int mf = 0; mf < 4; mf++)
#pragma unroll
      for (int nf = 0; nf < 4; nf++)
        acc[mf][nf] = MFMA(av[mf], bv[nf], acc[mf][nf]);
    __builtin_amdgcn_s_setprio(0);
    __builtin_amdgcn_s_barrier();
    // ---- phase 1: reads(A4-7) || stage-B(kt+3) -> MFMA mf4-7 -> vmcnt -> bar ----
#pragma unroll
    for (int i = 0; i < 4; i++) av2[i] = *(const uint4*)(At + offA[4 + i]);
    if (kt + 3 < NT) STAGEB(kt + 3);
    __builtin_amdgcn_s_setprio(1);
#pragma unroll
    for (int mf = 0; mf < 4; mf++)
#pragma unroll
      for (int nf = 0; nf < 4; nf++)
        acc[4 + mf][nf] = MFMA(av2[mf], bv[nf], acc[4 + mf][nf]);
    __builtin_amdgcn_s_setprio(0);
    // counted wait for next tile, BEFORE the end barrier (all waves' DMA then landed)
    if (kt < NT - 3)       { asm volatile("s_waitcnt vmcnt(8)" ::: "memory"); }
    else if (kt == NT - 3) { asm volatile("s_waitcnt vmcnt(4)" ::: "memory"); }
    else if (kt == NT - 2) { asm volatile("s_waitcnt vmcnt(0)" ::: "memory"); }
    __builtin_amdgcn_s_barrier();
  }
#undef STAGEA
#undef STAGEB
#undef BUFA
#undef BUFB
#pragma unroll
  for (int mf = 0; mf < 8; mf++) {
    const int r0 = m0 + wr * 128 + mf * 16 + lh * 4;
#pragma unroll
    for (int nf = 0; nf < 4; nf++) {
      const int c = n0 + wc * 64 + nf * 16 + l15;
      f32x4 v = acc[mf][nf] * scale;
      if constexpr (MODE == EP_F32_RES) {
#pragma unroll
        for (int jj = 0; jj < 4; jj++) {
          const size_t idx = (size_t)(r0 + jj) * N + c;
          Cf[idx] = v[jj] + resid[idx];
        }
      } else if constexpr (MODE == EP_STATE) {
        unsigned short* Tg = Cb + ((size_t)blockIdx.z << 20);
#pragma unroll
        for (int jj = 0; jj < 4; jj++)
          Tg[(size_t)(r0 + jj) * 1024 + c] = f2bf(v[jj]);
      } else if constexpr (MODE == EP_CROSS) {
        const float rs = exp2f((float)(r0 >> 6) * LOG2_09);  // 0.9^chunk-local (rows 4-aligned)
#pragma unroll
        for (int jj = 0; jj < 4; jj++) {
          const size_t idx = ((size_t)zb * SS + (size_t)zg * 1024 + r0 + jj) * DD + c;
          Cb[idx] = f2bf(bf2f(Cb[idx]) + v[jj] * rs);
        }
      } else if constexpr (MODE == EP_SCORE) {
        // decay/tril weighting: qt = chunk of row, tb = chunk of col (superchunk-local)
        unsigned short* Sg = Cb + ((size_t)blockIdx.z << 20);
        const int qt = r0 >> 6;           // uniform over jj (r0 16-aligned, +3 < 64 boundary)
        const int tb = c >> 6;
        float w;
        if (tb > qt)       w = 0.0f;
        else if (tb == qt) w = 1.0f;
        else               w = exp2f((float)(qt - 1 - tb) * LOG2_09);
#pragma unroll
        for (int jj = 0; jj < 4; jj++) {
          float val = v[jj] * w;
          if (tb == qt && (c & 63) > ((r0 + jj) & 63)) val = 0.0f;  // inclusive tril in-chunk
          Sg[(size_t)(r0 + jj) * 1024 + c] = f2bf(val);
        }
      } else if constexpr (MODE == EP_PV) {
#pragma unroll
        for (int jj = 0; jj < 4; jj++)
          Cb[((size_t)zb * SS + (size_t)zg * 1024 + r0 + jj) * DD + c] = f2bf(v[jj]);
      } else {
        if constexpr (MODE == EP_BF16 || MODE == EP_BF16_BOTH) {
#pragma unroll
          for (int jj = 0; jj < 4; jj++)
            Cb[(size_t)(r0 + jj) * N + c] = f2bf(v[jj]);
        }
        if constexpr (MODE == EP_BF16_BOTH || MODE == EP_BF16_T) {
          // transposed store: Ct[b][c][s]  (requires N == DD).
          // BOTH (k-proj): pre-scale kt by 0.9^(15-cl) so state_gemm is a plain GEMM.
          const int bb = r0 >> 13, s0 = r0 & (SS - 1);
          float wt = 1.0f;
          if constexpr (MODE == EP_BF16_BOTH)
            wt = exp2f((float)(15 - ((s0 >> 6) & 15)) * LOG2_09);
          uint2 pk;
          pk.x = (unsigned)f2bf(v[0] * wt) | ((unsigned)f2bf(v[1] * wt) << 16);
          pk.y = (unsigned)f2bf(v[2] * wt) | ((unsigned)f2bf(v[3] * wt) << 16);
          *(uint2*)(Ct + ((size_t)bb * DD + c) * SS + s0) = pk;
        }
      }
    }
  }
}

// ---------------- causal depthwise conv (K=4) + SiLU, gate SiLU, multiply ----------------
__global__ __launch_bounds__(256)
void convgate_kernel(const unsigned short* __restrict__ ug, const float* __restrict__ cw,
                     const float* __restrict__ cb, unsigned short* __restrict__ hin) {
  const int r = blockIdx.x;          // global row (b*S + s)
  const int c0 = threadIdx.x * 8;    // channel base [0,2048)
  const int s = r & (SS - 1);
  float acc[8];
#pragma unroll
  for (int i = 0; i < 8; i++) acc[i] = cb[c0 + i];
  for (int tap = 0; tap < 4; tap++) {
    const int ds = s - 3 + tap;
    if (ds < 0) continue;
    uint4 uv = *(const uint4*)(ug + (size_t)(r - 3 + tap) * 4096 + c0);
    float u[8]; unpack8(uv, u);
#pragma unroll
    for (int i = 0; i < 8; i++) acc[i] += u[i] * cw[tap * DI2 + c0 + i];
  }
  uint4 gv = *(const uint4*)(ug + (size_t)r * 4096 + DI2 + c0);
  float gt[8]; unpack8(gv, gt);
  unsigned short o16[8];
#pragma unroll
  for (int i = 0; i < 8; i++) {
    const float val = acc[i] / (1.0f + __expf(-acc[i]));
    const float gg  = gt[i] / (1.0f + __expf(-gt[i]));
    o16[i] = f2bf(val * gg);
  }
  uint4 ov;
  ov.x = (unsigned)o16[0] | ((unsigned)o16[1] << 16);
  ov.y = (unsigned)o16[2] | ((unsigned)o16[3] << 16);
  ov.z = (unsigned)o16[4] | ((unsigned)o16[5] << 16);
  ov.w = (unsigned)o16[6] | ((unsigned)o16[7] << 16);
  *(uint4*)(hin + (size_t)r * DI2 + c0) = ov;
}

// ---------------- superchunk prefix (in-place): Minit_g = 0.9^16 Minit_{g-1} + T_{g-1} ----------------
__global__ __launch_bounds__(256)
void prefix_kernel(unsigned short* __restrict__ Tb) {
  const int tid = blockIdx.x * 256 + threadIdx.x;  // 262144 threads
  const int b = tid >> 17, i = tid & 131071;
  unsigned short* p = Tb + (((size_t)b * 8) << 20) + (size_t)i * 8;
  float acc[8] = {};
  for (int g = 0; g < 8; g++) {
    unsigned short* pg = p + ((size_t)g << 20);
    uint4 tv = *(uint4*)pg;
    float tf_[8]; unpack8(tv, tf_);
    uint4 ov;
    ov.x = (unsigned)f2bf(acc[0]) | ((unsigned)f2bf(acc[1]) << 16);
    ov.y = (unsigned)f2bf(acc[2]) | ((unsigned)f2bf(acc[3]) << 16);
    ov.z = (unsigned)f2bf(acc[4]) | ((unsigned)f2bf(acc[5]) << 16);
    ov.w = (unsigned)f2bf(acc[6]) | ((unsigned)f2bf(acc[7]) << 16);
    *(uint4*)pg = ov;
#pragma unroll
    for (int e = 0; e < 8; e++) acc[e] = LAMBDA16 * acc[e] + tf_[e];
  }
}

extern "C" void kernel_launch(void* const* d_in, const int* in_sizes, int n_in,
                              void* d_out, int out_size, void* d_ws, size_t ws_size,
                              hipStream_t stream) {
  (void)in_sizes; (void)n_in; (void)out_size;
  const float* x      = (const float*)d_in[0];
  const float* norm_w = (const float*)d_in[1];
  const float* w_up   = (const float*)d_in[2];
  const float* w_gate = (const float*)d_in[3];
  const float* w_down = (const float*)d_in[4];
  const float* conv_w = (const float*)d_in[5];
  const float* conv_b = (const float*)d_in[6];
  const float* wq     = (const float*)d_in[7];
  const float* wk     = (const float*)d_in[8];
  const float* wv     = (const float*)d_in[9];
  const float* wo     = (const float*)d_in[10];
  float* out = (float*)d_out;

  const size_t MB = 1ull << 20;
  // Aliased workspace plan (212 MiB). Lifetimes:
  //   [0,32M)    ug -> hbuf -> Tbuf (after QKV gemms)
  //   [32,64M)   ug -> qbuf
  //   [64,96M)   ug -> kbuf
  //   [96,128M)  ug -> ktbuf (pre-scaled by decay) -> sbuf (after state gemm)
  //   [128,160M) normed -> hin -> vtbuf
  //   [160,192M) hin tail -> obuf
  //   [192,212M) weight transposes
  if (ws_size < 212 * MB) return;
  char* base = (char*)d_ws;
  unsigned short* ug     = (unsigned short*)(base + 0);
  unsigned short* hbuf   = (unsigned short*)(base + 0);
  unsigned short* Tbuf   = (unsigned short*)(base + 0);
  unsigned short* qbuf   = (unsigned short*)(base + 32 * MB);
  unsigned short* kbuf   = (unsigned short*)(base + 64 * MB);
  unsigned short* ktbuf  = (unsigned short*)(base + 96 * MB);
  unsigned short* sbuf   = (unsigned short*)(base + 96 * MB);
  unsigned short* normed = (unsigned short*)(base + 128 * MB);
  unsigned short* hin    = (unsigned short*)(base + 128 * MB);
  unsigned short* vtbuf  = (unsigned short*)(base + 128 * MB);
  unsigned short* obuf   = (unsigned short*)(base + 160 * MB);
  unsigned short* wugt   = (unsigned short*)(base + 192 * MB);
  unsigned short* wdt    = (unsigned short*)(base + 200 * MB);
  unsigned short* wqt    = (unsigned short*)(base + 204 * MB);
  unsigned short* wkt    = (unsigned short*)(base + 206 * MB);
  unsigned short* wvt    = (unsigned short*)(base + 208 * MB);
  unsigned short* wot    = (unsigned short*)(base + 210 * MB);

  dim3 tb(32, 8);
  transpose_cast<<<dim3(DI2 / 32, DD / 32), tb, 0, stream>>>(w_up,   wugt,                    DD,  DI2);
  transpose_cast<<<dim3(DI2 / 32, DD / 32), tb, 0, stream>>>(w_gate, wugt + (size_t)DI2 * DD, DD,  DI2);
  transpose_cast<<<dim3(DD / 32, DI2 / 32), tb, 0, stream>>>(w_down, wdt, DI2, DD);
  transpose_cast<<<dim3(DD / 32, DD / 32),  tb, 0, stream>>>(wq, wqt, DD, DD);
  transpose_cast<<<dim3(DD / 32, DD / 32),  tb, 0, stream>>>(wk, wkt, DD, DD);
  transpose_cast<<<dim3(DD / 32, DD / 32),  tb, 0, stream>>>(wv, wvt, DD, DD);
  transpose_cast<<<dim3(DD / 32, DD / 32),  tb, 0, stream>>>(wo, wot, DD, DD);

  rmsnorm_kernel<<<NR, 256, 0, stream>>>(x, norm_w, normed);

  // [16384,1024] @ [1024,4096] -> ug (u | gate_pre); grid 64*16 = 1024 blocks
  gemm256<EP_BF16><<<dim3((NR / 256) * (4096 / 256)), 512, 0, stream>>>(
      normed, wugt, ug, nullptr, nullptr, nullptr, NR, 4096, DD, DD, DD, 1.0f);

  convgate_kernel<<<NR, 256, 0, stream>>>(ug, conv_w, conv_b, hin);

  // [16384,2048] @ [2048,1024] -> h; grid 64*4 = 256
  gemm256<EP_BF16><<<dim3((NR / 256) * (DD / 256)), 512, 0, stream>>>(
      hin, wdt, hbuf, nullptr, nullptr, nullptr, NR, DD, DI2, DI2, DI2, 1.0f);

  gemm256<EP_BF16><<<dim3((NR / 256) * (DD / 256)), 512, 0, stream>>>(
      hbuf, wqt, qbuf, nullptr, nullptr, nullptr, NR, DD, DD, DD, DD, 0.03125f);
  gemm256<EP_BF16_BOTH><<<dim3((NR / 256) * (DD / 256)), 512, 0, stream>>>(
      hbuf, wkt, kbuf, ktbuf, nullptr, nullptr, NR, DD, DD, DD, DD, 1.0f);
  gemm256<EP_BF16_T><<<dim3((NR / 256) * (DD / 256)), 512, 0, stream>>>(
      hbuf, wvt, nullptr, vtbuf, nullptr, nullptr, NR, DD, DD, DD, DD, 1.0f);

  // Hebbian memory via superchunk decomposition (16 chunks / superchunk):
  // T[gb] = (decayed V^T) @ K-slice  — ktbuf already carries the decay weights.
  gemm256<EP_STATE><<<dim3(16, 1, 16), 512, 0, stream>>>(
      vtbuf, ktbuf, Tbuf, nullptr, nullptr, nullptr, 1024, 1024, 1024, SS, SS, 1.0f);
  // S[gb] = decay/tril-weighted Q K^T (lower-triangular 256^2 tiles only) -> sbuf
  gemm256<EP_SCORE><<<dim3(10, 1, 16), 512, 0, stream>>>(
      qbuf, kbuf, sbuf, nullptr, nullptr, nullptr, 1024, 1024, 1024, DD, DD, 1.0f);
  prefix_kernel<<<1024, 256, 0, stream>>>(Tbuf);
  // O[gb] = S @ V (banded kLen per row-tile) -> obuf (plain store)
  gemm256<EP_PV><<<dim3(16, 1, 16), 512, 0, stream>>>(
      sbuf, vtbuf, obuf, nullptr, nullptr, nullptr, 1024, 1024, 1024, 1024, SS, 1.0f);
  // obuf += 0.9^cl * Q @ Minit
  gemm256<EP_CROSS><<<dim3(16, 1, 16), 512, 0, stream>>>(
      qbuf, Tbuf, obuf, nullptr, nullptr, nullptr, 1024, 1024, 1024, DD, 1024, 1.0f);

  // out = obuf @ wo + x; grid 256
  gemm256<EP_F32_RES><<<dim3((NR / 256) * (DD / 256)), 512, 0, stream>>>(
      obuf, wot, nullptr, nullptr, out, x, NR, DD, DD, DD, DD, 1.0f);
}

// Round 11
// 668.879 us; speedup vs baseline: 3.2675x; 1.0424x over previous
//
#include <hip/hip_runtime.h>
#include <cstdint>
#include <cstddef>

#define SS 8192
#define DD 1024
#define DI2 2048
#define NR 16384   // B*S

#define LOG2_09 (-0.152003093445050f)   // log2(0.9)
#define LAMBDA16 0.185302018885184f     // 0.9^16

typedef __attribute__((ext_vector_type(4))) float f32x4;
typedef __attribute__((ext_vector_type(8))) __bf16 bf16x8;

union U16 { uint4 u; bf16x8 b; };

static __device__ __forceinline__ f32x4 MFMA(uint4 a, uint4 b, f32x4 c) {
  U16 ua, ub; ua.u = a; ub.u = b;
  return __builtin_amdgcn_mfma_f32_16x16x32_bf16(ua.b, ub.b, c, 0, 0, 0);
}

static __device__ __forceinline__ unsigned short f2bf(float f) {
  union { float f; unsigned u; } v; v.f = f;
  return (unsigned short)((v.u + 0x7FFFu + ((v.u >> 16) & 1u)) >> 16);
}
static __device__ __forceinline__ float bf2f(unsigned b) {
  union { unsigned u; float f; } v; v.u = b << 16; return v.f;
}
static __device__ __forceinline__ void unpack8(uint4 u, float* f) {
  f[0] = bf2f(u.x & 0xFFFFu); f[1] = bf2f(u.x >> 16);
  f[2] = bf2f(u.y & 0xFFFFu); f[3] = bf2f(u.y >> 16);
  f[4] = bf2f(u.z & 0xFFFFu); f[5] = bf2f(u.z >> 16);
  f[6] = bf2f(u.w & 0xFFFFu); f[7] = bf2f(u.w >> 16);
}

// async global->LDS, 16B per lane. LDS dest is wave-uniform base + lane*16.
static __device__ __forceinline__ void glds16(const unsigned short* g, char* l) {
  __builtin_amdgcn_global_load_lds(
      (const __attribute__((address_space(1))) unsigned int*)g,
      (__attribute__((address_space(3))) unsigned int*)l, 16, 0, 0);
}

// ---------------- weight transpose + cast: out[c][r] = bf16(in[r][c]) ----------------
__global__ __launch_bounds__(256)
void transpose_cast(const float* __restrict__ in, unsigned short* __restrict__ out, int R, int Cc) {
  __shared__ float tile[32][33];
  const int r0 = blockIdx.y * 32, c0 = blockIdx.x * 32;
  const int tx = threadIdx.x, ty = threadIdx.y;
#pragma unroll
  for (int i = 0; i < 4; i++)
    tile[ty + i * 8][tx] = in[(size_t)(r0 + ty + i * 8) * Cc + c0 + tx];
  __syncthreads();
#pragma unroll
  for (int i = 0; i < 4; i++)
    out[(size_t)(c0 + ty + i * 8) * R + r0 + tx] = f2bf(tile[tx][ty + i * 8]);
}

// ---------------- RMSNorm (fp32 in -> bf16 out) ----------------
__global__ __launch_bounds__(256)
void rmsnorm_kernel(const float* __restrict__ x, const float* __restrict__ w,
                    unsigned short* __restrict__ out) {
  const int row = blockIdx.x, t = threadIdx.x;
  const float4 v = ((const float4*)(x + (size_t)row * DD))[t];
  float ss = v.x * v.x + v.y * v.y + v.z * v.z + v.w * v.w;
  __shared__ float sred[256];
  sred[t] = ss;
  __syncthreads();
  for (int o = 128; o > 0; o >>= 1) {
    if (t < o) sred[t] += sred[t + o];
    __syncthreads();
  }
  const float rr = rsqrtf(sred[0] * (1.0f / (float)DD) + 1e-5f);
  const float4 wv = ((const float4*)w)[t];
  uint2 pk;
  pk.x = (unsigned)f2bf(v.x * rr * wv.x) | ((unsigned)f2bf(v.y * rr * wv.y) << 16);
  pk.y = (unsigned)f2bf(v.z * rr * wv.z) | ((unsigned)f2bf(v.w * rr * wv.w) << 16);
  *(uint2*)(out + (size_t)row * DD + t * 4) = pk;
}

// ---------------- 256x256-tile deep-pipelined bf16 GEMM: C = A[M][.] @ Bt[N][.]^T ----------------
// 8 waves (512 thr), wave grid 2M x 4N (128x64 out/wave). BK=32, quad-buffered LDS (128KB),
// depth-3 prefetch, counted vmcnt(8). ONE barrier per K-tile: {12 reads || 4 stage ||
// 32 MFMA -> vmcnt -> bar} — compiler fine-schedules reads under MFMA (mid-bar removed r11).
// XCD m-slice remap when mblocks%8==0 (per-XCD A working set = 4MB = L2).
// EP_STATE/EP_CROSS/EP_SCORE/EP_PV: z-batched per-superchunk GEMMs. EP_QKV: fused N=3072.
enum { EP_BF16 = 0, EP_BF16_BOTH = 1, EP_BF16_T = 2, EP_F32_RES = 3, EP_STATE = 4,
       EP_CROSS = 5, EP_SCORE = 6, EP_PV = 7, EP_QKV = 8 };

template <int MODE>
__global__ __launch_bounds__(512, 2)
void gemm256(const unsigned short* __restrict__ A, const unsigned short* __restrict__ Bt,
             unsigned short* __restrict__ Cb, unsigned short* __restrict__ Ct,
             float* __restrict__ Cf, const float* __restrict__ resid,
             int M, int N, int kLen, int lda, int ldb, float scale) {
  __shared__ char sLds[131072];
  const int t = threadIdx.x, lane = t & 63, wid = t >> 6;
  const int wr = wid >> 2, wc = wid & 3;
  const int l15 = lane & 15, lh = lane >> 4;
  // block -> (m0, n0)
  const int mblocks = M >> 8;
  int m0, n0;
  if constexpr (MODE == EP_SCORE) {
    // triangular tile grid: only lower-or-diagonal 256^2 tiles (10 of 16)
    const int p = (int)blockIdx.x;
    const int mt = (p >= 6) ? 3 : (p >= 3) ? 2 : (p >= 1) ? 1 : 0;
    const int nt = p - ((mt * (mt + 1)) >> 1);
    m0 = mt << 8; n0 = nt << 8;
  } else if ((mblocks & 7) == 0) {   // XCD m-slice remap
    const int msl = mblocks >> 3;
    const int xcd = (int)blockIdx.x & 7, loc = (int)blockIdx.x >> 3;
    m0 = (xcd * msl + (loc % msl)) << 8;
    n0 = (loc / msl) << 8;
  } else {
    m0 = ((int)blockIdx.x % mblocks) << 8;
    n0 = ((int)blockIdx.x / mblocks) << 8;
  }
  // z-batched bases (superchunk modes)
  int zb = 0, zg = 0;
  const unsigned short* Abase = A;
  const unsigned short* Bbase = Bt;
  if constexpr (MODE == EP_STATE || MODE == EP_CROSS || MODE == EP_SCORE || MODE == EP_PV) {
    const int gb = blockIdx.z;
    zb = gb >> 3; zg = gb & 7;
    if constexpr (MODE == EP_STATE) {
      Abase = A + (size_t)zb * DD * SS + (size_t)zg * 1024;
      Bbase = Bt + (size_t)zb * DD * SS + (size_t)zg * 1024;
    } else if constexpr (MODE == EP_CROSS) {
      Abase = A + ((size_t)zb * SS + (size_t)zg * 1024) * (size_t)lda;
      Bbase = Bt + ((size_t)blockIdx.z << 20);
    } else if constexpr (MODE == EP_SCORE) {
      Abase = A + ((size_t)zb * SS + (size_t)zg * 1024) * (size_t)lda;
      Bbase = Bt + ((size_t)zb * SS + (size_t)zg * 1024) * (size_t)ldb;
    } else {  // EP_PV: A = sbuf[gb] (row-major 1024), B = vt rows (e), cols (t)
      Abase = A + ((size_t)blockIdx.z << 20);
      Bbase = Bt + (size_t)zb * DD * SS + (size_t)zg * 1024;
    }
  }
  // staging source (inverse swizzle on the global column)
  const int srow = wid * 16 + (lane >> 2);                          // 0..127 within half
  const int scol = ((lane & 3) << 3) ^ (((srow >> 1) & 3) << 3);   // bf16 elems
  const unsigned short* pA0 = Abase + (size_t)(m0 + srow) * lda + scol;
  const unsigned short* pA1 = pA0 + (size_t)128 * lda;
  const unsigned short* pB0 = Bbase + (size_t)(n0 + srow) * ldb + scol;
  const unsigned short* pB1 = pB0 + (size_t)128 * ldb;
  const int ldsW = wid * 1024;
  // swizzled read offsets (iteration-invariant)
  int offA[8], offB[4];
#pragma unroll
  for (int mf = 0; mf < 8; mf++) {
    const int r = wr * 128 + mf * 16 + l15;
    offA[mf] = r * 64 + ((lh * 16) ^ (((r >> 1) & 3) << 4));
  }
#pragma unroll
  for (int nf = 0; nf < 4; nf++) {
    const int r = wc * 64 + nf * 16 + l15;
    offB[nf] = r * 64 + ((lh * 16) ^ (((r >> 1) & 3) << 4));
  }
  int NT = kLen >> 5;
  if constexpr (MODE == EP_PV) NT = ((m0 >> 8) + 1) << 3;  // banded: k <= (mt+1)*256
#define BUFA(tt) (sLds + ((tt) & 3) * 32768)
#define BUFB(tt) (sLds + ((tt) & 3) * 32768 + 16384)
#define STAGEA(tt) do { const int _k = (tt) * 32; \
    glds16(pA0 + _k, BUFA(tt) + ldsW); \
    glds16(pA1 + _k, BUFA(tt) + 8192 + ldsW); } while (0)
#define STAGEB(tt) do { const int _k = (tt) * 32; \
    glds16(pB0 + _k, BUFB(tt) + ldsW); \
    glds16(pB1 + _k, BUFB(tt) + 8192 + ldsW); } while (0)
  STAGEA(0); STAGEB(0); STAGEA(1); STAGEB(1); STAGEA(2); STAGEB(2);
  asm volatile("s_waitcnt vmcnt(8)" ::: "memory");   // tile 0 landed (own); barrier -> all waves'
  __builtin_amdgcn_s_barrier();
  f32x4 acc[8][4] = {};
  for (int kt = 0; kt < NT; ++kt) {
    const char* At  = BUFA(kt);
    const char* Bt_ = BUFB(kt);
    uint4 av[8], bv[4];
    // reads || stage (next+3) || MFMA x32: compiler interleaves by dependency
#pragma unroll
    for (int i = 0; i < 8; i++) av[i] = *(const uint4*)(At + offA[i]);
#pragma unroll
    for (int i = 0; i < 4; i++) bv[i] = *(const uint4*)(Bt_ + offB[i]);
    if (kt + 3 < NT) { STAGEA(kt + 3); STAGEB(kt + 3); }  // buf (kt-1)&3: reads done pre-bar(kt-1)
    __builtin_amdgcn_s_setprio(1);
#pragma unroll
    for (int mf = 0; mf < 8; mf++)
#pragma unroll
      for (int nf = 0; nf < 4; nf++)
        acc[mf][nf] = MFMA(av[mf], bv[nf], acc[mf][nf]);
    __builtin_amdgcn_s_setprio(0);
    // counted wait for next tile, BEFORE the end barrier (all waves' DMA then landed)
    if (kt < NT - 3)       { asm volatile("s_waitcnt vmcnt(8)" ::: "memory"); }
    else if (kt == NT - 3) { asm volatile("s_waitcnt vmcnt(4)" ::: "memory"); }
    else if (kt == NT - 2) { asm volatile("s_waitcnt vmcnt(0)" ::: "memory"); }
    __builtin_amdgcn_s_barrier();
  }
#undef STAGEA
#undef STAGEB
#undef BUFA
#undef BUFB
#pragma unroll
  for (int mf = 0; mf < 8; mf++) {
    const int r0 = m0 + wr * 128 + mf * 16 + lh * 4;
#pragma unroll
    for (int nf = 0; nf < 4; nf++) {
      const int c = n0 + wc * 64 + nf * 16 + l15;
      f32x4 v = acc[mf][nf] * scale;
      if constexpr (MODE == EP_F32_RES) {
#pragma unroll
        for (int jj = 0; jj < 4; jj++) {
          const size_t idx = (size_t)(r0 + jj) * N + c;
          Cf[idx] = v[jj] + resid[idx];
        }
      } else if constexpr (MODE == EP_STATE) {
        unsigned short* Tg = Cb + ((size_t)blockIdx.z << 20);
#pragma unroll
        for (int jj = 0; jj < 4; jj++)
          Tg[(size_t)(r0 + jj) * 1024 + c] = f2bf(v[jj]);
      } else if constexpr (MODE == EP_CROSS) {
        const float rs = exp2f((float)(r0 >> 6) * LOG2_09);  // 0.9^chunk-local (rows 4-aligned)
#pragma unroll
        for (int jj = 0; jj < 4; jj++) {
          const size_t idx = ((size_t)zb * SS + (size_t)zg * 1024 + r0 + jj) * DD + c;
          Cb[idx] = f2bf(bf2f(Cb[idx]) + v[jj] * rs);
        }
      } else if constexpr (MODE == EP_SCORE) {
        // decay/tril weighting: qt = chunk of row, tb = chunk of col (superchunk-local)
        unsigned short* Sg = Cb + ((size_t)blockIdx.z << 20);
        const int qt = r0 >> 6;           // uniform over jj (r0 16-aligned, +3 < 64 boundary)
        const int tb = c >> 6;
        float w;
        if (tb > qt)       w = 0.0f;
        else if (tb == qt) w = 1.0f;
        else               w = exp2f((float)(qt - 1 - tb) * LOG2_09);
#pragma unroll
        for (int jj = 0; jj < 4; jj++) {
          float val = v[jj] * w;
          if (tb == qt && (c & 63) > ((r0 + jj) & 63)) val = 0.0f;  // inclusive tril in-chunk
          Sg[(size_t)(r0 + jj) * 1024 + c] = f2bf(val);
        }
      } else if constexpr (MODE == EP_PV) {
#pragma unroll
        for (int jj = 0; jj < 4; jj++)
          Cb[((size_t)zb * SS + (size_t)zg * 1024 + r0 + jj) * DD + c] = f2bf(v[jj]);
      } else if constexpr (MODE == EP_QKV) {
        // N=3072 fused: sect 0=q (scaled), 1=k (row + decayed k^T), 2=v (v^T). Uniform per block.
        unsigned short* qb  = Cb;
        unsigned short* kb  = Ct;
        unsigned short* ktb = (unsigned short*)Cf;
        unsigned short* vtb = (unsigned short*)const_cast<float*>(resid);
        const int sect = c >> 10, cc = c & 1023;
        const int bb = r0 >> 13, s0 = r0 & (SS - 1);
        if (sect == 0) {
#pragma unroll
          for (int jj = 0; jj < 4; jj++)
            qb[(size_t)(r0 + jj) * DD + cc] = f2bf(v[jj] * 0.03125f);
        } else if (sect == 1) {
#pragma unroll
          for (int jj = 0; jj < 4; jj++)
            kb[(size_t)(r0 + jj) * DD + cc] = f2bf(v[jj]);
          const float wt = exp2f((float)(15 - ((s0 >> 6) & 15)) * LOG2_09);
          uint2 pk;
          pk.x = (unsigned)f2bf(v[0] * wt) | ((unsigned)f2bf(v[1] * wt) << 16);
          pk.y = (unsigned)f2bf(v[2] * wt) | ((unsigned)f2bf(v[3] * wt) << 16);
          *(uint2*)(ktb + ((size_t)bb * DD + cc) * SS + s0) = pk;
        } else {
          uint2 pk;
          pk.x = (unsigned)f2bf(v[0]) | ((unsigned)f2bf(v[1]) << 16);
          pk.y = (unsigned)f2bf(v[2]) | ((unsigned)f2bf(v[3]) << 16);
          *(uint2*)(vtb + ((size_t)bb * DD + cc) * SS + s0) = pk;
        }
      } else {
        if constexpr (MODE == EP_BF16 || MODE == EP_BF16_BOTH) {
#pragma unroll
          for (int jj = 0; jj < 4; jj++)
            Cb[(size_t)(r0 + jj) * N + c] = f2bf(v[jj]);
        }
        if constexpr (MODE == EP_BF16_BOTH || MODE == EP_BF16_T) {
          const int bb = r0 >> 13, s0 = r0 & (SS - 1);
          float wt = 1.0f;
          if constexpr (MODE == EP_BF16_BOTH)
            wt = exp2f((float)(15 - ((s0 >> 6) & 15)) * LOG2_09);
          uint2 pk;
          pk.x = (unsigned)f2bf(v[0] * wt) | ((unsigned)f2bf(v[1] * wt) << 16);
          pk.y = (unsigned)f2bf(v[2] * wt) | ((unsigned)f2bf(v[3] * wt) << 16);
          *(uint2*)(Ct + ((size_t)bb * DD + c) * SS + s0) = pk;
        }
      }
    }
  }
}

// ---------------- causal depthwise conv (K=4) + SiLU, gate SiLU, multiply ----------------
__global__ __launch_bounds__(256)
void convgate_kernel(const unsigned short* __restrict__ ug, const float* __restrict__ cw,
                     const float* __restrict__ cb, unsigned short* __restrict__ hin) {
  const int r = blockIdx.x;          // global row (b*S + s)
  const int c0 = threadIdx.x * 8;    // channel base [0,2048)
  const int s = r & (SS - 1);
  float acc[8];
#pragma unroll
  for (int i = 0; i < 8; i++) acc[i] = cb[c0 + i];
  for (int tap = 0; tap < 4; tap++) {
    const int ds = s - 3 + tap;
    if (ds < 0) continue;
    uint4 uv = *(const uint4*)(ug + (size_t)(r - 3 + tap) * 4096 + c0);
    float u[8]; unpack8(uv, u);
#pragma unroll
    for (int i = 0; i < 8; i++) acc[i] += u[i] * cw[tap * DI2 + c0 + i];
  }
  uint4 gv = *(const uint4*)(ug + (size_t)r * 4096 + DI2 + c0);
  float gt[8]; unpack8(gv, gt);
  unsigned short o16[8];
#pragma unroll
  for (int i = 0; i < 8; i++) {
    const float val = acc[i] / (1.0f + __expf(-acc[i]));
    const float gg  = gt[i] / (1.0f + __expf(-gt[i]));
    o16[i] = f2bf(val * gg);
  }
  uint4 ov;
  ov.x = (unsigned)o16[0] | ((unsigned)o16[1] << 16);
  ov.y = (unsigned)o16[2] | ((unsigned)o16[3] << 16);
  ov.z = (unsigned)o16[4] | ((unsigned)o16[5] << 16);
  ov.w = (unsigned)o16[6] | ((unsigned)o16[7] << 16);
  *(uint4*)(hin + (size_t)r * DI2 + c0) = ov;
}

// ---------------- superchunk prefix (in-place): Minit_g = 0.9^16 Minit_{g-1} + T_{g-1} ----------------
__global__ __launch_bounds__(256)
void prefix_kernel(unsigned short* __restrict__ Tb) {
  const int tid = blockIdx.x * 256 + threadIdx.x;  // 262144 threads
  const int b = tid >> 17, i = tid & 131071;
  unsigned short* p = Tb + (((size_t)b * 8) << 20) + (size_t)i * 8;
  float acc[8] = {};
  for (int g = 0; g < 8; g++) {
    unsigned short* pg = p + ((size_t)g << 20);
    uint4 tv = *(uint4*)pg;
    float tf_[8]; unpack8(tv, tf_);
    uint4 ov;
    ov.x = (unsigned)f2bf(acc[0]) | ((unsigned)f2bf(acc[1]) << 16);
    ov.y = (unsigned)f2bf(acc[2]) | ((unsigned)f2bf(acc[3]) << 16);
    ov.z = (unsigned)f2bf(acc[4]) | ((unsigned)f2bf(acc[5]) << 16);
    ov.w = (unsigned)f2bf(acc[6]) | ((unsigned)f2bf(acc[7]) << 16);
    *(uint4*)pg = ov;
#pragma unroll
    for (int e = 0; e < 8; e++) acc[e] = LAMBDA16 * acc[e] + tf_[e];
  }
}

extern "C" void kernel_launch(void* const* d_in, const int* in_sizes, int n_in,
                              void* d_out, int out_size, void* d_ws, size_t ws_size,
                              hipStream_t stream) {
  (void)in_sizes; (void)n_in; (void)out_size;
  const float* x      = (const float*)d_in[0];
  const float* norm_w = (const float*)d_in[1];
  const float* w_up   = (const float*)d_in[2];
  const float* w_gate = (const float*)d_in[3];
  const float* w_down = (const float*)d_in[4];
  const float* conv_w = (const float*)d_in[5];
  const float* conv_b = (const float*)d_in[6];
  const float* wq     = (const float*)d_in[7];
  const float* wk     = (const float*)d_in[8];
  const float* wv     = (const float*)d_in[9];
  const float* wo     = (const float*)d_in[10];
  float* out = (float*)d_out;

  const size_t MB = 1ull << 20;
  // Aliased workspace plan (212 MiB). Lifetimes:
  //   [0,32M)    ug -> hbuf -> Tbuf (after QKV gemm)
  //   [32,64M)   ug -> qbuf
  //   [64,96M)   ug -> kbuf
  //   [96,128M)  ug -> ktbuf (pre-scaled by decay) -> sbuf (after state gemm)
  //   [128,160M) normed -> hin -> vtbuf
  //   [160,192M) hin tail -> obuf
  //   [192,212M) weight transposes (wqt/wkt/wvt contiguous => fused QKV weight [3072][1024])
  if (ws_size < 212 * MB) return;
  char* base = (char*)d_ws;
  unsigned short* ug     = (unsigned short*)(base + 0);
  unsigned short* hbuf   = (unsigned short*)(base + 0);
  unsigned short* Tbuf   = (unsigned short*)(base + 0);
  unsigned short* qbuf   = (unsigned short*)(base + 32 * MB);
  unsigned short* kbuf   = (unsigned short*)(base + 64 * MB);
  unsigned short* ktbuf  = (unsigned short*)(base + 96 * MB);
  unsigned short* sbuf   = (unsigned short*)(base + 96 * MB);
  unsigned short* normed = (unsigned short*)(base + 128 * MB);
  unsigned short* hin    = (unsigned short*)(base + 128 * MB);
  unsigned short* vtbuf  = (unsigned short*)(base + 128 * MB);
  unsigned short* obuf   = (unsigned short*)(base + 160 * MB);
  unsigned short* wugt   = (unsigned short*)(base + 192 * MB);
  unsigned short* wdt    = (unsigned short*)(base + 200 * MB);
  unsigned short* wqkvt  = (unsigned short*)(base + 204 * MB);  // [3072][1024]: wq|wk|wv
  unsigned short* wot    = (unsigned short*)(base + 210 * MB);

  dim3 tb(32, 8);
  transpose_cast<<<dim3(DI2 / 32, DD / 32), tb, 0, stream>>>(w_up,   wugt,                    DD,  DI2);
  transpose_cast<<<dim3(DI2 / 32, DD / 32), tb, 0, stream>>>(w_gate, wugt + (size_t)DI2 * DD, DD,  DI2);
  transpose_cast<<<dim3(DD / 32, DI2 / 32), tb, 0, stream>>>(w_down, wdt, DI2, DD);
  transpose_cast<<<dim3(DD / 32, DD / 32),  tb, 0, stream>>>(wq, wqkvt,                          DD, DD);
  transpose_cast<<<dim3(DD / 32, DD / 32),  tb, 0, stream>>>(wk, wqkvt + (size_t)DD * DD,       DD, DD);
  transpose_cast<<<dim3(DD / 32, DD / 32),  tb, 0, stream>>>(wv, wqkvt + (size_t)2 * DD * DD,   DD, DD);
  transpose_cast<<<dim3(DD / 32, DD / 32),  tb, 0, stream>>>(wo, wot, DD, DD);

  rmsnorm_kernel<<<NR, 256, 0, stream>>>(x, norm_w, normed);

  // [16384,1024] @ [1024,4096] -> ug (u | gate_pre); grid 64*16 = 1024 blocks
  gemm256<EP_BF16><<<dim3((NR / 256) * (4096 / 256)), 512, 0, stream>>>(
      normed, wugt, ug, nullptr, nullptr, nullptr, NR, 4096, DD, DD, DD, 1.0f);

  convgate_kernel<<<NR, 256, 0, stream>>>(ug, conv_w, conv_b, hin);

  // [16384,2048] @ [2048,1024] -> h; grid 64*4 = 256
  gemm256<EP_BF16><<<dim3((NR / 256) * (DD / 256)), 512, 0, stream>>>(
      hin, wdt, hbuf, nullptr, nullptr, nullptr, NR, DD, DI2, DI2, DI2, 1.0f);

  // fused QKV: [16384,1024] @ [1024,3072]; epilogue splits q/k(+k^T decayed)/v^T
  gemm256<EP_QKV><<<dim3((NR / 256) * (3072 / 256)), 512, 0, stream>>>(
      hbuf, wqkvt, qbuf, kbuf, (float*)ktbuf, (const float*)vtbuf,
      NR, 3072, DD, DD, DD, 1.0f);

  // Hebbian memory via superchunk decomposition (16 chunks / superchunk):
  // T[gb] = (decayed V^T) @ K-slice  — ktbuf already carries the decay weights.
  gemm256<EP_STATE><<<dim3(16, 1, 16), 512, 0, stream>>>(
      vtbuf, ktbuf, Tbuf, nullptr, nullptr, nullptr, 1024, 1024, 1024, SS, SS, 1.0f);
  // S[gb] = decay/tril-weighted Q K^T (lower-triangular 256^2 tiles only) -> sbuf
  gemm256<EP_SCORE><<<dim3(10, 1, 16), 512, 0, stream>>>(
      qbuf, kbuf, sbuf, nullptr, nullptr, nullptr, 1024, 1024, 1024, DD, DD, 1.0f);
  prefix_kernel<<<1024, 256, 0, stream>>>(Tbuf);
  // O[gb] = S @ V (banded kLen per row-tile) -> obuf (plain store)
  gemm256<EP_PV><<<dim3(16, 1, 16), 512, 0, stream>>>(
      sbuf, vtbuf, obuf, nullptr, nullptr, nullptr, 1024, 1024, 1024, 1024, SS, 1.0f);
  // obuf += 0.9^cl * Q @ Minit
  gemm256<EP_CROSS><<<dim3(16, 1, 16), 512, 0, stream>>>(
      qbuf, Tbuf, obuf, nullptr, nullptr, nullptr, 1024, 1024, 1024, DD, 1024, 1.0f);

  // out = obuf @ wo + x; grid 256
  gemm256<EP_F32_RES><<<dim3((NR / 256) * (DD / 256)), 512, 0, stream>>>(
      obuf, wot, nullptr, nullptr, out, x, NR, DD, DD, DD, DD, 1.0f);
}